// Round 8
// baseline (263.416 us; speedup 1.0000x reference)
//
#include <hip/hip_runtime.h>
#include <math.h>

#define NH    8
#define NQB   4
#define NPAIR 32
#define NTOK  1024
#define DH    64
#define DIMX  512
#define NROWS (NPAIR*NTOK)

typedef __attribute__((ext_vector_type(8))) short short8;
typedef _Float16 half8 __attribute__((ext_vector_type(8)));
typedef __attribute__((ext_vector_type(4))) float f32x4;

__device__ __forceinline__ unsigned short f2bf(float x){
  unsigned u = __float_as_uint(x);
  u += 0x7fffu + ((u>>16)&1u);
  return (unsigned short)(u>>16);
}
__device__ __forceinline__ float bf2f(unsigned short h){
  return __uint_as_float(((unsigned)h)<<16);
}
__device__ __forceinline__ unsigned short f2h(float x){
  union{ _Float16 f; unsigned short u; } c; c.f = (_Float16)x; return c.u;
}
__device__ __forceinline__ float h2f(unsigned short u){
  union{ _Float16 f; unsigned short u; } c; c.u = u; return (float)c.f;
}
__device__ __forceinline__ f32x4 mfma16(short8 a, short8 b, f32x4 c){
  return __builtin_amdgcn_mfma_f32_16x16x32_bf16(a,b,c,0,0,0);
}
__device__ __forceinline__ f32x4 mfma16f(half8 a, half8 b, f32x4 c){
  return __builtin_amdgcn_mfma_f32_16x16x32_f16(a,b,c,0,0,0);
}
// async global->LDS DMA, 16B per lane; LDS dest = base + lane*16
__device__ __forceinline__ void dma16(const void* g, void* l){
  __builtin_amdgcn_global_load_lds(
      (const __attribute__((address_space(1))) void*)g,
      (__attribute__((address_space(3))) void*)l, 16, 0, 0);
}

// chunk layout for 512-col matrices: [rowgrp64][colgrp64][cq8][row64][8]
__device__ __forceinline__ size_t cidx(int r, int c){
  return ((((size_t)((r>>6)*8 + (c>>6)))*8 + ((c&63)>>3))*64 + (r&63))*8 + (c&7);
}
// K layout: FK[p][kc][dq][k64][8]
__device__ __forceinline__ size_t kidx(int p, int key, int dh){
  return ((((size_t)(p*16 + (key>>6)))*8 + (dh>>3))*64 + (key&63))*8 + (dh&7);
}

// ---------------- fused prelude: LN stats | W split | accumulator zeroing

__global__ __launch_bounds__(256) void k_pre(
    const float* __restrict__ q, const float* __restrict__ k, const float* __restrict__ v,
    float* __restrict__ mu_rstd,
    const float* __restrict__ Wa, const float* __restrict__ Wb,
    unsigned short* __restrict__ Wth, unsigned short* __restrict__ Wtl,
    unsigned short* __restrict__ Woth, unsigned short* __restrict__ Wotl,
    float* __restrict__ zacc){
  __shared__ float tile[64][65];
  int b = blockIdx.x, tid = threadIdx.x;
  if (b < 3072){
    int wid = tid >> 6, lane = tid & 63;
    int tok = b*4 + wid;                   // 0..12287
    const float* src = (tok < 4096) ? q : ((tok < 8192) ? k : v);
    int t = tok & 4095;
    const float4* p4 = (const float4*)(src + (size_t)t*DIMX) + lane*2;
    float4 a = p4[0], bb = p4[1];
    float s  = a.x+a.y+a.z+a.w + bb.x+bb.y+bb.z+bb.w;
    float ss = a.x*a.x+a.y*a.y+a.z*a.z+a.w*a.w
             + bb.x*bb.x+bb.y*bb.y+bb.z*bb.z+bb.w*bb.w;
    #pragma unroll
    for (int off=32; off; off>>=1){ s += __shfl_down(s,off); ss += __shfl_down(ss,off); }
    if (lane==0){
      float mu = s*(1.0f/512.0f);
      float var = ss*(1.0f/512.0f) - mu*mu;
      mu_rstd[tok*2+0] = mu;
      mu_rstd[tok*2+1] = 1.0f/sqrtf(var + 1e-5f);
    }
  } else if (b < 3200){
    int sb = b - 3072;
    int z = sb >> 6, rem = sb & 63, kb = rem & 7, nb = rem >> 3;
    const float* W = z ? Wb : Wa;
    unsigned short* oh_ = z ? Woth : Wth;
    unsigned short* ol_ = z ? Wotl : Wtl;
    #pragma unroll
    for (int it=0; it<4; ++it){
      int idx = tid + 256*it;          // 0..1023
      int kr = idx>>4, c4 = idx&15;
      float4 vv = *(const float4*)(W + (size_t)(kb*64+kr)*DIMX + nb*64 + c4*4);
      tile[c4*4+0][kr]=vv.x; tile[c4*4+1][kr]=vv.y; tile[c4*4+2][kr]=vv.z; tile[c4*4+3][kr]=vv.w;
    }
    __syncthreads();
    #pragma unroll
    for (int it=0; it<4; ++it){
      int idx = tid + 256*it;
      int n = idx>>4, k4 = idx&15;
      size_t base = cidx(nb*64+n, kb*64+k4*4);
      ushort4 hv, lv;
      { float xx=tile[n][k4*4+0]; unsigned short hh=f2bf(xx); hv.x=hh; lv.x=f2bf(xx-bf2f(hh)); }
      { float xx=tile[n][k4*4+1]; unsigned short hh=f2bf(xx); hv.y=hh; lv.y=f2bf(xx-bf2f(hh)); }
      { float xx=tile[n][k4*4+2]; unsigned short hh=f2bf(xx); hv.z=hh; lv.z=f2bf(xx-bf2f(hh)); }
      { float xx=tile[n][k4*4+3]; unsigned short hh=f2bf(xx); hv.w=hh; lv.w=f2bf(xx-bf2f(hh)); }
      *(ushort4*)(oh_+base) = hv;
      *(ushort4*)(ol_+base) = lv;
    }
  } else {
    // zero 24576 B of accumulators (gacc/racc/qgs/nusum/ctr/coefG)
    uint4 z4 = {0u,0u,0u,0u};
    uint4* dst = (uint4*)zacc;
    #pragma unroll
    for (int i=0;i<6;++i) dst[tid + 256*i] = z4;
  }
}

// --------------- LN + projection GEMM via split-bf16 MFMA (q, k, v by z)

__global__ __launch_bounds__(256) void k_projmm(
    const float* __restrict__ q, const float* __restrict__ k, const float* __restrict__ v,
    const float* __restrict__ g, const float* __restrict__ bln,
    const unsigned short* __restrict__ Wth, const unsigned short* __restrict__ Wtl,
    const float* __restrict__ mu_rstd,
    unsigned short* __restrict__ fqh, unsigned short* __restrict__ fql,
    unsigned short* __restrict__ fkh, unsigned short* __restrict__ fkl,
    float* __restrict__ fv,
    double* __restrict__ qgs, double* __restrict__ nusum){
  __shared__ __align__(16) unsigned short Ahs[64*72];
  __shared__ __align__(16) unsigned short Als[64*72];
  __shared__ __align__(16) unsigned short WhL[2][4096];
  __shared__ __align__(16) unsigned short WlL[2][4096];
  __shared__ float scrc[4][128];
  int z = blockIdx.z;
  const float* x = (z==0) ? q : ((z==1) ? k : v);
  int mb = blockIdx.x, nb = blockIdx.y;
  int tid = threadIdx.x, w = tid>>6, l = tid&63, lm = l&15, qd = l>>4;
  int rbase = (w&1)*32;
  int tile = w>>1;
  int cbase = nb*128 + tile*64;
  scrc[tid>>7][tid&127] = 0.f;
  scrc[2+(tid>>7)][tid&127] = 0.f;
  f32x4 acc[2][4];
  #pragma unroll
  for (int mt=0;mt<2;++mt)
    #pragma unroll
    for (int nt=0;nt<4;++nt) acc[mt][nt] = (f32x4){0.f,0.f,0.f,0.f};
  int r0 = mb & 7;
  for (int t = 0; t < 8; ++t){
    int kc8 = (t + r0) & 7;
    float4 xv[4]; float mus[4], rss[4]; float4 gv[4], bv[4]; int rr[4], kk4[4];
    #pragma unroll
    for (int it=0; it<4; ++it){
      int idx = tid + 256*it;          // 0..1023
      int r = idx>>4, k4 = idx&15;
      rr[it]=r; kk4[it]=k4;
      int tokg = z*4096 + mb*64 + r;
      mus[it] = mu_rstd[tokg*2+0]; rss[it] = mu_rstd[tokg*2+1];
      xv[it] = *(const float4*)(x + (size_t)(mb*64+r)*DIMX + kc8*64 + k4*4);
      gv[it] = *(const float4*)(g   + kc8*64 + k4*4);
      bv[it] = *(const float4*)(bln + kc8*64 + k4*4);
    }
    __syncthreads();                   // prev chunk consumed
    {  // wave w stages W chunk: tile w>>1, hi/lo w&1
      int st = w>>1, hl = w&1;
      const unsigned short* src = (hl ? Wtl : Wth)
          + ((size_t)((nb*2+st)*8 + kc8))*4096;
      unsigned short* dst = hl ? WlL[st] : WhL[st];
      #pragma unroll
      for (int j=0;j<8;++j) dma16(src + j*512 + l*8, dst + j*512);
    }
    #pragma unroll
    for (int it=0; it<4; ++it){
      float y0 = (xv[it].x-mus[it])*rss[it]*gv[it].x + bv[it].x;
      float y1 = (xv[it].y-mus[it])*rss[it]*gv[it].y + bv[it].y;
      float y2 = (xv[it].z-mus[it])*rss[it]*gv[it].z + bv[it].z;
      float y3 = (xv[it].w-mus[it])*rss[it]*gv[it].w + bv[it].w;
      ushort4 hv, lv;
      { unsigned short hh=f2bf(y0); hv.x=hh; lv.x=f2bf(y0-bf2f(hh)); }
      { unsigned short hh=f2bf(y1); hv.y=hh; lv.y=f2bf(y1-bf2f(hh)); }
      { unsigned short hh=f2bf(y2); hv.z=hh; lv.z=f2bf(y2-bf2f(hh)); }
      { unsigned short hh=f2bf(y3); hv.w=hh; lv.w=f2bf(y3-bf2f(hh)); }
      *(ushort4*)(Ahs + rr[it]*72 + kk4[it]*4) = hv;
      *(ushort4*)(Als + rr[it]*72 + kk4[it]*4) = lv;
    }
    __syncthreads();                   // staging + DMA visible
    #pragma unroll
    for (int kch=0; kch<2; ++kch){
      short8 a_h[2], a_l[2];
      #pragma unroll
      for (int mt=0;mt<2;++mt){
        a_h[mt] = *(const short8*)(Ahs + (rbase+mt*16+lm)*72 + kch*32 + qd*8);
        a_l[mt] = *(const short8*)(Als + (rbase+mt*16+lm)*72 + kch*32 + qd*8);
      }
      #pragma unroll
      for (int nt=0;nt<4;++nt){
        int off = ((kch*4+qd)*64 + nt*16+lm)*8;
        short8 bh = *(const short8*)(WhL[tile] + off);
        short8 bl = *(const short8*)(WlL[tile] + off);
        #pragma unroll
        for (int mt=0;mt<2;++mt){
          acc[mt][nt] = mfma16(a_h[mt], bh, acc[mt][nt]);
          acc[mt][nt] = mfma16(a_h[mt], bl, acc[mt][nt]);
          acc[mt][nt] = mfma16(a_l[mt], bh, acc[mt][nt]);
        }
      }
    }
  }
  int head = cbase >> 6;
  if (z < 2){
    float csum[4] = {0.f,0.f,0.f,0.f};
    #pragma unroll
    for (int mt=0;mt<2;++mt){
      #pragma unroll
      for (int nt=0;nt<4;++nt){
        #pragma unroll
        for (int i=0;i<4;++i){
          float val = acc[mt][nt][i];
          csum[nt] += val;
          int tglob = mb*64 + rbase + mt*16 + qd*4 + i;
          int qb = tglob>>10, n = tglob&1023;
          int p = head*4 + qb;
          int d = nt*16 + lm;
          unsigned short hh = f2bf(val);
          unsigned short ll = f2bf(val - bf2f(hh));
          if (z==0){
            size_t ix = ((size_t)(p*NTOK+n))*DH + d;
            fqh[ix] = hh; fql[ix] = ll;
          } else {
            size_t ix = kidx(p, n, d);
            fkh[ix] = hh; fkl[ix] = ll;
          }
        }
      }
    }
    #pragma unroll
    for (int m=16;m<64;m<<=1){
      #pragma unroll
      for (int nt=0;nt<4;++nt) csum[nt] += __shfl_xor(csum[nt], m);
    }
    if (qd==0){
      #pragma unroll
      for (int nt=0;nt<4;++nt) scrc[w][tile*64 + nt*16 + lm] = csum[nt];
    }
    __syncthreads();
    if (tid < 128){
      float s = scrc[0][tid]+scrc[1][tid]+scrc[2][tid]+scrc[3][tid];
      if (z==0){
        atomicAdd(&qgs[nb*128 + tid], (double)s);
      } else {
        int col = nb*128 + tid;
        int hh2 = col>>6, d = col&63;
        int qb = mb>>4;
        atomicAdd(&nusum[(size_t)(hh2*4+qb)*DH + d], (double)s);
      }
    }
  } else {
    #pragma unroll
    for (int mt=0;mt<2;++mt){
      #pragma unroll
      for (int nt=0;nt<4;++nt){
        #pragma unroll
        for (int i=0;i<4;++i){
          int tglob = mb*64 + rbase + mt*16 + qd*4 + i;
          int qb = tglob>>10, n = tglob&1023;
          int p = head*4 + qb;
          int d = nt*16 + lm;
          fv[((size_t)(p*NTOK+n))*DH + d] = acc[mt][nt][i];
        }
      }
    }
  }
}

// ------- fused mid pass: fv transpose | per-row scalars | weight predictor

__global__ __launch_bounds__(256) void k_mid(
    const float* __restrict__ fv,
    unsigned short* __restrict__ fvTh, unsigned short* __restrict__ fvTl,
    const unsigned short* __restrict__ fqh, const unsigned short* __restrict__ fql,
    const unsigned short* __restrict__ fkh, const unsigned short* __restrict__ fkl,
    const double* __restrict__ nusum,
    float* __restrict__ inv_na_q, float* __restrict__ muqA, float* __restrict__ tqA,
    float* __restrict__ inv_na_k, float* __restrict__ skA,
    const double* __restrict__ qgs,
    const float* __restrict__ W1, const float* __restrict__ b1,
    const float* __restrict__ lgv, const float* __restrict__ lbv,
    const float* __restrict__ W2, const float* __restrict__ b2,
    const float* __restrict__ W3, const float* __restrict__ b3,
    const float* __restrict__ wtemp, float* __restrict__ wp_out,
    float* __restrict__ Sarr){
  __shared__ __align__(16) float msm[64*65];
  int b = blockIdx.x, tid = threadIdx.x;
  if (b < 512){
    float (*tile)[65] = (float(*)[65])msm;
    int mc = b & 15, p = b >> 4;
    #pragma unroll
    for (int it=0; it<4; ++it){
      int idx = tid + 256*it;
      int m = idx>>4, d4 = idx&15;
      float4 vv = *(const float4*)(fv + ((size_t)(p*NTOK + mc*64 + m)*DH + d4*4));
      tile[d4*4+0][m]=vv.x; tile[d4*4+1][m]=vv.y; tile[d4*4+2][m]=vv.z; tile[d4*4+3][m]=vv.w;
    }
    __syncthreads();
    #pragma unroll
    for (int it=0; it<2; ++it){
      int idx = tid + 256*it;       // 0..511
      int d = idx>>3, seg = idx&7;  // keys seg*8..seg*8+8
      size_t base = ((((size_t)(p*16+mc))*8 + seg)*64 + d)*8;
      ushort4 h0,h1v,l0,l1;
      { float xx=tile[d][seg*8+0]; unsigned short hh=f2h(xx); h0.x=hh; l0.x=f2h(xx-h2f(hh)); }
      { float xx=tile[d][seg*8+1]; unsigned short hh=f2h(xx); h0.y=hh; l0.y=f2h(xx-h2f(hh)); }
      { float xx=tile[d][seg*8+2]; unsigned short hh=f2h(xx); h0.z=hh; l0.z=f2h(xx-h2f(hh)); }
      { float xx=tile[d][seg*8+3]; unsigned short hh=f2h(xx); h0.w=hh; l0.w=f2h(xx-h2f(hh)); }
      { float xx=tile[d][seg*8+4]; unsigned short hh=f2h(xx); h1v.x=hh; l1.x=f2h(xx-h2f(hh)); }
      { float xx=tile[d][seg*8+5]; unsigned short hh=f2h(xx); h1v.y=hh; l1.y=f2h(xx-h2f(hh)); }
      { float xx=tile[d][seg*8+6]; unsigned short hh=f2h(xx); h1v.z=hh; l1.z=f2h(xx-h2f(hh)); }
      { float xx=tile[d][seg*8+7]; unsigned short hh=f2h(xx); h1v.w=hh; l1.w=f2h(xx-h2f(hh)); }
      *(ushort4*)(fvTh+base)   = h0;
      *(ushort4*)(fvTh+base+4) = h1v;
      *(ushort4*)(fvTl+base)   = l0;
      *(ushort4*)(fvTl+base+4) = l1;
    }
  } else if (b < 8704){
    int rb = b - 512;
    int wid = tid >> 6, lane = tid & 63;
    int row = rb*4 + wid;            // < 32768
    int p = row >> 10;
    int key = row & 1023;
    size_t ix = (size_t)row*DH + lane;
    float xq = bf2f(fqh[ix]) + bf2f(fql[ix]);
    float nv = (float)(nusum[(size_t)p*DH + lane] * (1.0/1024.0));
    float s = xq, ss = xq*xq, sd = xq*nv;
    #pragma unroll
    for (int off=32; off; off>>=1){
      s += __shfl_down(s,off); ss += __shfl_down(ss,off); sd += __shfl_down(sd,off);
    }
    if (lane==0){
      float nrm = sqrtf(ss);
      inv_na_q[row] = 1.0f/(nrm+1e-8f);
      muqA[row] = s*(1.0f/64.0f);
      tqA[row] = sd;
    }
    size_t ixk = kidx(p, key, lane);
    float xk = bf2f(fkh[ixk]) + bf2f(fkl[ixk]);
    float s2 = xk, ss2 = xk*xk;
    #pragma unroll
    for (int off=32; off; off>>=1){
      s2 += __shfl_down(s2,off); ss2 += __shfl_down(ss2,off);
    }
    if (lane==0){
      float nrm = sqrtf(ss2);
      inv_na_k[row] = 1.0f/(nrm+1e-8f);
      skA[row] = s2;
    }
  } else {
    // weight predictor + Sarr (single block)
    float* feats = msm;           // 8*128
    float* h1    = msm + 1024;    // 8*64
    float* h2s   = msm + 1536;    // 8*32
    float* lgt   = msm + 1792;    // 8*3 (stride 3)
    float* mv    = msm + 1832;    // 8*2
    for (int idx = tid; idx < 1024; idx += 256){
      int h = idx >> 7, i = idx & 127;
      double vv;
      if (i < 64){
        vv = qgs[h*64+i];
      } else {
        int d = i - 64;
        vv = nusum[(size_t)(h*4+0)*DH+d] + nusum[(size_t)(h*4+1)*DH+d]
           + nusum[(size_t)(h*4+2)*DH+d] + nusum[(size_t)(h*4+3)*DH+d];
      }
      feats[h*128+i] = (float)(vv * (1.0/4096.0));
    }
    if (tid < 32){
      double s = 0.0;
      for (int d = 0; d < 64; ++d) s += nusum[(size_t)tid*DH + d];
      Sarr[tid] = (float)(s * (1.0/1024.0));
    }
    __syncthreads();
    for (int idx = tid; idx < 512; idx += 256){
      int h = idx >> 6, j = idx & 63;
      float s = b1[j];
      for (int i = 0; i < 128; ++i) s += feats[h*128+i]*W1[i*64+j];
      h1[h*64+j] = s;
    }
    __syncthreads();
    if (tid < 8){
      float s=0.f, ss=0.f;
      for (int j=0;j<64;++j){ float vv=h1[tid*64+j]; s+=vv; ss+=vv*vv; }
      float mu = s*(1.0f/64.0f);
      float var = ss*(1.0f/64.0f)-mu*mu;
      mv[tid*2+0]=mu; mv[tid*2+1]=1.0f/sqrtf(var+1e-5f);
    }
    __syncthreads();
    for (int idx = tid; idx < 512; idx += 256){
      int h = idx>>6, j = idx&63;
      float vv = (h1[h*64+j]-mv[h*2+0])*mv[h*2+1]*lgv[j] + lbv[j];
      h1[h*64+j] = fmaxf(vv, 0.f);
    }
    __syncthreads();
    {
      int h = tid >> 5, j = tid & 31;
      float s = b2[j];
      for (int i=0;i<64;++i) s += h1[h*64+i]*W2[i*32+j];
      h2s[h*32+j] = fmaxf(s, 0.f);
    }
    __syncthreads();
    if (tid < 24){
      int h = tid/3, j = tid - h*3;
      float s = b3[j];
      for (int i=0;i<32;++i) s += h2s[h*32+i]*W3[i*3+j];
      lgt[h*3+j] = s;
    }
    __syncthreads();
    if (tid < 8){
      int h = tid;
      float z0=lgt[h*3+0], z1=lgt[h*3+1], z2=lgt[h*3+2];
      float m = fmaxf(z0,fmaxf(z1,z2));
      float e0=expf(z0-m), e1=expf(z1-m), e2=expf(z2-m);
      float inv = 1.0f/(e0+e1+e2);
      float l0=e0*inv, l1=e1*inv, l2=e2*inv;
      float wt = fminf(fmaxf(wtemp[0], 0.1f), 20.0f);
      float y0=l0/wt, y1=l1/wt, y2=l2/wt;
      float m2 = fmaxf(y0,fmaxf(y1,y2));
      float f0=expf(y0-m2), f1=expf(y1-m2), f2=expf(y2-m2);
      float inv2 = 1.0f/(f0+f1+f2);
      float w0=f0*inv2, w1=f1*inv2, w2=f2*inv2;
      w0 = fminf(fmaxf(w0,0.05f),0.8f);
      w1 = fminf(fmaxf(w1,0.05f),0.8f);
      w2 = fminf(fmaxf(w2,0.05f),0.8f);
      float isum = 1.0f/(w0+w1+w2);
      wp_out[h*3+0]=w0*isum; wp_out[h*3+1]=w1*isum; wp_out[h*3+2]=w2*isum;
    }
  }
}

// ------------- pass A (MFMA): KA/KB register prefetch; row-finish fused;
// the LAST block to finish also computes coef (old k_final) exactly once.

__global__ __launch_bounds__(256) void k_passA(
    const unsigned short* __restrict__ fqh, const unsigned short* __restrict__ fql,
    const unsigned short* __restrict__ fkh, const unsigned short* __restrict__ fkl,
    const float* __restrict__ inv_na_q, const float* __restrict__ muqA,
    const float* __restrict__ tqA,
    const float* __restrict__ inv_na_k, const float* __restrict__ skA,
    const float* __restrict__ Sarr,
    float* __restrict__ var_row,
    float* __restrict__ mxcosA, float* __restrict__ mxcovA,
    double* __restrict__ gacc, double* __restrict__ racc,
    const float* __restrict__ wp_out,
    float* __restrict__ coefG, unsigned* __restrict__ ctr){
  __shared__ float redbuf[4][16][5];
  __shared__ double wredS[4][3];
  int b = blockIdx.x;
  int p = ((b&7)<<2) | ((b>>3)&3);   // XCD swizzle
  int s = b>>5;                      // 0..31
  int n0 = s*32;
  int tid = threadIdx.x, w = tid>>6, l = tid&63;
  int lm = l&15, q = l>>4;
  int rt = w&1, cw = w>>1;
  int nw = n0 + rt*16;
  float Sp = Sarr[p];
  const float inv8 = (float)(1.0/(8.0+1e-6));
  float ia[4], m8[4], t8[4];
  #pragma unroll
  for (int i=0;i<4;++i){
    int rg = p*NTOK + nw + q*4 + i;
    float mq = muqA[rg];
    ia[i] = inv_na_q[rg];
    m8[i] = mq*inv8;
    t8[i] = (tqA[rg] - mq*Sp)*inv8;
  }
  const short8* aqh = (const short8*)(fqh + (size_t)(p*NTOK + nw + lm)*DH);
  const short8* aql = (const short8*)(fql + (size_t)(p*NTOK + nw + lm)*DH);
  short8 ah0 = aqh[q], ah1 = aqh[4+q], al0 = aql[q], al1 = aql[4+q];
  const unsigned short* gKh = fkh + (size_t)p*16*4096;
  const unsigned short* gKl = fkl + (size_t)p*16*4096;
  const float* cAg = inv_na_k + p*NTOK;
  const float* cSg = skA + p*NTOK;
  float sc2=0.f, sv2=0.f, scv=0.f;
  float pc[4]={0,0,0,0}, pv_[4]={0,0,0,0}, pm[4]={0,0,0,0};
  float xc[4], xv[4];
  #pragma unroll
  for (int i=0;i<4;++i){ xc[i]=-1e30f; xv[i]=-1e30f; }
  int ko0 = ((q  )*64 + (cw*2)*16+lm)*8;
  int ko1 = ((q+4)*64 + (cw*2)*16+lm)*8;
  int c0 = s & 15;                   // rotation offset

#define PA_LOAD(K, cc_) do{ \
    const unsigned short* cbh_ = gKh + (size_t)(cc_)*4096; \
    const unsigned short* cbl_ = gKl + (size_t)(cc_)*4096; \
    K[0] = *(const short8*)(cbh_ + ko0); \
    K[1] = *(const short8*)(cbh_ + ko1); \
    K[2] = *(const short8*)(cbl_ + ko0); \
    K[3] = *(const short8*)(cbl_ + ko1); \
    K[4] = *(const short8*)(cbh_ + ko0 + 128); \
    K[5] = *(const short8*)(cbh_ + ko1 + 128); \
    K[6] = *(const short8*)(cbl_ + ko0 + 128); \
    K[7] = *(const short8*)(cbl_ + ko1 + 128); \
  }while(0)

#define PA_COMP(K, cc_) do{ \
    _Pragma("unroll") \
    for (int t2=0; t2<2; ++t2){ \
      int c16 = cw*2 + t2; \
      f32x4 acc = {0.f,0.f,0.f,0.f}; \
      acc = mfma16(ah0,K[t2*4+0],acc); acc = mfma16(ah1,K[t2*4+1],acc); \
      acc = mfma16(al0,K[t2*4+0],acc); acc = mfma16(al1,K[t2*4+1],acc); \
      acc = mfma16(ah0,K[t2*4+2],acc); acc = mfma16(ah1,K[t2*4+3],acc); \
      int colg = (cc_)*64 + c16*16 + lm; \
      float ca = cAg[colg], cs = cSg[colg]; \
      _Pragma("unroll") \
      for (int i=0;i<4;++i){ \
        float dot = acc[i]; \
        float cosv = fminf(fmaxf(dot*ia[i]*ca,-0.99f),0.99f); \
        float cov  = fmaf(-m8[i], cs, fmaf(dot, inv8, -t8[i])); \
        float marg = fmaxf(0.01f - cosv, 0.f); \
        sc2 = fmaf(cosv,cosv,sc2); sv2 = fmaf(cov,cov,sv2); scv = fmaf(cosv,cov,scv); \
        pc[i]+=cosv; pv_[i]+=cov; pm[i]+=marg; \
        xc[i]=fmaxf(xc[i],cosv); \
        xv[i]=fmaxf(xv[i],cov); \
      } \
    } \
  }while(0)

  short8 KA[8], KB[8];
  PA_LOAD(KA, c0);
  for (int t = 0; t < 16; t += 2){
    int ccA = (t + c0) & 15;
    int ccB = (t + 1 + c0) & 15;
    PA_LOAD(KB, ccB);
    PA_COMP(KA, ccA);
    if (t < 14){
      int ccA2 = (t + 2 + c0) & 15;
      PA_LOAD(KA, ccA2);
    }
    PA_COMP(KB, ccB);
  }
#undef PA_LOAD
#undef PA_COMP

  #pragma unroll
  for (int m=1;m<16;m<<=1){
    #pragma unroll
    for (int i=0;i<4;++i){
      pc[i]+=__shfl_xor(pc[i],m); pv_[i]+=__shfl_xor(pv_[i],m); pm[i]+=__shfl_xor(pm[i],m);
      xc[i]=fmaxf(xc[i],__shfl_xor(xc[i],m));
      xv[i]=fmaxf(xv[i],__shfl_xor(xv[i],m));
    }
  }
  if (lm==0){
    #pragma unroll
    for (int i=0;i<4;++i){
      int r16 = q*4+i;
      redbuf[w][r16][0]=pc[i]; redbuf[w][r16][1]=pv_[i]; redbuf[w][r16][2]=pm[i];
      redbuf[w][r16][3]=xc[i]; redbuf[w][r16][4]=xv[i];
    }
  }
  double vals[3] = {(double)sc2,(double)sv2,(double)scv};
  #pragma unroll
  for (int c2=0;c2<3;++c2){
    double vv = vals[c2];
    #pragma unroll
    for (int off=32; off; off>>=1) vv += __shfl_down(vv, off);
    if (l==0) wredS[w][c2] = vv;
  }
  __syncthreads();
  if (tid < 32){
    int rt2 = tid>>4, r16 = tid&15;
    int w0 = rt2, w1 = rt2+2;
    float sc = redbuf[w0][r16][0]+redbuf[w1][r16][0];
    float sv = redbuf[w0][r16][1]+redbuf[w1][r16][1];
    float sm = redbuf[w0][r16][2]+redbuf[w1][r16][2];
    float mxc = fmaxf(redbuf[w0][r16][3],redbuf[w1][r16][3]);
    float mxv = fmaxf(redbuf[w0][r16][4],redbuf[w1][r16][4]);
    int row = p*NTOK + n0 + tid;
    float vr = sm * (1.0f/1024.0f);
    var_row[row] = vr;
    mxcosA[row] = mxc; mxcovA[row] = mxv;
    // fused row-finish: per-row moments -> racc
    double dv = (double)vr;
    double rc = (double)sc, rv = (double)sv;
    double vals2[6];
    vals2[0] = 1024.0*dv;
    vals2[1] = 1024.0*dv*dv;
    vals2[2] = dv*rc;
    vals2[3] = dv*rv;
    vals2[4] = rc;
    vals2[5] = rv;
    int hh = p >> 2;
    #pragma unroll
    for (int c2 = 0; c2 < 6; ++c2){
      double vv = vals2[c2];
      vv += __shfl_down(vv,16);
      vv += __shfl_down(vv,8);
      vv += __shfl_down(vv,4);
      vv += __shfl_down(vv,2);
      vv += __shfl_down(vv,1);
      if (tid==0) atomicAdd(&racc[hh*6+c2], vv);
    }
  }
  if (tid == 0){
    int h = p >> 2;
    #pragma unroll
    for (int c2=0;c2<3;++c2){
      double t = wredS[0][c2]+wredS[1][c2]+wredS[2][c2]+wredS[3][c2];
      atomicAdd(&gacc[h*3+c2], t);
    }
    // last block finalizes coef (k_final math, executed exactly once)
    __threadfence();
    unsigned old = atomicAdd(ctr, 1u);
    if (old == 1023u){
      __threadfence();
      const double N = 33554432.0;
      double Sc1=0,Sc2=0,Sv1=0,Sv2=0,Sr1=0,Sr2=0;
      for (int hh=0;hh<8;++hh){
        Sc2+=gacc[hh*3+0]; Sv2+=gacc[hh*3+1];
        Sr1+=racc[hh*6+0]; Sr2+=racc[hh*6+1];
        Sc1+=racc[hh*6+4]; Sv1+=racc[hh*6+5];
      }
      double cvar = (Sc2 - Sc1*Sc1/N)/(N-1.0);
      double cn = sqrt(fmax(cvar,0.0)) + 1e-6;
      double cscale = (cn < 1e-4) ? 0.1 : 1.0;
      double vraw = (Sv2 - Sv1*Sv1/N)/(N-1.0);
      double sraw = sqrt(fmax(vraw,0.0));
      double basev = 0.001/1024.0;
      double regv = (sraw < 1e-6) ? basev*10.0 : basev;
      double covn = regv*sraw + 1e-6;
      double vvar = (Sr2 - Sr1*Sr1/N)/(N-1.0);
      double vn = sqrt(fmax(vvar,0.0)) + 1e-6;
      double ah[8], bh[8], chh[8];
      double Sd1=0.0, Sd2=0.0;
      for (int hh=0;hh<8;++hh){
        double a = (double)wp_out[hh*3+0]/cn*cscale;
        double bcoef = (double)wp_out[hh*3+1]*regv*0.5/covn;
        double c = (double)wp_out[hh*3+2]*0.5/vn;
        ah[hh]=a; bh[hh]=bcoef; chh[hh]=c;
        Sd1 += a*racc[hh*6+4] + bcoef*racc[hh*6+5] + c*racc[hh*6+0];
        Sd2 += a*a*gacc[hh*3+0] + bcoef*bcoef*gacc[hh*3+1] + c*c*racc[hh*6+1]
             + 2.0*(a*bcoef*gacc[hh*3+2] + a*c*racc[hh*6+2] + bcoef*c*racc[hh*6+3]);
      }
      double dvar = (Sd2 - Sd1*Sd1/N)/(N-1.0);
      double dstd = sqrt(fmax(dvar,0.0));
      double temp = (dstd < 1e-6) ? 0.1 : 0.3 + dstd;
      double tcl = fmin(fmax(temp,0.1),5.0);
      double it = 1.0/tcl;
      for (int hh=0;hh<8;++hh){
        coefG[hh*3+0] = (float)(ah[hh]*it);
        coefG[hh*3+1] = (float)(bh[hh]*it);
        coefG[hh*3+2] = (float)(chh[hh]*it);
      }
    }
  }
}

// -------------------- pass C (MFMA): K/V direct from L2; P-transpose in
// LDS (double-buffered, stride 76 = conflict-free); coef precomputed.

__global__ __launch_bounds__(256) void k_pv(
    const unsigned short* __restrict__ fqh, const unsigned short* __restrict__ fql,
    const unsigned short* __restrict__ fkh, const unsigned short* __restrict__ fkl,
    const unsigned short* __restrict__ fvTh, const unsigned short* __restrict__ fvTl,
    const float* __restrict__ inv_na_q, const float* __restrict__ muqA,
    const float* __restrict__ tqA,
    const float* __restrict__ inv_na_k, const float* __restrict__ skA,
    const float* __restrict__ Sarr, const float* __restrict__ var_row,
    const float* __restrict__ mxcosA, const float* __restrict__ mxcovA,
    const float* __restrict__ coef,
    unsigned short* __restrict__ ohh, unsigned short* __restrict__ ohl){
  __shared__ __align__(16) unsigned short ph[2][32][76];
  __shared__ float denbuf[4][16];
  __shared__ float dnv[32];
  int b = blockIdx.x;
  int p = ((b&7)<<2) | ((b>>3)&3);   // XCD swizzle
  int s = b>>5;
  int n0 = s*32;
  int h = p>>2, qb = p&3;
  int tid = threadIdx.x, w = tid>>6, l = tid&63;
  int lm = l&15, q = l>>4;
  int rt = w&1, cw = w>>1;
  int nw = n0 + rt*16;
  float A = coef[h*3+0], B = coef[h*3+1], C = coef[h*3+2];
  float Sp = Sarr[p];
  const float inv8 = (float)(1.0/(8.0+1e-6));
  float B8 = B*inv8;
  float ia[4], bm[4], o2[4];
  #pragma unroll
  for (int i=0;i<4;++i){
    int rg = p*NTOK + nw + q*4 + i;
    float mq = muqA[rg];
    ia[i] = inv_na_q[rg];
    bm[i] = B8*mq;
    float tq2 = tqA[rg] - mq*Sp;
    float vr = var_row[rg];
    float Mh = A*mxcosA[rg] + B*mxcovA[rg] + C*vr;
    o2[i] = (C*vr - Mh) - B8*tq2;
  }
  const short8* aqh = (const short8*)(fqh + (size_t)(p*NTOK + nw + lm)*DH);
  const short8* aql = (const short8*)(fql + (size_t)(p*NTOK + nw + lm)*DH);
  short8 ah0 = aqh[q], ah1 = aqh[4+q], al0 = aql[q], al1 = aql[4+q];
  const unsigned short* gKh = fkh  + (size_t)p*16*4096;
  const unsigned short* gKl = fkl  + (size_t)p*16*4096;
  const unsigned short* gVh = fvTh + (size_t)p*16*4096;
  const unsigned short* gVl = fvTl + (size_t)p*16*4096;
  const float* cAg = inv_na_k + p*NTOK;
  const float* cSg = skA + p*NTOK;
  f32x4 o0 = {0.f,0.f,0.f,0.f}, o1 = {0.f,0.f,0.f,0.f};
  float den[4] = {0.f,0.f,0.f,0.f};
  int ko0 = ((q  )*64 + (cw*2)*16+lm)*8;
  int ko1 = ((q+4)*64 + (cw*2)*16+lm)*8;
  int vo0 = ((q  )*64 + w*16+lm)*8;
  int vo1 = ((q+4)*64 + w*16+lm)*8;
  int c0 = s & 15;                   // rotation offset

#define PV_KLOAD(K, cc_) do{ \
    const unsigned short* cbh_ = gKh + (size_t)(cc_)*4096; \
    const unsigned short* cbl_ = gKl + (size_t)(cc_)*4096; \
    K[0] = *(const short8*)(cbh_ + ko0); \
    K[1] = *(const short8*)(cbh_ + ko1); \
    K[2] = *(const short8*)(cbl_ + ko0); \
    K[3] = *(const short8*)(cbl_ + ko1); \
    K[4] = *(const short8*)(cbh_ + ko0 + 128); \
    K[5] = *(const short8*)(cbh_ + ko1 + 128); \
    K[6] = *(const short8*)(cbl_ + ko0 + 128); \
    K[7] = *(const short8*)(cbl_ + ko1 + 128); \
  }while(0)

#define PV_QK(K, cc_, phc_) do{ \
    _Pragma("unroll") \
    for (int t2=0; t2<2; ++t2){ \
      int c16 = cw*2 + t2; \
      f32x4 acc = {0.f,0.f,0.f,0.f}; \
      acc = mfma16(ah0,K[t2*4+0],acc); acc = mfma16(ah1,K[t2*4+1],acc); \
      acc = mfma16(al0,K[t2*4+0],acc); acc = mfma16(al1,K[t2*4+1],acc); \
      acc = mfma16(ah0,K[t2*4+2],acc); acc = mfma16(ah1,K[t2*4+3],acc); \
      int colg = (cc_)*64 + c16*16 + lm; \
      float ca = cAg[colg], cs = cSg[colg]; \
      _Pragma("unroll") \
      for (int i=0;i<4;++i){ \
        float dot = acc[i]; \
        float cosv = fminf(fmaxf(dot*ia[i]*ca,-0.99f),0.99f); \
        float arg = fmaf(A, cosv, fmaf(-bm[i], cs, fmaf(B8, dot, o2[i]))); \
        float e = __expf(arg); \
        unsigned short us = f2h(e); \
        phc_[rt*16+q*4+i][c16*16+lm] = us; \
        den[i] += h2f(us); \
      } \
    } \
  }while(0)

#define PV_TAIL(cc_, phc_) do{ \
    const unsigned short* cvh_ = gVh + (size_t)(cc_)*4096; \
    const unsigned short* cvl_ = gVl + (size_t)(cc_)*4096; \
    half8 vh0 = *(const half8*)(cvh_ + vo0); \
    half8 vh1 = *(const half8*)(cvh_ + vo1); \
    half8 vl0 = *(const half8*)(cvl_ + vo0); \
    half8 vl1 = *(const half8*)(cvl_ + vo1); \
    __syncthreads(); \
    half8 pb00 = *(const half8*)&phc_[lm][q*8]; \
    half8 pb01 = *(const half8*)&phc_[lm][32+q*8]; \
    half8 pb10 = *(const half8*)&phc_[16+lm][q*8]; \
    half8 pb11 = *(const half8*)&phc_[16+lm][32+q*8]; \
    o0 = mfma16f(vh0,pb00,o0); o0 = mfma16f(vl0,pb00,o0); \
    o0 = mfma16f(vh1,pb01,o0); o0 = mfma16f(vl1,pb01,o0); \
    o1 = mfma16f(vh0,pb10,o1); o1 = mfma16f(vl0,pb10,o1); \
    o1 = mfma16f(vh1,pb11,o1); o1 = mfma16f(vl1,pb11,o1); \
  }while(0)

  short8 KA[8], KB[8];
  PV_KLOAD(KA, c0);
  for (int t = 0; t < 16; t += 2){
    int ccA = (t + c0) & 15;
    int ccB = (t + 1 + c0) & 15;
    PV_KLOAD(KB, ccB);
    {
      unsigned short (*phc)[76] = ph[0];
      PV_QK(KA, ccA, phc);
      PV_TAIL(ccA, phc);
    }
    if (t < 14){
      int ccA2 = (t + 2 + c0) & 15;
      PV_KLOAD(KA, ccA2);
    }
    {
      unsigned short (*phc)[76] = ph[1];
      PV_QK(KB, ccB, phc);
      PV_TAIL(ccB, phc);
    }
  }
#undef PV_KLOAD
#undef PV_QK
#undef PV_TAIL

  #pragma unroll
  for (int m=1;m<16;m<<=1){
    #pragma unroll
    for (int i=0;i<4;++i) den[i] += __shfl_xor(den[i],m);
  }
  if (lm==0){
    #pragma unroll
    for (int i=0;i<4;++i) denbuf[w][q*4+i] = den[i];
  }
  __syncthreads();
  if (tid < 32){
    int rt2 = tid>>4, r16 = tid&15;
    dnv[tid] = 1.0f/(denbuf[rt2][r16] + denbuf[rt2+2][r16]);
  }
  __syncthreads();
  {
    float inv0 = dnv[lm];
    float inv1 = dnv[16+lm];
    int dcol = h*64 + w*16 + q*4;
    int row0 = qb*NTOK + n0 + lm;
    int row1 = row0 + 16;
    size_t b0i = cidx(row0, dcol);
    size_t b1i = cidx(row1, dcol);
    ushort4 h0,l0,h1,l1;
    { float xx=o0[0]*inv0; unsigned short hh=f2bf(xx); h0.x=hh; l0.x=f2bf(xx-bf2f(hh)); }
    { float xx=o0[1]*inv0; unsigned short hh=f2bf(xx); h0.y=hh; l0.y=f2bf(xx-bf2f(hh)); }
    { float xx=o0[2]*inv0; unsigned short hh=f2bf(xx); h0.z=hh; l0.z=f2bf(xx-bf2f(hh)); }
    { float xx=o0[3]*inv0; unsigned short hh=f2bf(xx); h0.w=hh; l0.w=f2bf(xx-bf2f(hh)); }
    { float xx=o1[0]*inv1; unsigned short hh=f2bf(xx); h1.x=hh; l1.x=f2bf(xx-bf2f(hh)); }
    { float xx=o1[1]*inv1; unsigned short hh=f2bf(xx); h1.y=hh; l1.y=f2bf(xx-bf2f(hh)); }
    { float xx=o1[2]*inv1; unsigned short hh=f2bf(xx); h1.z=hh; l1.z=f2bf(xx-bf2f(hh)); }
    { float xx=o1[3]*inv1; unsigned short hh=f2bf(xx); h1.w=hh; l1.w=f2bf(xx-bf2f(hh)); }
    *(ushort4*)(ohh+b0i)=h0; *(ushort4*)(ohl+b0i)=l0;
    *(ushort4*)(ohh+b1i)=h1; *(ushort4*)(ohl+b1i)=l1;
  }
}

// ----------------- output GEMM (MFMA): A and W staged via global_load_lds.

__global__ __launch_bounds__(256) void k_outmm(
    const unsigned short* __restrict__ ohh, const unsigned short* __restrict__ ohl,
    const unsigned short* __restrict__ Woth, const unsigned short* __restrict__ Wotl,
    const float* __restrict__ bias, float* __restrict__ out){
  __shared__ __align__(16) unsigned short Ah[4096];
  __shared__ __align__(16) unsigned short Al[4096];
  __shared__ __align__(16) unsigned short W0h[4096];
  __shared__ __align__(16) unsigned short W0l[4096];
  __shared__ __align__(16) unsigned short W1h[4096];
  __shared__ __align__(16) unsigned short W1l[4096];
  int mb = blockIdx.x, nb = blockIdx.y;
  int tid = threadIdx.x, w = tid>>6, l = tid&63, lm = l&15, qd = l>>4;
  int rh = w&1, tile = w>>1;
  int cbase = nb*128 + tile*64;
  f32x4 acc[2][4];
  #pragma unroll
  for (int mt=0;mt<2;++mt)
    #pragma unroll
    for (int nt=0;nt<4;++nt) acc[mt][nt] = (f32x4){0.f,0.f,0.f,0.f};
  int r0 = mb & 7;
  for (int t=0; t<8; ++t){
    int kc8 = (t + r0) & 7;
    __syncthreads();
    {
      const unsigned short* aSh = ohh  + ((size_t)(mb*8+kc8))*4096;
      const unsigned short* aSl = ohl  + ((size_t)(mb*8+kc8))*4096;
      const unsigned short* s0h = Woth + ((size_t)((nb*2  )*8+kc8))*4096;
      const unsigned short* s0l = Wotl + ((size_t)((nb*2  )*8+kc8))*4096;
      const unsigned short* s1h = Woth + ((size_t)((nb*2+1)*8+kc8))*4096;
      const unsigned short* s1l = Wotl + ((size_t)((nb*2+1)*8+kc8))*4096;
      if (w==0){
        #pragma unroll
        for (int j=0;j<8;++j) dma16(aSh + j*512 + l*8, &Ah[j*512]);
        #pragma unroll
        for (int j=0;j<4;++j) dma16(s1h + j*512 + l*8, &W1h[j*512]);
      } else if (w==1){
        #pragma unroll
        for (int j=0;j<8;++j) dma16(aSl + j*512 + l*8, &Al[j*512]);
        #pragma unroll
        for (int j=4;j<8;++j) dma16(s1h + j*512 + l*8, &W1h[j*512]);
      } else if (w==2){
        #pragma unroll
        for (int j=0;j<8;++j) dma16(s0h + j*512 + l*8, &W0h[j*512]);
        #pragma unroll
        for (int j=0;j<4;++j) dma16(s1l + j*512 + l*8, &W1l[j*512]);
      } else {
        #pragma unroll
        for (int j=0;j<8;++j) dma16(s0l + j*512 + l*8, &W0l[j*512]);
        #pragma unroll
        for (int j=4;j<8;++j) dma16(s1l + j*512 + l*8, &W1l[j*512]);
      }
    }
    __syncthreads();
    const unsigned short* Wh_ = tile ? W1h : W0h;
    const unsigned short* Wl_ = tile ? W1l : W0l;
    #pragma unroll
    for (int kch=0; kch<2; ++kch){
      short8 a_h[2], a_l[2];
      #pragma unroll
      for (int mt=0;mt<2;++mt){
        int off = ((kch*4+qd)*64 + rh*32 + mt*16 + lm)*8;
        a_h[mt] = *(const short8*)(Ah + off);
        a_l[mt] = *(const short8*)(Al + off);
      }
      #pragma unroll
      for (int nt=0;nt<4;++nt){
        int off = ((kch*4+qd)*64 + nt*16+lm)*8;
        short8 bh = *(const short8*)(Wh_ + off);
        short8 bl = *(const short8*)(Wl_ + off);
        #pragma unroll
        for (int mt=0;mt<2;++mt){
          acc[mt][nt] = mfma16(a_h[mt], bh, acc[mt][nt]);
          acc[mt][nt] = mfma16(a_h[mt], bl, acc[mt][nt]);
          acc[mt][nt] = mfma16(a_l[mt], bh, acc[mt][nt]);
        }
      }
    }
  }
  float bv[4];
  #pragma unroll
  for (int nt=0;nt<4;++nt) bv[nt] = bias[cbase+nt*16+lm];
  #pragma unroll
  for (int mt=0;mt<2;++mt){
    #pragma unroll
    for (int i=0;i<4;++i){
      int row = mb*64 + rh*32 + mt*16 + qd*4 + i;
      #pragma unroll
      for (int nt=0;nt<4;++nt){
        out[(size_t)row*DIMX + cbase + nt*16 + lm] = acc[mt][nt][i] + bv[nt];
      }
    }
  }
}

// ----------------------------------------------------------------- launch

extern "C" void kernel_launch(void* const* d_in, const int* in_sizes, int n_in,
                              void* d_out, int out_size, void* d_ws, size_t ws_size,
                              hipStream_t stream) {
  (void)in_sizes; (void)n_in; (void)out_size;
  const float* q     = (const float*)d_in[0];
  const float* k     = (const float*)d_in[1];
  const float* v     = (const float*)d_in[2];
  const float* ln_g  = (const float*)d_in[3];
  const float* ln_b  = (const float*)d_in[4];
  const float* W_in  = (const float*)d_in[5];
  const float* wp_W1 = (const float*)d_in[6];
  const float* wp_b1 = (const float*)d_in[7];
  const float* wp_lg = (const float*)d_in[8];
  const float* wp_lb = (const float*)d_in[9];
  const float* wp_W2 = (const float*)d_in[10];
  const float* wp_b2 = (const float*)d_in[11];
  const float* wp_W3 = (const float*)d_in[12];
  const float* wp_b3 = (const float*)d_in[13];
  const float* wtemp = (const float*)d_in[14];
  const float* W_out = (const float*)d_in[15];
  const float* b_out = (const float*)d_in[16];
  float* out = (float*)d_out;

  char* wsb = (char*)d_ws;
  double* gacc = (double*)wsb;            // 24 doubles
  double* racc = gacc + 24;               // 48
  double* qgs  = racc + 48;               // 512
  double* nusum= qgs + 512;               // 2048  (doubles end @ 21056 B)
  unsigned* ctr = (unsigned*)(wsb + 21056);   // zeroed each launch by k_pre
  float* coefG  = (float*)(wsb + 21120);      // 24 floats, inside zeroed zone
  float* fvA = (float*)(wsb + 24576);     // 8 MB; reused as ohh/ohl after k_mid
  unsigned short* ohh = (unsigned short*)fvA;                   // 4 MB
  unsigned short* ohl = ohh + (size_t)NQB*NTOK*NH*DH;           // 4 MB
  float* mu_rstd = fvA + (size_t)NPAIR*NTOK*DH;   // 24576
  float* Sarr = mu_rstd + 24576;          // 64 (padded)
  float* inv_na_q = Sarr + 64;
  float* muqA     = inv_na_q + NROWS;
  float* tqA      = muqA + NROWS;
  float* inv_na_k = tqA + NROWS;
  float* skA      = inv_na_k + NROWS;
  float* var_row  = skA + NROWS;
  float* mxcos    = var_row + NROWS;
  float* mxcov    = mxcos + NROWS;
  float* wp_out   = mxcov + NROWS;        // 32 (padded)
  float* endf     = wp_out + 32;
  size_t off16 = (size_t)((char*)endf - wsb);
  off16 = (off16 + 63) & ~(size_t)63;
  unsigned short* fqh  = (unsigned short*)(wsb + off16);
  unsigned short* fql  = fqh  + (size_t)NPAIR*NTOK*DH;
  unsigned short* fkh  = fql  + (size_t)NPAIR*NTOK*DH;
  unsigned short* fkl  = fkh  + (size_t)NPAIR*NTOK*DH;
  unsigned short* fvTh = fkl  + (size_t)NPAIR*NTOK*DH;
  unsigned short* fvTl = fvTh + (size_t)NPAIR*NTOK*DH;
  unsigned short* Wth  = fvTl + (size_t)NPAIR*NTOK*DH;
  unsigned short* Wtl  = Wth  + (size_t)DIMX*DIMX;
  unsigned short* Woth = Wtl  + (size_t)DIMX*DIMX;
  unsigned short* Wotl = Woth + (size_t)DIMX*DIMX;
  size_t need = (size_t)((char*)(Wotl + (size_t)DIMX*DIMX) - wsb);
  if (ws_size < need) return;  // fail cleanly rather than corrupt

  k_pre<<<3201, 256, 0, stream>>>(q, k, v, mu_rstd, W_in, W_out,
                                  Wth, Wtl, Woth, Wotl, (float*)wsb);
  k_projmm<<<dim3(64,4,3), 256, 0, stream>>>(q, k, v, ln_g, ln_b, Wth, Wtl,
                                             mu_rstd, fqh, fql, fkh, fkl, fvA,
                                             qgs, nusum);
  k_mid<<<8705, 256, 0, stream>>>(fvA, fvTh, fvTl, fqh, fql, fkh, fkl, nusum,
                                  inv_na_q, muqA, tqA, inv_na_k, skA,
                                  qgs, wp_W1, wp_b1, wp_lg, wp_lb,
                                  wp_W2, wp_b2, wp_W3, wp_b3, wtemp,
                                  wp_out, Sarr);
  k_passA<<<1024, 256, 0, stream>>>(fqh, fql, fkh, fkl,
                                    inv_na_q, muqA, tqA, inv_na_k, skA, Sarr,
                                    var_row, mxcos, mxcov, gacc, racc,
                                    wp_out, coefG, ctr);
  k_pv<<<1024, 256, 0, stream>>>(fqh, fql, fkh, fkl, fvTh, fvTl,
                                 inv_na_q, muqA, tqA, inv_na_k, skA, Sarr,
                                 var_row, mxcos, mxcov, coefG,
                                 ohh, ohl);
  k_outmm<<<dim3(64,4), 256, 0, stream>>>(ohh, ohl, Woth, Wotl, b_out, out);
}

// Round 9
// 253.833 us; speedup vs baseline: 1.0378x; 1.0378x over previous
//
#include <hip/hip_runtime.h>
#include <math.h>

#define NH    8
#define NQB   4
#define NPAIR 32
#define NTOK  1024
#define DH    64
#define DIMX  512
#define NROWS (NPAIR*NTOK)

typedef __attribute__((ext_vector_type(8))) short short8;
typedef _Float16 half8 __attribute__((ext_vector_type(8)));
typedef __attribute__((ext_vector_type(4))) float f32x4;

__device__ __forceinline__ unsigned short f2bf(float x){
  unsigned u = __float_as_uint(x);
  u += 0x7fffu + ((u>>16)&1u);
  return (unsigned short)(u>>16);
}
__device__ __forceinline__ float bf2f(unsigned short h){
  return __uint_as_float(((unsigned)h)<<16);
}
__device__ __forceinline__ unsigned short f2h(float x){
  union{ _Float16 f; unsigned short u; } c; c.f = (_Float16)x; return c.u;
}
__device__ __forceinline__ float h2f(unsigned short u){
  union{ _Float16 f; unsigned short u; } c; c.u = u; return (float)c.f;
}
__device__ __forceinline__ f32x4 mfma16(short8 a, short8 b, f32x4 c){
  return __builtin_amdgcn_mfma_f32_16x16x32_bf16(a,b,c,0,0,0);
}
__device__ __forceinline__ f32x4 mfma16f(half8 a, half8 b, f32x4 c){
  return __builtin_amdgcn_mfma_f32_16x16x32_f16(a,b,c,0,0,0);
}
// async global->LDS DMA, 16B per lane; LDS dest = base + lane*16
__device__ __forceinline__ void dma16(const void* g, void* l){
  __builtin_amdgcn_global_load_lds(
      (const __attribute__((address_space(1))) void*)g,
      (__attribute__((address_space(3))) void*)l, 16, 0, 0);
}

// chunk layout for 512-col matrices: [rowgrp64][colgrp64][cq8][row64][8]
__device__ __forceinline__ size_t cidx(int r, int c){
  return ((((size_t)((r>>6)*8 + (c>>6)))*8 + ((c&63)>>3))*64 + (r&63))*8 + (c&7);
}
// K layout: FK[p][kc][dq][k64][8]
__device__ __forceinline__ size_t kidx(int p, int key, int dh){
  return ((((size_t)(p*16 + (key>>6)))*8 + (dh>>3))*64 + (key&63))*8 + (dh&7);
}

// ---------------- fused prelude: LN stats | W split | accumulator zeroing

__global__ __launch_bounds__(256) void k_pre(
    const float* __restrict__ q, const float* __restrict__ k, const float* __restrict__ v,
    float* __restrict__ mu_rstd,
    const float* __restrict__ Wa, const float* __restrict__ Wb,
    unsigned short* __restrict__ Wth, unsigned short* __restrict__ Wtl,
    unsigned short* __restrict__ Woth, unsigned short* __restrict__ Wotl,
    float* __restrict__ zacc){
  __shared__ float tile[64][65];
  int b = blockIdx.x, tid = threadIdx.x;
  if (b < 3072){
    int wid = tid >> 6, lane = tid & 63;
    int tok = b*4 + wid;                   // 0..12287
    const float* src = (tok < 4096) ? q : ((tok < 8192) ? k : v);
    int t = tok & 4095;
    const float4* p4 = (const float4*)(src + (size_t)t*DIMX) + lane*2;
    float4 a = p4[0], bb = p4[1];
    float s  = a.x+a.y+a.z+a.w + bb.x+bb.y+bb.z+bb.w;
    float ss = a.x*a.x+a.y*a.y+a.z*a.z+a.w*a.w
             + bb.x*bb.x+bb.y*bb.y+bb.z*bb.z+bb.w*bb.w;
    #pragma unroll
    for (int off=32; off; off>>=1){ s += __shfl_down(s,off); ss += __shfl_down(ss,off); }
    if (lane==0){
      float mu = s*(1.0f/512.0f);
      float var = ss*(1.0f/512.0f) - mu*mu;
      mu_rstd[tok*2+0] = mu;
      mu_rstd[tok*2+1] = 1.0f/sqrtf(var + 1e-5f);
    }
  } else if (b < 3200){
    int sb = b - 3072;
    int z = sb >> 6, rem = sb & 63, kb = rem & 7, nb = rem >> 3;
    const float* W = z ? Wb : Wa;
    unsigned short* oh_ = z ? Woth : Wth;
    unsigned short* ol_ = z ? Wotl : Wtl;
    #pragma unroll
    for (int it=0; it<4; ++it){
      int idx = tid + 256*it;          // 0..1023
      int kr = idx>>4, c4 = idx&15;
      float4 vv = *(const float4*)(W + (size_t)(kb*64+kr)*DIMX + nb*64 + c4*4);
      tile[c4*4+0][kr]=vv.x; tile[c4*4+1][kr]=vv.y; tile[c4*4+2][kr]=vv.z; tile[c4*4+3][kr]=vv.w;
    }
    __syncthreads();
    #pragma unroll
    for (int it=0; it<4; ++it){
      int idx = tid + 256*it;
      int n = idx>>4, k4 = idx&15;
      size_t base = cidx(nb*64+n, kb*64+k4*4);
      ushort4 hv, lv;
      { float xx=tile[n][k4*4+0]; unsigned short hh=f2bf(xx); hv.x=hh; lv.x=f2bf(xx-bf2f(hh)); }
      { float xx=tile[n][k4*4+1]; unsigned short hh=f2bf(xx); hv.y=hh; lv.y=f2bf(xx-bf2f(hh)); }
      { float xx=tile[n][k4*4+2]; unsigned short hh=f2bf(xx); hv.z=hh; lv.z=f2bf(xx-bf2f(hh)); }
      { float xx=tile[n][k4*4+3]; unsigned short hh=f2bf(xx); hv.w=hh; lv.w=f2bf(xx-bf2f(hh)); }
      *(ushort4*)(oh_+base) = hv;
      *(ushort4*)(ol_+base) = lv;
    }
  } else {
    // zero 24576 B of accumulators (gacc/racc/qgs/nusum/coefG)
    uint4 z4 = {0u,0u,0u,0u};
    uint4* dst = (uint4*)zacc;
    #pragma unroll
    for (int i=0;i<6;++i) dst[tid + 256*i] = z4;
  }
}

// --------------- LN + projection GEMM via split-bf16 MFMA (q, k, v by z)

__global__ __launch_bounds__(256) void k_projmm(
    const float* __restrict__ q, const float* __restrict__ k, const float* __restrict__ v,
    const float* __restrict__ g, const float* __restrict__ bln,
    const unsigned short* __restrict__ Wth, const unsigned short* __restrict__ Wtl,
    const float* __restrict__ mu_rstd,
    unsigned short* __restrict__ fqh, unsigned short* __restrict__ fql,
    unsigned short* __restrict__ fkh, unsigned short* __restrict__ fkl,
    float* __restrict__ fv,
    double* __restrict__ qgs, double* __restrict__ nusum){
  __shared__ __align__(16) unsigned short Ahs[64*72];
  __shared__ __align__(16) unsigned short Als[64*72];
  __shared__ __align__(16) unsigned short WhL[2][4096];
  __shared__ __align__(16) unsigned short WlL[2][4096];
  __shared__ float scrc[4][128];
  int z = blockIdx.z;
  const float* x = (z==0) ? q : ((z==1) ? k : v);
  int mb = blockIdx.x, nb = blockIdx.y;
  int tid = threadIdx.x, w = tid>>6, l = tid&63, lm = l&15, qd = l>>4;
  int rbase = (w&1)*32;
  int tile = w>>1;
  int cbase = nb*128 + tile*64;
  scrc[tid>>7][tid&127] = 0.f;
  scrc[2+(tid>>7)][tid&127] = 0.f;
  f32x4 acc[2][4];
  #pragma unroll
  for (int mt=0;mt<2;++mt)
    #pragma unroll
    for (int nt=0;nt<4;++nt) acc[mt][nt] = (f32x4){0.f,0.f,0.f,0.f};
  int r0 = mb & 7;
  for (int t = 0; t < 8; ++t){
    int kc8 = (t + r0) & 7;
    float4 xv[4]; float mus[4], rss[4]; float4 gv[4], bv[4]; int rr[4], kk4[4];
    #pragma unroll
    for (int it=0; it<4; ++it){
      int idx = tid + 256*it;          // 0..1023
      int r = idx>>4, k4 = idx&15;
      rr[it]=r; kk4[it]=k4;
      int tokg = z*4096 + mb*64 + r;
      mus[it] = mu_rstd[tokg*2+0]; rss[it] = mu_rstd[tokg*2+1];
      xv[it] = *(const float4*)(x + (size_t)(mb*64+r)*DIMX + kc8*64 + k4*4);
      gv[it] = *(const float4*)(g   + kc8*64 + k4*4);
      bv[it] = *(const float4*)(bln + kc8*64 + k4*4);
    }
    __syncthreads();                   // prev chunk consumed
    {  // wave w stages W chunk: tile w>>1, hi/lo w&1
      int st = w>>1, hl = w&1;
      const unsigned short* src = (hl ? Wtl : Wth)
          + ((size_t)((nb*2+st)*8 + kc8))*4096;
      unsigned short* dst = hl ? WlL[st] : WhL[st];
      #pragma unroll
      for (int j=0;j<8;++j) dma16(src + j*512 + l*8, dst + j*512);
    }
    #pragma unroll
    for (int it=0; it<4; ++it){
      float y0 = (xv[it].x-mus[it])*rss[it]*gv[it].x + bv[it].x;
      float y1 = (xv[it].y-mus[it])*rss[it]*gv[it].y + bv[it].y;
      float y2 = (xv[it].z-mus[it])*rss[it]*gv[it].z + bv[it].z;
      float y3 = (xv[it].w-mus[it])*rss[it]*gv[it].w + bv[it].w;
      ushort4 hv, lv;
      { unsigned short hh=f2bf(y0); hv.x=hh; lv.x=f2bf(y0-bf2f(hh)); }
      { unsigned short hh=f2bf(y1); hv.y=hh; lv.y=f2bf(y1-bf2f(hh)); }
      { unsigned short hh=f2bf(y2); hv.z=hh; lv.z=f2bf(y2-bf2f(hh)); }
      { unsigned short hh=f2bf(y3); hv.w=hh; lv.w=f2bf(y3-bf2f(hh)); }
      *(ushort4*)(Ahs + rr[it]*72 + kk4[it]*4) = hv;
      *(ushort4*)(Als + rr[it]*72 + kk4[it]*4) = lv;
    }
    __syncthreads();                   // staging + DMA visible
    #pragma unroll
    for (int kch=0; kch<2; ++kch){
      short8 a_h[2], a_l[2];
      #pragma unroll
      for (int mt=0;mt<2;++mt){
        a_h[mt] = *(const short8*)(Ahs + (rbase+mt*16+lm)*72 + kch*32 + qd*8);
        a_l[mt] = *(const short8*)(Als + (rbase+mt*16+lm)*72 + kch*32 + qd*8);
      }
      #pragma unroll
      for (int nt=0;nt<4;++nt){
        int off = ((kch*4+qd)*64 + nt*16+lm)*8;
        short8 bh = *(const short8*)(WhL[tile] + off);
        short8 bl = *(const short8*)(WlL[tile] + off);
        #pragma unroll
        for (int mt=0;mt<2;++mt){
          acc[mt][nt] = mfma16(a_h[mt], bh, acc[mt][nt]);
          acc[mt][nt] = mfma16(a_h[mt], bl, acc[mt][nt]);
          acc[mt][nt] = mfma16(a_l[mt], bh, acc[mt][nt]);
        }
      }
    }
  }
  int head = cbase >> 6;
  if (z < 2){
    float csum[4] = {0.f,0.f,0.f,0.f};
    #pragma unroll
    for (int mt=0;mt<2;++mt){
      #pragma unroll
      for (int nt=0;nt<4;++nt){
        #pragma unroll
        for (int i=0;i<4;++i){
          float val = acc[mt][nt][i];
          csum[nt] += val;
          int tglob = mb*64 + rbase + mt*16 + qd*4 + i;
          int qb = tglob>>10, n = tglob&1023;
          int p = head*4 + qb;
          int d = nt*16 + lm;
          unsigned short hh = f2bf(val);
          unsigned short ll = f2bf(val - bf2f(hh));
          if (z==0){
            size_t ix = ((size_t)(p*NTOK+n))*DH + d;
            fqh[ix] = hh; fql[ix] = ll;
          } else {
            size_t ix = kidx(p, n, d);
            fkh[ix] = hh; fkl[ix] = ll;
          }
        }
      }
    }
    #pragma unroll
    for (int m=16;m<64;m<<=1){
      #pragma unroll
      for (int nt=0;nt<4;++nt) csum[nt] += __shfl_xor(csum[nt], m);
    }
    if (qd==0){
      #pragma unroll
      for (int nt=0;nt<4;++nt) scrc[w][tile*64 + nt*16 + lm] = csum[nt];
    }
    __syncthreads();
    if (tid < 128){
      float s = scrc[0][tid]+scrc[1][tid]+scrc[2][tid]+scrc[3][tid];
      if (z==0){
        atomicAdd(&qgs[nb*128 + tid], (double)s);
      } else {
        int col = nb*128 + tid;
        int hh2 = col>>6, d = col&63;
        int qb = mb>>4;
        atomicAdd(&nusum[(size_t)(hh2*4+qb)*DH + d], (double)s);
      }
    }
  } else {
    #pragma unroll
    for (int mt=0;mt<2;++mt){
      #pragma unroll
      for (int nt=0;nt<4;++nt){
        #pragma unroll
        for (int i=0;i<4;++i){
          int tglob = mb*64 + rbase + mt*16 + qd*4 + i;
          int qb = tglob>>10, n = tglob&1023;
          int p = head*4 + qb;
          int d = nt*16 + lm;
          fv[((size_t)(p*NTOK+n))*DH + d] = acc[mt][nt][i];
        }
      }
    }
  }
}

// ------- fused mid pass: fv transpose | per-row scalars | weight predictor

__global__ __launch_bounds__(256) void k_mid(
    const float* __restrict__ fv,
    unsigned short* __restrict__ fvTh, unsigned short* __restrict__ fvTl,
    const unsigned short* __restrict__ fqh, const unsigned short* __restrict__ fql,
    const unsigned short* __restrict__ fkh, const unsigned short* __restrict__ fkl,
    const double* __restrict__ nusum,
    float* __restrict__ inv_na_q, float* __restrict__ muqA, float* __restrict__ tqA,
    float* __restrict__ inv_na_k, float* __restrict__ skA,
    const double* __restrict__ qgs,
    const float* __restrict__ W1, const float* __restrict__ b1,
    const float* __restrict__ lgv, const float* __restrict__ lbv,
    const float* __restrict__ W2, const float* __restrict__ b2,
    const float* __restrict__ W3, const float* __restrict__ b3,
    const float* __restrict__ wtemp, float* __restrict__ wp_out,
    float* __restrict__ Sarr){
  __shared__ __align__(16) float msm[64*65];
  int b = blockIdx.x, tid = threadIdx.x;
  if (b < 512){
    float (*tile)[65] = (float(*)[65])msm;
    int mc = b & 15, p = b >> 4;
    #pragma unroll
    for (int it=0; it<4; ++it){
      int idx = tid + 256*it;
      int m = idx>>4, d4 = idx&15;
      float4 vv = *(const float4*)(fv + ((size_t)(p*NTOK + mc*64 + m)*DH + d4*4));
      tile[d4*4+0][m]=vv.x; tile[d4*4+1][m]=vv.y; tile[d4*4+2][m]=vv.z; tile[d4*4+3][m]=vv.w;
    }
    __syncthreads();
    #pragma unroll
    for (int it=0; it<2; ++it){
      int idx = tid + 256*it;       // 0..511
      int d = idx>>3, seg = idx&7;  // keys seg*8..seg*8+8
      size_t base = ((((size_t)(p*16+mc))*8 + seg)*64 + d)*8;
      ushort4 h0,h1v,l0,l1;
      { float xx=tile[d][seg*8+0]; unsigned short hh=f2h(xx); h0.x=hh; l0.x=f2h(xx-h2f(hh)); }
      { float xx=tile[d][seg*8+1]; unsigned short hh=f2h(xx); h0.y=hh; l0.y=f2h(xx-h2f(hh)); }
      { float xx=tile[d][seg*8+2]; unsigned short hh=f2h(xx); h0.z=hh; l0.z=f2h(xx-h2f(hh)); }
      { float xx=tile[d][seg*8+3]; unsigned short hh=f2h(xx); h0.w=hh; l0.w=f2h(xx-h2f(hh)); }
      { float xx=tile[d][seg*8+4]; unsigned short hh=f2h(xx); h1v.x=hh; l1.x=f2h(xx-h2f(hh)); }
      { float xx=tile[d][seg*8+5]; unsigned short hh=f2h(xx); h1v.y=hh; l1.y=f2h(xx-h2f(hh)); }
      { float xx=tile[d][seg*8+6]; unsigned short hh=f2h(xx); h1v.z=hh; l1.z=f2h(xx-h2f(hh)); }
      { float xx=tile[d][seg*8+7]; unsigned short hh=f2h(xx); h1v.w=hh; l1.w=f2h(xx-h2f(hh)); }
      *(ushort4*)(fvTh+base)   = h0;
      *(ushort4*)(fvTh+base+4) = h1v;
      *(ushort4*)(fvTl+base)   = l0;
      *(ushort4*)(fvTl+base+4) = l1;
    }
  } else if (b < 8704){
    int rb = b - 512;
    int wid = tid >> 6, lane = tid & 63;
    int row = rb*4 + wid;            // < 32768
    int p = row >> 10;
    int key = row & 1023;
    size_t ix = (size_t)row*DH + lane;
    float xq = bf2f(fqh[ix]) + bf2f(fql[ix]);
    float nv = (float)(nusum[(size_t)p*DH + lane] * (1.0/1024.0));
    float s = xq, ss = xq*xq, sd = xq*nv;
    #pragma unroll
    for (int off=32; off; off>>=1){
      s += __shfl_down(s,off); ss += __shfl_down(ss,off); sd += __shfl_down(sd,off);
    }
    if (lane==0){
      float nrm = sqrtf(ss);
      inv_na_q[row] = 1.0f/(nrm+1e-8f);
      muqA[row] = s*(1.0f/64.0f);
      tqA[row] = sd;
    }
    size_t ixk = kidx(p, key, lane);
    float xk = bf2f(fkh[ixk]) + bf2f(fkl[ixk]);
    float s2 = xk, ss2 = xk*xk;
    #pragma unroll
    for (int off=32; off; off>>=1){
      s2 += __shfl_down(s2,off); ss2 += __shfl_down(ss2,off);
    }
    if (lane==0){
      float nrm = sqrtf(ss2);
      inv_na_k[row] = 1.0f/(nrm+1e-8f);
      skA[row] = s2;
    }
  } else {
    // weight predictor + Sarr (single block)
    float* feats = msm;           // 8*128
    float* h1    = msm + 1024;    // 8*64
    float* h2s   = msm + 1536;    // 8*32
    float* lgt   = msm + 1792;    // 8*3 (stride 3)
    float* mv    = msm + 1832;    // 8*2
    for (int idx = tid; idx < 1024; idx += 256){
      int h = idx >> 7, i = idx & 127;
      double vv;
      if (i < 64){
        vv = qgs[h*64+i];
      } else {
        int d = i - 64;
        vv = nusum[(size_t)(h*4+0)*DH+d] + nusum[(size_t)(h*4+1)*DH+d]
           + nusum[(size_t)(h*4+2)*DH+d] + nusum[(size_t)(h*4+3)*DH+d];
      }
      feats[h*128+i] = (float)(vv * (1.0/4096.0));
    }
    if (tid < 32){
      double s = 0.0;
      for (int d = 0; d < 64; ++d) s += nusum[(size_t)tid*DH + d];
      Sarr[tid] = (float)(s * (1.0/1024.0));
    }
    __syncthreads();
    for (int idx = tid; idx < 512; idx += 256){
      int h = idx >> 6, j = idx & 63;
      float s = b1[j];
      for (int i = 0; i < 128; ++i) s += feats[h*128+i]*W1[i*64+j];
      h1[h*64+j] = s;
    }
    __syncthreads();
    if (tid < 8){
      float s=0.f, ss=0.f;
      for (int j=0;j<64;++j){ float vv=h1[tid*64+j]; s+=vv; ss+=vv*vv; }
      float mu = s*(1.0f/64.0f);
      float var = ss*(1.0f/64.0f)-mu*mu;
      mv[tid*2+0]=mu; mv[tid*2+1]=1.0f/sqrtf(var+1e-5f);
    }
    __syncthreads();
    for (int idx = tid; idx < 512; idx += 256){
      int h = idx>>6, j = idx&63;
      float vv = (h1[h*64+j]-mv[h*2+0])*mv[h*2+1]*lgv[j] + lbv[j];
      h1[h*64+j] = fmaxf(vv, 0.f);
    }
    __syncthreads();
    {
      int h = tid >> 5, j = tid & 31;
      float s = b2[j];
      for (int i=0;i<64;++i) s += h1[h*64+i]*W2[i*32+j];
      h2s[h*32+j] = fmaxf(s, 0.f);
    }
    __syncthreads();
    if (tid < 24){
      int h = tid/3, j = tid - h*3;
      float s = b3[j];
      for (int i=0;i<32;++i) s += h2s[h*32+i]*W3[i*3+j];
      lgt[h*3+j] = s;
    }
    __syncthreads();
    if (tid < 8){
      int h = tid;
      float z0=lgt[h*3+0], z1=lgt[h*3+1], z2=lgt[h*3+2];
      float m = fmaxf(z0,fmaxf(z1,z2));
      float e0=expf(z0-m), e1=expf(z1-m), e2=expf(z2-m);
      float inv = 1.0f/(e0+e1+e2);
      float l0=e0*inv, l1=e1*inv, l2=e2*inv;
      float wt = fminf(fmaxf(wtemp[0], 0.1f), 20.0f);
      float y0=l0/wt, y1=l1/wt, y2=l2/wt;
      float m2 = fmaxf(y0,fmaxf(y1,y2));
      float f0=expf(y0-m2), f1=expf(y1-m2), f2=expf(y2-m2);
      float inv2 = 1.0f/(f0+f1+f2);
      float w0=f0*inv2, w1=f1*inv2, w2=f2*inv2;
      w0 = fminf(fmaxf(w0,0.05f),0.8f);
      w1 = fminf(fmaxf(w1,0.05f),0.8f);
      w2 = fminf(fmaxf(w2,0.05f),0.8f);
      float isum = 1.0f/(w0+w1+w2);
      wp_out[h*3+0]=w0*isum; wp_out[h*3+1]=w1*isum; wp_out[h*3+2]=w2*isum;
    }
  }
}

// ------------- pass A (MFMA): KA/KB register prefetch; row-finish fused.
// coef is computed by the standalone k_final (keeps this kernel's VGPR low).

__global__ __launch_bounds__(256) void k_passA(
    const unsigned short* __restrict__ fqh, const unsigned short* __restrict__ fql,
    const unsigned short* __restrict__ fkh, const unsigned short* __restrict__ fkl,
    const float* __restrict__ inv_na_q, const float* __restrict__ muqA,
    const float* __restrict__ tqA,
    const float* __restrict__ inv_na_k, const float* __restrict__ skA,
    const float* __restrict__ Sarr,
    float* __restrict__ var_row,
    float* __restrict__ mxcosA, float* __restrict__ mxcovA,
    double* __restrict__ gacc, double* __restrict__ racc){
  __shared__ float redbuf[4][16][5];
  __shared__ double wredS[4][3];
  int b = blockIdx.x;
  int p = ((b&7)<<2) | ((b>>3)&3);   // XCD swizzle
  int s = b>>5;                      // 0..31
  int n0 = s*32;
  int tid = threadIdx.x, w = tid>>6, l = tid&63;
  int lm = l&15, q = l>>4;
  int rt = w&1, cw = w>>1;
  int nw = n0 + rt*16;
  float Sp = Sarr[p];
  const float inv8 = (float)(1.0/(8.0+1e-6));
  float ia[4], m8[4], t8[4];
  #pragma unroll
  for (int i=0;i<4;++i){
    int rg = p*NTOK + nw + q*4 + i;
    float mq = muqA[rg];
    ia[i] = inv_na_q[rg];
    m8[i] = mq*inv8;
    t8[i] = (tqA[rg] - mq*Sp)*inv8;
  }
  const short8* aqh = (const short8*)(fqh + (size_t)(p*NTOK + nw + lm)*DH);
  const short8* aql = (const short8*)(fql + (size_t)(p*NTOK + nw + lm)*DH);
  short8 ah0 = aqh[q], ah1 = aqh[4+q], al0 = aql[q], al1 = aql[4+q];
  const unsigned short* gKh = fkh + (size_t)p*16*4096;
  const unsigned short* gKl = fkl + (size_t)p*16*4096;
  const float* cAg = inv_na_k + p*NTOK;
  const float* cSg = skA + p*NTOK;
  float sc2=0.f, sv2=0.f, scv=0.f;
  float pc[4]={0,0,0,0}, pv_[4]={0,0,0,0}, pm[4]={0,0,0,0};
  float xc[4], xv[4];
  #pragma unroll
  for (int i=0;i<4;++i){ xc[i]=-1e30f; xv[i]=-1e30f; }
  int ko0 = ((q  )*64 + (cw*2)*16+lm)*8;
  int ko1 = ((q+4)*64 + (cw*2)*16+lm)*8;
  int c0 = s & 15;                   // rotation offset

#define PA_LOAD(K, cc_) do{ \
    const unsigned short* cbh_ = gKh + (size_t)(cc_)*4096; \
    const unsigned short* cbl_ = gKl + (size_t)(cc_)*4096; \
    K[0] = *(const short8*)(cbh_ + ko0); \
    K[1] = *(const short8*)(cbh_ + ko1); \
    K[2] = *(const short8*)(cbl_ + ko0); \
    K[3] = *(const short8*)(cbl_ + ko1); \
    K[4] = *(const short8*)(cbh_ + ko0 + 128); \
    K[5] = *(const short8*)(cbh_ + ko1 + 128); \
    K[6] = *(const short8*)(cbl_ + ko0 + 128); \
    K[7] = *(const short8*)(cbl_ + ko1 + 128); \
  }while(0)

#define PA_COMP(K, cc_) do{ \
    _Pragma("unroll") \
    for (int t2=0; t2<2; ++t2){ \
      int c16 = cw*2 + t2; \
      f32x4 acc = {0.f,0.f,0.f,0.f}; \
      acc = mfma16(ah0,K[t2*4+0],acc); acc = mfma16(ah1,K[t2*4+1],acc); \
      acc = mfma16(al0,K[t2*4+0],acc); acc = mfma16(al1,K[t2*4+1],acc); \
      acc = mfma16(ah0,K[t2*4+2],acc); acc = mfma16(ah1,K[t2*4+3],acc); \
      int colg = (cc_)*64 + c16*16 + lm; \
      float ca = cAg[colg], cs = cSg[colg]; \
      _Pragma("unroll") \
      for (int i=0;i<4;++i){ \
        float dot = acc[i]; \
        float cosv = fminf(fmaxf(dot*ia[i]*ca,-0.99f),0.99f); \
        float cov  = fmaf(-m8[i], cs, fmaf(dot, inv8, -t8[i])); \
        float marg = fmaxf(0.01f - cosv, 0.f); \
        sc2 = fmaf(cosv,cosv,sc2); sv2 = fmaf(cov,cov,sv2); scv = fmaf(cosv,cov,scv); \
        pc[i]+=cosv; pv_[i]+=cov; pm[i]+=marg; \
        xc[i]=fmaxf(xc[i],cosv); \
        xv[i]=fmaxf(xv[i],cov); \
      } \
    } \
  }while(0)

  short8 KA[8], KB[8];
  PA_LOAD(KA, c0);
  for (int t = 0; t < 16; t += 2){
    int ccA = (t + c0) & 15;
    int ccB = (t + 1 + c0) & 15;
    PA_LOAD(KB, ccB);
    PA_COMP(KA, ccA);
    if (t < 14){
      int ccA2 = (t + 2 + c0) & 15;
      PA_LOAD(KA, ccA2);
    }
    PA_COMP(KB, ccB);
  }
#undef PA_LOAD
#undef PA_COMP

  #pragma unroll
  for (int m=1;m<16;m<<=1){
    #pragma unroll
    for (int i=0;i<4;++i){
      pc[i]+=__shfl_xor(pc[i],m); pv_[i]+=__shfl_xor(pv_[i],m); pm[i]+=__shfl_xor(pm[i],m);
      xc[i]=fmaxf(xc[i],__shfl_xor(xc[i],m));
      xv[i]=fmaxf(xv[i],__shfl_xor(xv[i],m));
    }
  }
  if (lm==0){
    #pragma unroll
    for (int i=0;i<4;++i){
      int r16 = q*4+i;
      redbuf[w][r16][0]=pc[i]; redbuf[w][r16][1]=pv_[i]; redbuf[w][r16][2]=pm[i];
      redbuf[w][r16][3]=xc[i]; redbuf[w][r16][4]=xv[i];
    }
  }
  double vals[3] = {(double)sc2,(double)sv2,(double)scv};
  #pragma unroll
  for (int c2=0;c2<3;++c2){
    double vv = vals[c2];
    #pragma unroll
    for (int off=32; off; off>>=1) vv += __shfl_down(vv, off);
    if (l==0) wredS[w][c2] = vv;
  }
  __syncthreads();
  if (tid < 32){
    int rt2 = tid>>4, r16 = tid&15;
    int w0 = rt2, w1 = rt2+2;
    float sc = redbuf[w0][r16][0]+redbuf[w1][r16][0];
    float sv = redbuf[w0][r16][1]+redbuf[w1][r16][1];
    float sm = redbuf[w0][r16][2]+redbuf[w1][r16][2];
    float mxc = fmaxf(redbuf[w0][r16][3],redbuf[w1][r16][3]);
    float mxv = fmaxf(redbuf[w0][r16][4],redbuf[w1][r16][4]);
    int row = p*NTOK + n0 + tid;
    float vr = sm * (1.0f/1024.0f);
    var_row[row] = vr;
    mxcosA[row] = mxc; mxcovA[row] = mxv;
    // fused row-finish: per-row moments -> racc
    double dv = (double)vr;
    double rc = (double)sc, rv = (double)sv;
    double vals2[6];
    vals2[0] = 1024.0*dv;
    vals2[1] = 1024.0*dv*dv;
    vals2[2] = dv*rc;
    vals2[3] = dv*rv;
    vals2[4] = rc;
    vals2[5] = rv;
    int hh = p >> 2;
    #pragma unroll
    for (int c2 = 0; c2 < 6; ++c2){
      double vv = vals2[c2];
      vv += __shfl_down(vv,16);
      vv += __shfl_down(vv,8);
      vv += __shfl_down(vv,4);
      vv += __shfl_down(vv,2);
      vv += __shfl_down(vv,1);
      if (tid==0) atomicAdd(&racc[hh*6+c2], vv);
    }
  }
  if (tid == 0){
    int h = p >> 2;
    #pragma unroll
    for (int c2=0;c2<3;++c2){
      double t = wredS[0][c2]+wredS[1][c2]+wredS[2][c2]+wredS[3][c2];
      atomicAdd(&gacc[h*3+c2], t);
    }
  }
}

// ------------------------------------- finalize scalars -> d2 coefficients

__global__ void k_final(const double* __restrict__ gacc, const double* __restrict__ racc,
                        const float* __restrict__ wp_out, float* __restrict__ coef){
  if (threadIdx.x != 0) return;
  const double N = 33554432.0;
  double Sc1=0,Sc2=0,Sv1=0,Sv2=0,Sr1=0,Sr2=0;
  for (int h=0;h<8;++h){
    Sc2+=gacc[h*3+0]; Sv2+=gacc[h*3+1];
    Sr1+=racc[h*6+0]; Sr2+=racc[h*6+1];
    Sc1+=racc[h*6+4]; Sv1+=racc[h*6+5];
  }
  double cvar = (Sc2 - Sc1*Sc1/N)/(N-1.0);
  double cn = sqrt(fmax(cvar,0.0)) + 1e-6;
  double cscale = (cn < 1e-4) ? 0.1 : 1.0;
  double vraw = (Sv2 - Sv1*Sv1/N)/(N-1.0);
  double sraw = sqrt(fmax(vraw,0.0));
  double basev = 0.001/1024.0;
  double regv = (sraw < 1e-6) ? basev*10.0 : basev;
  double covn = regv*sraw + 1e-6;
  double vvar = (Sr2 - Sr1*Sr1/N)/(N-1.0);
  double vn = sqrt(fmax(vvar,0.0)) + 1e-6;
  double ah[8], bh[8], chh[8];
  double Sd1=0.0, Sd2=0.0;
  for (int h=0;h<8;++h){
    double a = (double)wp_out[h*3+0]/cn*cscale;
    double b = (double)wp_out[h*3+1]*regv*0.5/covn;
    double c = (double)wp_out[h*3+2]*0.5/vn;
    ah[h]=a; bh[h]=b; chh[h]=c;
    Sd1 += a*racc[h*6+4] + b*racc[h*6+5] + c*racc[h*6+0];
    Sd2 += a*a*gacc[h*3+0] + b*b*gacc[h*3+1] + c*c*racc[h*6+1]
         + 2.0*(a*b*gacc[h*3+2] + a*c*racc[h*6+2] + b*c*racc[h*6+3]);
  }
  double dvar = (Sd2 - Sd1*Sd1/N)/(N-1.0);
  double dstd = sqrt(fmax(dvar,0.0));
  double temp = (dstd < 1e-6) ? 0.1 : 0.3 + dstd;
  double tcl = fmin(fmax(temp,0.1),5.0);
  double it = 1.0/tcl;
  for (int h=0;h<8;++h){
    coef[h*3+0] = (float)(ah[h]*it);
    coef[h*3+1] = (float)(bh[h]*it);
    coef[h*3+2] = (float)(chh[h]*it);
  }
}

// -------------------- pass C (MFMA): K/V direct from L2; P-transpose in
// LDS (double-buffered, stride 76 = conflict-free); coef precomputed.

__global__ __launch_bounds__(256) void k_pv(
    const unsigned short* __restrict__ fqh, const unsigned short* __restrict__ fql,
    const unsigned short* __restrict__ fkh, const unsigned short* __restrict__ fkl,
    const unsigned short* __restrict__ fvTh, const unsigned short* __restrict__ fvTl,
    const float* __restrict__ inv_na_q, const float* __restrict__ muqA,
    const float* __restrict__ tqA,
    const float* __restrict__ inv_na_k, const float* __restrict__ skA,
    const float* __restrict__ Sarr, const float* __restrict__ var_row,
    const float* __restrict__ mxcosA, const float* __restrict__ mxcovA,
    const float* __restrict__ coef,
    unsigned short* __restrict__ ohh, unsigned short* __restrict__ ohl){
  __shared__ __align__(16) unsigned short ph[2][32][76];
  __shared__ float denbuf[4][16];
  __shared__ float dnv[32];
  int b = blockIdx.x;
  int p = ((b&7)<<2) | ((b>>3)&3);   // XCD swizzle
  int s = b>>5;
  int n0 = s*32;
  int h = p>>2, qb = p&3;
  int tid = threadIdx.x, w = tid>>6, l = tid&63;
  int lm = l&15, q = l>>4;
  int rt = w&1, cw = w>>1;
  int nw = n0 + rt*16;
  float A = coef[h*3+0], B = coef[h*3+1], C = coef[h*3+2];
  float Sp = Sarr[p];
  const float inv8 = (float)(1.0/(8.0+1e-6));
  float B8 = B*inv8;
  float ia[4], bm[4], o2[4];
  #pragma unroll
  for (int i=0;i<4;++i){
    int rg = p*NTOK + nw + q*4 + i;
    float mq = muqA[rg];
    ia[i] = inv_na_q[rg];
    bm[i] = B8*mq;
    float tq2 = tqA[rg] - mq*Sp;
    float vr = var_row[rg];
    float Mh = A*mxcosA[rg] + B*mxcovA[rg] + C*vr;
    o2[i] = (C*vr - Mh) - B8*tq2;
  }
  const short8* aqh = (const short8*)(fqh + (size_t)(p*NTOK + nw + lm)*DH);
  const short8* aql = (const short8*)(fql + (size_t)(p*NTOK + nw + lm)*DH);
  short8 ah0 = aqh[q], ah1 = aqh[4+q], al0 = aql[q], al1 = aql[4+q];
  const unsigned short* gKh = fkh  + (size_t)p*16*4096;
  const unsigned short* gKl = fkl  + (size_t)p*16*4096;
  const unsigned short* gVh = fvTh + (size_t)p*16*4096;
  const unsigned short* gVl = fvTl + (size_t)p*16*4096;
  const float* cAg = inv_na_k + p*NTOK;
  const float* cSg = skA + p*NTOK;
  f32x4 o0 = {0.f,0.f,0.f,0.f}, o1 = {0.f,0.f,0.f,0.f};
  float den[4] = {0.f,0.f,0.f,0.f};
  int ko0 = ((q  )*64 + (cw*2)*16+lm)*8;
  int ko1 = ((q+4)*64 + (cw*2)*16+lm)*8;
  int vo0 = ((q  )*64 + w*16+lm)*8;
  int vo1 = ((q+4)*64 + w*16+lm)*8;
  int c0 = s & 15;                   // rotation offset

#define PV_KLOAD(K, cc_) do{ \
    const unsigned short* cbh_ = gKh + (size_t)(cc_)*4096; \
    const unsigned short* cbl_ = gKl + (size_t)(cc_)*4096; \
    K[0] = *(const short8*)(cbh_ + ko0); \
    K[1] = *(const short8*)(cbh_ + ko1); \
    K[2] = *(const short8*)(cbl_ + ko0); \
    K[3] = *(const short8*)(cbl_ + ko1); \
    K[4] = *(const short8*)(cbh_ + ko0 + 128); \
    K[5] = *(const short8*)(cbh_ + ko1 + 128); \
    K[6] = *(const short8*)(cbl_ + ko0 + 128); \
    K[7] = *(const short8*)(cbl_ + ko1 + 128); \
  }while(0)

#define PV_QK(K, cc_, phc_) do{ \
    _Pragma("unroll") \
    for (int t2=0; t2<2; ++t2){ \
      int c16 = cw*2 + t2; \
      f32x4 acc = {0.f,0.f,0.f,0.f}; \
      acc = mfma16(ah0,K[t2*4+0],acc); acc = mfma16(ah1,K[t2*4+1],acc); \
      acc = mfma16(al0,K[t2*4+0],acc); acc = mfma16(al1,K[t2*4+1],acc); \
      acc = mfma16(ah0,K[t2*4+2],acc); acc = mfma16(ah1,K[t2*4+3],acc); \
      int colg = (cc_)*64 + c16*16 + lm; \
      float ca = cAg[colg], cs = cSg[colg]; \
      _Pragma("unroll") \
      for (int i=0;i<4;++i){ \
        float dot = acc[i]; \
        float cosv = fminf(fmaxf(dot*ia[i]*ca,-0.99f),0.99f); \
        float arg = fmaf(A, cosv, fmaf(-bm[i], cs, fmaf(B8, dot, o2[i]))); \
        float e = __expf(arg); \
        unsigned short us = f2h(e); \
        phc_[rt*16+q*4+i][c16*16+lm] = us; \
        den[i] += h2f(us); \
      } \
    } \
  }while(0)

#define PV_TAIL(cc_, phc_) do{ \
    const unsigned short* cvh_ = gVh + (size_t)(cc_)*4096; \
    const unsigned short* cvl_ = gVl + (size_t)(cc_)*4096; \
    half8 vh0 = *(const half8*)(cvh_ + vo0); \
    half8 vh1 = *(const half8*)(cvh_ + vo1); \
    half8 vl0 = *(const half8*)(cvl_ + vo0); \
    half8 vl1 = *(const half8*)(cvl_ + vo1); \
    __syncthreads(); \
    half8 pb00 = *(const half8*)&phc_[lm][q*8]; \
    half8 pb01 = *(const half8*)&phc_[lm][32+q*8]; \
    half8 pb10 = *(const half8*)&phc_[16+lm][q*8]; \
    half8 pb11 = *(const half8*)&phc_[16+lm][32+q*8]; \
    o0 = mfma16f(vh0,pb00,o0); o0 = mfma16f(vl0,pb00,o0); \
    o0 = mfma16f(vh1,pb01,o0); o0 = mfma16f(vl1,pb01,o0); \
    o1 = mfma16f(vh0,pb10,o1); o1 = mfma16f(vl0,pb10,o1); \
    o1 = mfma16f(vh1,pb11,o1); o1 = mfma16f(vl1,pb11,o1); \
  }while(0)

  short8 KA[8], KB[8];
  PV_KLOAD(KA, c0);
  for (int t = 0; t < 16; t += 2){
    int ccA = (t + c0) & 15;
    int ccB = (t + 1 + c0) & 15;
    PV_KLOAD(KB, ccB);
    {
      unsigned short (*phc)[76] = ph[0];
      PV_QK(KA, ccA, phc);
      PV_TAIL(ccA, phc);
    }
    if (t < 14){
      int ccA2 = (t + 2 + c0) & 15;
      PV_KLOAD(KA, ccA2);
    }
    {
      unsigned short (*phc)[76] = ph[1];
      PV_QK(KB, ccB, phc);
      PV_TAIL(ccB, phc);
    }
  }
#undef PV_KLOAD
#undef PV_QK
#undef PV_TAIL

  #pragma unroll
  for (int m=1;m<16;m<<=1){
    #pragma unroll
    for (int i=0;i<4;++i) den[i] += __shfl_xor(den[i],m);
  }
  if (lm==0){
    #pragma unroll
    for (int i=0;i<4;++i) denbuf[w][q*4+i] = den[i];
  }
  __syncthreads();
  if (tid < 32){
    int rt2 = tid>>4, r16 = tid&15;
    dnv[tid] = 1.0f/(denbuf[rt2][r16] + denbuf[rt2+2][r16]);
  }
  __syncthreads();
  {
    float inv0 = dnv[lm];
    float inv1 = dnv[16+lm];
    int dcol = h*64 + w*16 + q*4;
    int row0 = qb*NTOK + n0 + lm;
    int row1 = row0 + 16;
    size_t b0i = cidx(row0, dcol);
    size_t b1i = cidx(row1, dcol);
    ushort4 h0,l0,h1,l1;
    { float xx=o0[0]*inv0; unsigned short hh=f2bf(xx); h0.x=hh; l0.x=f2bf(xx-bf2f(hh)); }
    { float xx=o0[1]*inv0; unsigned short hh=f2bf(xx); h0.y=hh; l0.y=f2bf(xx-bf2f(hh)); }
    { float xx=o0[2]*inv0; unsigned short hh=f2bf(xx); h0.z=hh; l0.z=f2bf(xx-bf2f(hh)); }
    { float xx=o0[3]*inv0; unsigned short hh=f2bf(xx); h0.w=hh; l0.w=f2bf(xx-bf2f(hh)); }
    { float xx=o1[0]*inv1; unsigned short hh=f2bf(xx); h1.x=hh; l1.x=f2bf(xx-bf2f(hh)); }
    { float xx=o1[1]*inv1; unsigned short hh=f2bf(xx); h1.y=hh; l1.y=f2bf(xx-bf2f(hh)); }
    { float xx=o1[2]*inv1; unsigned short hh=f2bf(xx); h1.z=hh; l1.z=f2bf(xx-bf2f(hh)); }
    { float xx=o1[3]*inv1; unsigned short hh=f2bf(xx); h1.w=hh; l1.w=f2bf(xx-bf2f(hh)); }
    *(ushort4*)(ohh+b0i)=h0; *(ushort4*)(ohl+b0i)=l0;
    *(ushort4*)(ohh+b1i)=h1; *(ushort4*)(ohl+b1i)=l1;
  }
}

// ----------------- output GEMM (MFMA): A and W staged via global_load_lds.

__global__ __launch_bounds__(256) void k_outmm(
    const unsigned short* __restrict__ ohh, const unsigned short* __restrict__ ohl,
    const unsigned short* __restrict__ Woth, const unsigned short* __restrict__ Wotl,
    const float* __restrict__ bias, float* __restrict__ out){
  __shared__ __align__(16) unsigned short Ah[4096];
  __shared__ __align__(16) unsigned short Al[4096];
  __shared__ __align__(16) unsigned short W0h[4096];
  __shared__ __align__(16) unsigned short W0l[4096];
  __shared__ __align__(16) unsigned short W1h[4096];
  __shared__ __align__(16) unsigned short W1l[4096];
  int mb = blockIdx.x, nb = blockIdx.y;
  int tid = threadIdx.x, w = tid>>6, l = tid&63, lm = l&15, qd = l>>4;
  int rh = w&1, tile = w>>1;
  int cbase = nb*128 + tile*64;
  f32x4 acc[2][4];
  #pragma unroll
  for (int mt=0;mt<2;++mt)
    #pragma unroll
    for (int nt=0;nt<4;++nt) acc[mt][nt] = (f32x4){0.f,0.f,0.f,0.f};
  int r0 = mb & 7;
  for (int t=0; t<8; ++t){
    int kc8 = (t + r0) & 7;
    __syncthreads();
    {
      const unsigned short* aSh = ohh  + ((size_t)(mb*8+kc8))*4096;
      const unsigned short* aSl = ohl  + ((size_t)(mb*8+kc8))*4096;
      const unsigned short* s0h = Woth + ((size_t)((nb*2  )*8+kc8))*4096;
      const unsigned short* s0l = Wotl + ((size_t)((nb*2  )*8+kc8))*4096;
      const unsigned short* s1h = Woth + ((size_t)((nb*2+1)*8+kc8))*4096;
      const unsigned short* s1l = Wotl + ((size_t)((nb*2+1)*8+kc8))*4096;
      if (w==0){
        #pragma unroll
        for (int j=0;j<8;++j) dma16(aSh + j*512 + l*8, &Ah[j*512]);
        #pragma unroll
        for (int j=0;j<4;++j) dma16(s1h + j*512 + l*8, &W1h[j*512]);
      } else if (w==1){
        #pragma unroll
        for (int j=0;j<8;++j) dma16(aSl + j*512 + l*8, &Al[j*512]);
        #pragma unroll
        for (int j=4;j<8;++j) dma16(s1h + j*512 + l*8, &W1h[j*512]);
      } else if (w==2){
        #pragma unroll
        for (int j=0;j<8;++j) dma16(s0h + j*512 + l*8, &W0h[j*512]);
        #pragma unroll
        for (int j=0;j<4;++j) dma16(s1l + j*512 + l*8, &W1l[j*512]);
      } else {
        #pragma unroll
        for (int j=0;j<8;++j) dma16(s0l + j*512 + l*8, &W0l[j*512]);
        #pragma unroll
        for (int j=4;j<8;++j) dma16(s1l + j*512 + l*8, &W1l[j*512]);
      }
    }
    __syncthreads();
    const unsigned short* Wh_ = tile ? W1h : W0h;
    const unsigned short* Wl_ = tile ? W1l : W0l;
    #pragma unroll
    for (int kch=0; kch<2; ++kch){
      short8 a_h[2], a_l[2];
      #pragma unroll
      for (int mt=0;mt<2;++mt){
        int off = ((kch*4+qd)*64 + rh*32 + mt*16 + lm)*8;
        a_h[mt] = *(const short8*)(Ah + off);
        a_l[mt] = *(const short8*)(Al + off);
      }
      #pragma unroll
      for (int nt=0;nt<4;++nt){
        int off = ((kch*4+qd)*64 + nt*16+lm)*8;
        short8 bh = *(const short8*)(Wh_ + off);
        short8 bl = *(const short8*)(Wl_ + off);
        #pragma unroll
        for (int mt=0;mt<2;++mt){
          acc[mt][nt] = mfma16(a_h[mt], bh, acc[mt][nt]);
          acc[mt][nt] = mfma16(a_h[mt], bl, acc[mt][nt]);
          acc[mt][nt] = mfma16(a_l[mt], bh, acc[mt][nt]);
        }
      }
    }
  }
  float bv[4];
  #pragma unroll
  for (int nt=0;nt<4;++nt) bv[nt] = bias[cbase+nt*16+lm];
  #pragma unroll
  for (int mt=0;mt<2;++mt){
    #pragma unroll
    for (int i=0;i<4;++i){
      int row = mb*64 + rh*32 + mt*16 + qd*4 + i;
      #pragma unroll
      for (int nt=0;nt<4;++nt){
        out[(size_t)row*DIMX + cbase + nt*16 + lm] = acc[mt][nt][i] + bv[nt];
      }
    }
  }
}

// ----------------------------------------------------------------- launch

extern "C" void kernel_launch(void* const* d_in, const int* in_sizes, int n_in,
                              void* d_out, int out_size, void* d_ws, size_t ws_size,
                              hipStream_t stream) {
  (void)in_sizes; (void)n_in; (void)out_size;
  const float* q     = (const float*)d_in[0];
  const float* k     = (const float*)d_in[1];
  const float* v     = (const float*)d_in[2];
  const float* ln_g  = (const float*)d_in[3];
  const float* ln_b  = (const float*)d_in[4];
  const float* W_in  = (const float*)d_in[5];
  const float* wp_W1 = (const float*)d_in[6];
  const float* wp_b1 = (const float*)d_in[7];
  const float* wp_lg = (const float*)d_in[8];
  const float* wp_lb = (const float*)d_in[9];
  const float* wp_W2 = (const float*)d_in[10];
  const float* wp_b2 = (const float*)d_in[11];
  const float* wp_W3 = (const float*)d_in[12];
  const float* wp_b3 = (const float*)d_in[13];
  const float* wtemp = (const float*)d_in[14];
  const float* W_out = (const float*)d_in[15];
  const float* b_out = (const float*)d_in[16];
  float* out = (float*)d_out;

  char* wsb = (char*)d_ws;
  double* gacc = (double*)wsb;            // 24 doubles
  double* racc = gacc + 24;               // 48
  double* qgs  = racc + 48;               // 512
  double* nusum= qgs + 512;               // 2048  (doubles end @ 21056 B)
  float* coefG  = (float*)(wsb + 21120);      // 24 floats, inside zeroed zone
  float* fvA = (float*)(wsb + 24576);     // 8 MB; reused as ohh/ohl after k_mid
  unsigned short* ohh = (unsigned short*)fvA;                   // 4 MB
  unsigned short* ohl = ohh + (size_t)NQB*NTOK*NH*DH;           // 4 MB
  float* mu_rstd = fvA + (size_t)NPAIR*NTOK*DH;   // 24576
  float* Sarr = mu_rstd + 24576;          // 64 (padded)
  float* inv_na_q = Sarr + 64;
  float* muqA     = inv_na_q + NROWS;
  float* tqA      = muqA + NROWS;
  float* inv_na_k = tqA + NROWS;
  float* skA      = inv_na_k + NROWS;
  float* var_row  = skA + NROWS;
  float* mxcos    = var_row + NROWS;
  float* mxcov    = mxcos + NROWS;
  float* wp_out   = mxcov + NROWS;        // 32 (padded)
  float* endf     = wp_out + 32;
  size_t off16 = (size_t)((char*)endf - wsb);
  off16 = (off16 + 63) & ~(size_t)63;
  unsigned short* fqh  = (unsigned short*)(wsb + off16);
  unsigned short* fql  = fqh  + (size_t)NPAIR*NTOK*DH;
  unsigned short* fkh  = fql  + (size_t)NPAIR*NTOK*DH;
  unsigned short* fkl  = fkh  + (size_t)NPAIR*NTOK*DH;
  unsigned short* fvTh = fkl  + (size_t)NPAIR*NTOK*DH;
  unsigned short* fvTl = fvTh + (size_t)NPAIR*NTOK*DH;
  unsigned short* Wth  = fvTl + (size_t)NPAIR*NTOK*DH;
  unsigned short* Wtl  = Wth  + (size_t)DIMX*DIMX;
  unsigned short* Woth = Wtl  + (size_t)DIMX*DIMX;
  unsigned short* Wotl = Woth + (size_t)DIMX*DIMX;
  size_t need = (size_t)((char*)(Wotl + (size_t)DIMX*DIMX) - wsb);
  if (ws_size < need) return;  // fail cleanly rather than corrupt

  k_pre<<<3201, 256, 0, stream>>>(q, k, v, mu_rstd, W_in, W_out,
                                  Wth, Wtl, Woth, Wotl, (float*)wsb);
  k_projmm<<<dim3(64,4,3), 256, 0, stream>>>(q, k, v, ln_g, ln_b, Wth, Wtl,
                                             mu_rstd, fqh, fql, fkh, fkl, fvA,
                                             qgs, nusum);
  k_mid<<<8705, 256, 0, stream>>>(fvA, fvTh, fvTl, fqh, fql, fkh, fkl, nusum,
                                  inv_na_q, muqA, tqA, inv_na_k, skA,
                                  qgs, wp_W1, wp_b1, wp_lg, wp_lb,
                                  wp_W2, wp_b2, wp_W3, wp_b3, wtemp,
                                  wp_out, Sarr);
  k_passA<<<1024, 256, 0, stream>>>(fqh, fql, fkh, fkl,
                                    inv_na_q, muqA, tqA, inv_na_k, skA, Sarr,
                                    var_row, mxcos, mxcov, gacc, racc);
  k_final<<<1, 64, 0, stream>>>(gacc, racc, wp_out, coefG);
  k_pv<<<1024, 256, 0, stream>>>(fqh, fql, fkh, fkl, fvTh, fvTl,
                                 inv_na_q, muqA, tqA, inv_na_k, skA, Sarr,
                                 var_row, mxcos, mxcov, coefG,
                                 ohh, ohl);
  k_outmm<<<dim3(64,4), 256, 0, stream>>>(ohh, ohl, Woth, Wotl, b_out, out);
}

// Round 10
// 251.370 us; speedup vs baseline: 1.0479x; 1.0098x over previous
//
#include <hip/hip_runtime.h>
#include <math.h>

#define NH    8
#define NQB   4
#define NPAIR 32
#define NTOK  1024
#define DH    64
#define DIMX  512
#define NROWS (NPAIR*NTOK)

typedef __attribute__((ext_vector_type(8))) short short8;
typedef _Float16 half8 __attribute__((ext_vector_type(8)));
typedef __attribute__((ext_vector_type(4))) float f32x4;

__device__ __forceinline__ unsigned short f2bf(float x){
  unsigned u = __float_as_uint(x);
  u += 0x7fffu + ((u>>16)&1u);
  return (unsigned short)(u>>16);
}
__device__ __forceinline__ float bf2f(unsigned short h){
  return __uint_as_float(((unsigned)h)<<16);
}
__device__ __forceinline__ unsigned short f2h(float x){
  union{ _Float16 f; unsigned short u; } c; c.f = (_Float16)x; return c.u;
}
__device__ __forceinline__ float h2f(unsigned short u){
  union{ _Float16 f; unsigned short u; } c; c.u = u; return (float)c.f;
}
__device__ __forceinline__ f32x4 mfma16(short8 a, short8 b, f32x4 c){
  return __builtin_amdgcn_mfma_f32_16x16x32_bf16(a,b,c,0,0,0);
}
__device__ __forceinline__ f32x4 mfma16f(half8 a, half8 b, f32x4 c){
  return __builtin_amdgcn_mfma_f32_16x16x32_f16(a,b,c,0,0,0);
}
// async global->LDS DMA, 16B per lane; LDS dest = base + lane*16
__device__ __forceinline__ void dma16(const void* g, void* l){
  __builtin_amdgcn_global_load_lds(
      (const __attribute__((address_space(1))) void*)g,
      (__attribute__((address_space(3))) void*)l, 16, 0, 0);
}

// chunk layout for 512-col matrices: [rowgrp64][colgrp64][cq8][row64][8]
__device__ __forceinline__ size_t cidx(int r, int c){
  return ((((size_t)((r>>6)*8 + (c>>6)))*8 + ((c&63)>>3))*64 + (r&63))*8 + (c&7);
}
// K layout: FK[p][kc][dq][k64][8]
__device__ __forceinline__ size_t kidx(int p, int key, int dh){
  return ((((size_t)(p*16 + (key>>6)))*8 + (dh>>3))*64 + (key&63))*8 + (dh&7);
}

// ---------------- fused prelude: LN stats | W split | accumulator zeroing

__global__ __launch_bounds__(256) void k_pre(
    const float* __restrict__ q, const float* __restrict__ k, const float* __restrict__ v,
    float* __restrict__ mu_rstd,
    const float* __restrict__ Wa, const float* __restrict__ Wb,
    unsigned short* __restrict__ Wth, unsigned short* __restrict__ Wtl,
    unsigned short* __restrict__ Woth, unsigned short* __restrict__ Wotl,
    float* __restrict__ zacc){
  __shared__ float tile[64][65];
  int b = blockIdx.x, tid = threadIdx.x;
  if (b < 3072){
    int wid = tid >> 6, lane = tid & 63;
    int tok = b*4 + wid;                   // 0..12287
    const float* src = (tok < 4096) ? q : ((tok < 8192) ? k : v);
    int t = tok & 4095;
    const float4* p4 = (const float4*)(src + (size_t)t*DIMX) + lane*2;
    float4 a = p4[0], bb = p4[1];
    float s  = a.x+a.y+a.z+a.w + bb.x+bb.y+bb.z+bb.w;
    float ss = a.x*a.x+a.y*a.y+a.z*a.z+a.w*a.w
             + bb.x*bb.x+bb.y*bb.y+bb.z*bb.z+bb.w*bb.w;
    #pragma unroll
    for (int off=32; off; off>>=1){ s += __shfl_down(s,off); ss += __shfl_down(ss,off); }
    if (lane==0){
      float mu = s*(1.0f/512.0f);
      float var = ss*(1.0f/512.0f) - mu*mu;
      mu_rstd[tok*2+0] = mu;
      mu_rstd[tok*2+1] = 1.0f/sqrtf(var + 1e-5f);
    }
  } else if (b < 3200){
    int sb = b - 3072;
    int z = sb >> 6, rem = sb & 63, kb = rem & 7, nb = rem >> 3;
    const float* W = z ? Wb : Wa;
    unsigned short* oh_ = z ? Woth : Wth;
    unsigned short* ol_ = z ? Wotl : Wtl;
    #pragma unroll
    for (int it=0; it<4; ++it){
      int idx = tid + 256*it;          // 0..1023
      int kr = idx>>4, c4 = idx&15;
      float4 vv = *(const float4*)(W + (size_t)(kb*64+kr)*DIMX + nb*64 + c4*4);
      tile[c4*4+0][kr]=vv.x; tile[c4*4+1][kr]=vv.y; tile[c4*4+2][kr]=vv.z; tile[c4*4+3][kr]=vv.w;
    }
    __syncthreads();
    #pragma unroll
    for (int it=0; it<4; ++it){
      int idx = tid + 256*it;
      int n = idx>>4, k4 = idx&15;
      size_t base = cidx(nb*64+n, kb*64+k4*4);
      ushort4 hv, lv;
      { float xx=tile[n][k4*4+0]; unsigned short hh=f2bf(xx); hv.x=hh; lv.x=f2bf(xx-bf2f(hh)); }
      { float xx=tile[n][k4*4+1]; unsigned short hh=f2bf(xx); hv.y=hh; lv.y=f2bf(xx-bf2f(hh)); }
      { float xx=tile[n][k4*4+2]; unsigned short hh=f2bf(xx); hv.z=hh; lv.z=f2bf(xx-bf2f(hh)); }
      { float xx=tile[n][k4*4+3]; unsigned short hh=f2bf(xx); hv.w=hh; lv.w=f2bf(xx-bf2f(hh)); }
      *(ushort4*)(oh_+base) = hv;
      *(ushort4*)(ol_+base) = lv;
    }
  } else {
    // zero 24576 B of accumulators (gacc/racc/qgs/nusum/coefG)
    uint4 z4 = {0u,0u,0u,0u};
    uint4* dst = (uint4*)zacc;
    #pragma unroll
    for (int i=0;i<6;++i) dst[tid + 256*i] = z4;
  }
}

// --------------- LN + projection GEMM via split-bf16 MFMA (q, k, v by z)

__global__ __launch_bounds__(256) void k_projmm(
    const float* __restrict__ q, const float* __restrict__ k, const float* __restrict__ v,
    const float* __restrict__ g, const float* __restrict__ bln,
    const unsigned short* __restrict__ Wth, const unsigned short* __restrict__ Wtl,
    const float* __restrict__ mu_rstd,
    unsigned short* __restrict__ fqh, unsigned short* __restrict__ fql,
    unsigned short* __restrict__ fkh, unsigned short* __restrict__ fkl,
    float* __restrict__ fv,
    double* __restrict__ qgs, double* __restrict__ nusum){
  __shared__ __align__(16) unsigned short Ahs[64*72];
  __shared__ __align__(16) unsigned short Als[64*72];
  __shared__ __align__(16) unsigned short WhL[2][4096];
  __shared__ __align__(16) unsigned short WlL[2][4096];
  __shared__ float scrc[4][128];
  int z = blockIdx.z;
  const float* x = (z==0) ? q : ((z==1) ? k : v);
  int mb = blockIdx.x, nb = blockIdx.y;
  int tid = threadIdx.x, w = tid>>6, l = tid&63, lm = l&15, qd = l>>4;
  int rbase = (w&1)*32;
  int tile = w>>1;
  int cbase = nb*128 + tile*64;
  scrc[tid>>7][tid&127] = 0.f;
  scrc[2+(tid>>7)][tid&127] = 0.f;
  f32x4 acc[2][4];
  #pragma unroll
  for (int mt=0;mt<2;++mt)
    #pragma unroll
    for (int nt=0;nt<4;++nt) acc[mt][nt] = (f32x4){0.f,0.f,0.f,0.f};
  int r0 = mb & 7;
  for (int t = 0; t < 8; ++t){
    int kc8 = (t + r0) & 7;
    float4 xv[4]; float mus[4], rss[4]; float4 gv[4], bv[4]; int rr[4], kk4[4];
    #pragma unroll
    for (int it=0; it<4; ++it){
      int idx = tid + 256*it;          // 0..1023
      int r = idx>>4, k4 = idx&15;
      rr[it]=r; kk4[it]=k4;
      int tokg = z*4096 + mb*64 + r;
      mus[it] = mu_rstd[tokg*2+0]; rss[it] = mu_rstd[tokg*2+1];
      xv[it] = *(const float4*)(x + (size_t)(mb*64+r)*DIMX + kc8*64 + k4*4);
      gv[it] = *(const float4*)(g   + kc8*64 + k4*4);
      bv[it] = *(const float4*)(bln + kc8*64 + k4*4);
    }
    __syncthreads();                   // prev chunk consumed
    {  // wave w stages W chunk: tile w>>1, hi/lo w&1
      int st = w>>1, hl = w&1;
      const unsigned short* src = (hl ? Wtl : Wth)
          + ((size_t)((nb*2+st)*8 + kc8))*4096;
      unsigned short* dst = hl ? WlL[st] : WhL[st];
      #pragma unroll
      for (int j=0;j<8;++j) dma16(src + j*512 + l*8, dst + j*512);
    }
    #pragma unroll
    for (int it=0; it<4; ++it){
      float y0 = (xv[it].x-mus[it])*rss[it]*gv[it].x + bv[it].x;
      float y1 = (xv[it].y-mus[it])*rss[it]*gv[it].y + bv[it].y;
      float y2 = (xv[it].z-mus[it])*rss[it]*gv[it].z + bv[it].z;
      float y3 = (xv[it].w-mus[it])*rss[it]*gv[it].w + bv[it].w;
      ushort4 hv, lv;
      { unsigned short hh=f2bf(y0); hv.x=hh; lv.x=f2bf(y0-bf2f(hh)); }
      { unsigned short hh=f2bf(y1); hv.y=hh; lv.y=f2bf(y1-bf2f(hh)); }
      { unsigned short hh=f2bf(y2); hv.z=hh; lv.z=f2bf(y2-bf2f(hh)); }
      { unsigned short hh=f2bf(y3); hv.w=hh; lv.w=f2bf(y3-bf2f(hh)); }
      *(ushort4*)(Ahs + rr[it]*72 + kk4[it]*4) = hv;
      *(ushort4*)(Als + rr[it]*72 + kk4[it]*4) = lv;
    }
    __syncthreads();                   // staging + DMA visible
    #pragma unroll
    for (int kch=0; kch<2; ++kch){
      short8 a_h[2], a_l[2];
      #pragma unroll
      for (int mt=0;mt<2;++mt){
        a_h[mt] = *(const short8*)(Ahs + (rbase+mt*16+lm)*72 + kch*32 + qd*8);
        a_l[mt] = *(const short8*)(Als + (rbase+mt*16+lm)*72 + kch*32 + qd*8);
      }
      #pragma unroll
      for (int nt=0;nt<4;++nt){
        int off = ((kch*4+qd)*64 + nt*16+lm)*8;
        short8 bh = *(const short8*)(WhL[tile] + off);
        short8 bl = *(const short8*)(WlL[tile] + off);
        #pragma unroll
        for (int mt=0;mt<2;++mt){
          acc[mt][nt] = mfma16(a_h[mt], bh, acc[mt][nt]);
          acc[mt][nt] = mfma16(a_h[mt], bl, acc[mt][nt]);
          acc[mt][nt] = mfma16(a_l[mt], bh, acc[mt][nt]);
        }
      }
    }
  }
  int head = cbase >> 6;
  if (z < 2){
    float csum[4] = {0.f,0.f,0.f,0.f};
    #pragma unroll
    for (int mt=0;mt<2;++mt){
      #pragma unroll
      for (int nt=0;nt<4;++nt){
        #pragma unroll
        for (int i=0;i<4;++i){
          float val = acc[mt][nt][i];
          csum[nt] += val;
          int tglob = mb*64 + rbase + mt*16 + qd*4 + i;
          int qb = tglob>>10, n = tglob&1023;
          int p = head*4 + qb;
          int d = nt*16 + lm;
          unsigned short hh = f2bf(val);
          unsigned short ll = f2bf(val - bf2f(hh));
          if (z==0){
            size_t ix = ((size_t)(p*NTOK+n))*DH + d;
            fqh[ix] = hh; fql[ix] = ll;
          } else {
            size_t ix = kidx(p, n, d);
            fkh[ix] = hh; fkl[ix] = ll;
          }
        }
      }
    }
    #pragma unroll
    for (int m=16;m<64;m<<=1){
      #pragma unroll
      for (int nt=0;nt<4;++nt) csum[nt] += __shfl_xor(csum[nt], m);
    }
    if (qd==0){
      #pragma unroll
      for (int nt=0;nt<4;++nt) scrc[w][tile*64 + nt*16 + lm] = csum[nt];
    }
    __syncthreads();
    if (tid < 128){
      float s = scrc[0][tid]+scrc[1][tid]+scrc[2][tid]+scrc[3][tid];
      if (z==0){
        atomicAdd(&qgs[nb*128 + tid], (double)s);
      } else {
        int col = nb*128 + tid;
        int hh2 = col>>6, d = col&63;
        int qb = mb>>4;
        atomicAdd(&nusum[(size_t)(hh2*4+qb)*DH + d], (double)s);
      }
    }
  } else {
    #pragma unroll
    for (int mt=0;mt<2;++mt){
      #pragma unroll
      for (int nt=0;nt<4;++nt){
        #pragma unroll
        for (int i=0;i<4;++i){
          int tglob = mb*64 + rbase + mt*16 + qd*4 + i;
          int qb = tglob>>10, n = tglob&1023;
          int p = head*4 + qb;
          int d = nt*16 + lm;
          fv[((size_t)(p*NTOK+n))*DH + d] = acc[mt][nt][i];
        }
      }
    }
  }
}

// ------- fused mid pass: fv transpose | per-row scalars | weight predictor

__global__ __launch_bounds__(256) void k_mid(
    const float* __restrict__ fv,
    unsigned short* __restrict__ fvTh, unsigned short* __restrict__ fvTl,
    const unsigned short* __restrict__ fqh, const unsigned short* __restrict__ fql,
    const unsigned short* __restrict__ fkh, const unsigned short* __restrict__ fkl,
    const double* __restrict__ nusum,
    float* __restrict__ inv_na_q, float* __restrict__ muqA, float* __restrict__ tqA,
    float* __restrict__ inv_na_k, float* __restrict__ skA,
    const double* __restrict__ qgs,
    const float* __restrict__ W1, const float* __restrict__ b1,
    const float* __restrict__ lgv, const float* __restrict__ lbv,
    const float* __restrict__ W2, const float* __restrict__ b2,
    const float* __restrict__ W3, const float* __restrict__ b3,
    const float* __restrict__ wtemp, float* __restrict__ wp_out,
    float* __restrict__ Sarr){
  __shared__ __align__(16) float msm[64*65];
  int b = blockIdx.x, tid = threadIdx.x;
  if (b < 512){
    float (*tile)[65] = (float(*)[65])msm;
    int mc = b & 15, p = b >> 4;
    #pragma unroll
    for (int it=0; it<4; ++it){
      int idx = tid + 256*it;
      int m = idx>>4, d4 = idx&15;
      float4 vv = *(const float4*)(fv + ((size_t)(p*NTOK + mc*64 + m)*DH + d4*4));
      tile[d4*4+0][m]=vv.x; tile[d4*4+1][m]=vv.y; tile[d4*4+2][m]=vv.z; tile[d4*4+3][m]=vv.w;
    }
    __syncthreads();
    #pragma unroll
    for (int it=0; it<2; ++it){
      int idx = tid + 256*it;       // 0..511
      int d = idx>>3, seg = idx&7;  // keys seg*8..seg*8+8
      size_t base = ((((size_t)(p*16+mc))*8 + seg)*64 + d)*8;
      ushort4 h0,h1v,l0,l1;
      { float xx=tile[d][seg*8+0]; unsigned short hh=f2h(xx); h0.x=hh; l0.x=f2h(xx-h2f(hh)); }
      { float xx=tile[d][seg*8+1]; unsigned short hh=f2h(xx); h0.y=hh; l0.y=f2h(xx-h2f(hh)); }
      { float xx=tile[d][seg*8+2]; unsigned short hh=f2h(xx); h0.z=hh; l0.z=f2h(xx-h2f(hh)); }
      { float xx=tile[d][seg*8+3]; unsigned short hh=f2h(xx); h0.w=hh; l0.w=f2h(xx-h2f(hh)); }
      { float xx=tile[d][seg*8+4]; unsigned short hh=f2h(xx); h1v.x=hh; l1.x=f2h(xx-h2f(hh)); }
      { float xx=tile[d][seg*8+5]; unsigned short hh=f2h(xx); h1v.y=hh; l1.y=f2h(xx-h2f(hh)); }
      { float xx=tile[d][seg*8+6]; unsigned short hh=f2h(xx); h1v.z=hh; l1.z=f2h(xx-h2f(hh)); }
      { float xx=tile[d][seg*8+7]; unsigned short hh=f2h(xx); h1v.w=hh; l1.w=f2h(xx-h2f(hh)); }
      *(ushort4*)(fvTh+base)   = h0;
      *(ushort4*)(fvTh+base+4) = h1v;
      *(ushort4*)(fvTl+base)   = l0;
      *(ushort4*)(fvTl+base+4) = l1;
    }
  } else if (b < 8704){
    int rb = b - 512;
    int wid = tid >> 6, lane = tid & 63;
    int row = rb*4 + wid;            // < 32768
    int p = row >> 10;
    int key = row & 1023;
    size_t ix = (size_t)row*DH + lane;
    float xq = bf2f(fqh[ix]) + bf2f(fql[ix]);
    float nv = (float)(nusum[(size_t)p*DH + lane] * (1.0/1024.0));
    float s = xq, ss = xq*xq, sd = xq*nv;
    #pragma unroll
    for (int off=32; off; off>>=1){
      s += __shfl_down(s,off); ss += __shfl_down(ss,off); sd += __shfl_down(sd,off);
    }
    if (lane==0){
      float nrm = sqrtf(ss);
      inv_na_q[row] = 1.0f/(nrm+1e-8f);
      muqA[row] = s*(1.0f/64.0f);
      tqA[row] = sd;
    }
    size_t ixk = kidx(p, key, lane);
    float xk = bf2f(fkh[ixk]) + bf2f(fkl[ixk]);
    float s2 = xk, ss2 = xk*xk;
    #pragma unroll
    for (int off=32; off; off>>=1){
      s2 += __shfl_down(s2,off); ss2 += __shfl_down(ss2,off);
    }
    if (lane==0){
      float nrm = sqrtf(ss2);
      inv_na_k[row] = 1.0f/(nrm+1e-8f);
      skA[row] = s2;
    }
  } else {
    // weight predictor + Sarr (single block)
    float* feats = msm;           // 8*128
    float* h1    = msm + 1024;    // 8*64
    float* h2s   = msm + 1536;    // 8*32
    float* lgt   = msm + 1792;    // 8*3 (stride 3)
    float* mv    = msm + 1832;    // 8*2
    for (int idx = tid; idx < 1024; idx += 256){
      int h = idx >> 7, i = idx & 127;
      double vv;
      if (i < 64){
        vv = qgs[h*64+i];
      } else {
        int d = i - 64;
        vv = nusum[(size_t)(h*4+0)*DH+d] + nusum[(size_t)(h*4+1)*DH+d]
           + nusum[(size_t)(h*4+2)*DH+d] + nusum[(size_t)(h*4+3)*DH+d];
      }
      feats[h*128+i] = (float)(vv * (1.0/4096.0));
    }
    if (tid < 32){
      double s = 0.0;
      for (int d = 0; d < 64; ++d) s += nusum[(size_t)tid*DH + d];
      Sarr[tid] = (float)(s * (1.0/1024.0));
    }
    __syncthreads();
    for (int idx = tid; idx < 512; idx += 256){
      int h = idx >> 6, j = idx & 63;
      float s = b1[j];
      for (int i = 0; i < 128; ++i) s += feats[h*128+i]*W1[i*64+j];
      h1[h*64+j] = s;
    }
    __syncthreads();
    if (tid < 8){
      float s=0.f, ss=0.f;
      for (int j=0;j<64;++j){ float vv=h1[tid*64+j]; s+=vv; ss+=vv*vv; }
      float mu = s*(1.0f/64.0f);
      float var = ss*(1.0f/64.0f)-mu*mu;
      mv[tid*2+0]=mu; mv[tid*2+1]=1.0f/sqrtf(var+1e-5f);
    }
    __syncthreads();
    for (int idx = tid; idx < 512; idx += 256){
      int h = idx>>6, j = idx&63;
      float vv = (h1[h*64+j]-mv[h*2+0])*mv[h*2+1]*lgv[j] + lbv[j];
      h1[h*64+j] = fmaxf(vv, 0.f);
    }
    __syncthreads();
    {
      int h = tid >> 5, j = tid & 31;
      float s = b2[j];
      for (int i=0;i<64;++i) s += h1[h*64+i]*W2[i*32+j];
      h2s[h*32+j] = fmaxf(s, 0.f);
    }
    __syncthreads();
    if (tid < 24){
      int h = tid/3, j = tid - h*3;
      float s = b3[j];
      for (int i=0;i<32;++i) s += h2s[h*32+i]*W3[i*3+j];
      lgt[h*3+j] = s;
    }
    __syncthreads();
    if (tid < 8){
      int h = tid;
      float z0=lgt[h*3+0], z1=lgt[h*3+1], z2=lgt[h*3+2];
      float m = fmaxf(z0,fmaxf(z1,z2));
      float e0=expf(z0-m), e1=expf(z1-m), e2=expf(z2-m);
      float inv = 1.0f/(e0+e1+e2);
      float l0=e0*inv, l1=e1*inv, l2=e2*inv;
      float wt = fminf(fmaxf(wtemp[0], 0.1f), 20.0f);
      float y0=l0/wt, y1=l1/wt, y2=l2/wt;
      float m2 = fmaxf(y0,fmaxf(y1,y2));
      float f0=expf(y0-m2), f1=expf(y1-m2), f2=expf(y2-m2);
      float inv2 = 1.0f/(f0+f1+f2);
      float w0=f0*inv2, w1=f1*inv2, w2=f2*inv2;
      w0 = fminf(fmaxf(w0,0.05f),0.8f);
      w1 = fminf(fmaxf(w1,0.05f),0.8f);
      w2 = fminf(fmaxf(w2,0.05f),0.8f);
      float isum = 1.0f/(w0+w1+w2);
      wp_out[h*3+0]=w0*isum; wp_out[h*3+1]=w1*isum; wp_out[h*3+2]=w2*isum;
    }
  }
}

// ------------- pass A (MFMA): KA/KB register prefetch; row-finish fused.
// coef is computed by the standalone k_final (keeps this kernel's VGPR low).

__global__ __launch_bounds__(256) void k_passA(
    const unsigned short* __restrict__ fqh, const unsigned short* __restrict__ fql,
    const unsigned short* __restrict__ fkh, const unsigned short* __restrict__ fkl,
    const float* __restrict__ inv_na_q, const float* __restrict__ muqA,
    const float* __restrict__ tqA,
    const float* __restrict__ inv_na_k, const float* __restrict__ skA,
    const float* __restrict__ Sarr,
    float* __restrict__ var_row,
    float* __restrict__ mxcosA, float* __restrict__ mxcovA,
    double* __restrict__ gacc, double* __restrict__ racc){
  __shared__ float redbuf[4][16][5];
  __shared__ double wredS[4][3];
  int b = blockIdx.x;
  int p = ((b&7)<<2) | ((b>>3)&3);   // XCD swizzle
  int s = b>>5;                      // 0..31
  int n0 = s*32;
  int tid = threadIdx.x, w = tid>>6, l = tid&63;
  int lm = l&15, q = l>>4;
  int rt = w&1, cw = w>>1;
  int nw = n0 + rt*16;
  float Sp = Sarr[p];
  const float inv8 = (float)(1.0/(8.0+1e-6));
  float ia[4], m8[4], t8[4];
  #pragma unroll
  for (int i=0;i<4;++i){
    int rg = p*NTOK + nw + q*4 + i;
    float mq = muqA[rg];
    ia[i] = inv_na_q[rg];
    m8[i] = mq*inv8;
    t8[i] = (tqA[rg] - mq*Sp)*inv8;
  }
  const short8* aqh = (const short8*)(fqh + (size_t)(p*NTOK + nw + lm)*DH);
  const short8* aql = (const short8*)(fql + (size_t)(p*NTOK + nw + lm)*DH);
  short8 ah0 = aqh[q], ah1 = aqh[4+q], al0 = aql[q], al1 = aql[4+q];
  const unsigned short* gKh = fkh + (size_t)p*16*4096;
  const unsigned short* gKl = fkl + (size_t)p*16*4096;
  const float* cAg = inv_na_k + p*NTOK;
  const float* cSg = skA + p*NTOK;
  float sc2=0.f, sv2=0.f, scv=0.f;
  float pc[4]={0,0,0,0}, pv_[4]={0,0,0,0}, pm[4]={0,0,0,0};
  float xc[4], xv[4];
  #pragma unroll
  for (int i=0;i<4;++i){ xc[i]=-1e30f; xv[i]=-1e30f; }
  int ko0 = ((q  )*64 + (cw*2)*16+lm)*8;
  int ko1 = ((q+4)*64 + (cw*2)*16+lm)*8;
  int c0 = s & 15;                   // rotation offset

#define PA_LOAD(K, cc_) do{ \
    const unsigned short* cbh_ = gKh + (size_t)(cc_)*4096; \
    const unsigned short* cbl_ = gKl + (size_t)(cc_)*4096; \
    K[0] = *(const short8*)(cbh_ + ko0); \
    K[1] = *(const short8*)(cbh_ + ko1); \
    K[2] = *(const short8*)(cbl_ + ko0); \
    K[3] = *(const short8*)(cbl_ + ko1); \
    K[4] = *(const short8*)(cbh_ + ko0 + 128); \
    K[5] = *(const short8*)(cbh_ + ko1 + 128); \
    K[6] = *(const short8*)(cbl_ + ko0 + 128); \
    K[7] = *(const short8*)(cbl_ + ko1 + 128); \
  }while(0)

#define PA_COMP(K, cc_) do{ \
    _Pragma("unroll") \
    for (int t2=0; t2<2; ++t2){ \
      int c16 = cw*2 + t2; \
      f32x4 acc = {0.f,0.f,0.f,0.f}; \
      acc = mfma16(ah0,K[t2*4+0],acc); acc = mfma16(ah1,K[t2*4+1],acc); \
      acc = mfma16(al0,K[t2*4+0],acc); acc = mfma16(al1,K[t2*4+1],acc); \
      acc = mfma16(ah0,K[t2*4+2],acc); acc = mfma16(ah1,K[t2*4+3],acc); \
      int colg = (cc_)*64 + c16*16 + lm; \
      float ca = cAg[colg], cs = cSg[colg]; \
      _Pragma("unroll") \
      for (int i=0;i<4;++i){ \
        float dot = acc[i]; \
        float cosv = fminf(fmaxf(dot*ia[i]*ca,-0.99f),0.99f); \
        float cov  = fmaf(-m8[i], cs, fmaf(dot, inv8, -t8[i])); \
        float marg = fmaxf(0.01f - cosv, 0.f); \
        sc2 = fmaf(cosv,cosv,sc2); sv2 = fmaf(cov,cov,sv2); scv = fmaf(cosv,cov,scv); \
        pc[i]+=cosv; pv_[i]+=cov; pm[i]+=marg; \
        xc[i]=fmaxf(xc[i],cosv); \
        xv[i]=fmaxf(xv[i],cov); \
      } \
    } \
  }while(0)

  short8 KA[8], KB[8];
  PA_LOAD(KA, c0);
  for (int t = 0; t < 16; t += 2){
    int ccA = (t + c0) & 15;
    int ccB = (t + 1 + c0) & 15;
    PA_LOAD(KB, ccB);
    PA_COMP(KA, ccA);
    if (t < 14){
      int ccA2 = (t + 2 + c0) & 15;
      PA_LOAD(KA, ccA2);
    }
    PA_COMP(KB, ccB);
  }
#undef PA_LOAD
#undef PA_COMP

  #pragma unroll
  for (int m=1;m<16;m<<=1){
    #pragma unroll
    for (int i=0;i<4;++i){
      pc[i]+=__shfl_xor(pc[i],m); pv_[i]+=__shfl_xor(pv_[i],m); pm[i]+=__shfl_xor(pm[i],m);
      xc[i]=fmaxf(xc[i],__shfl_xor(xc[i],m));
      xv[i]=fmaxf(xv[i],__shfl_xor(xv[i],m));
    }
  }
  if (lm==0){
    #pragma unroll
    for (int i=0;i<4;++i){
      int r16 = q*4+i;
      redbuf[w][r16][0]=pc[i]; redbuf[w][r16][1]=pv_[i]; redbuf[w][r16][2]=pm[i];
      redbuf[w][r16][3]=xc[i]; redbuf[w][r16][4]=xv[i];
    }
  }
  double vals[3] = {(double)sc2,(double)sv2,(double)scv};
  #pragma unroll
  for (int c2=0;c2<3;++c2){
    double vv = vals[c2];
    #pragma unroll
    for (int off=32; off; off>>=1) vv += __shfl_down(vv, off);
    if (l==0) wredS[w][c2] = vv;
  }
  __syncthreads();
  if (tid < 32){
    int rt2 = tid>>4, r16 = tid&15;
    int w0 = rt2, w1 = rt2+2;
    float sc = redbuf[w0][r16][0]+redbuf[w1][r16][0];
    float sv = redbuf[w0][r16][1]+redbuf[w1][r16][1];
    float sm = redbuf[w0][r16][2]+redbuf[w1][r16][2];
    float mxc = fmaxf(redbuf[w0][r16][3],redbuf[w1][r16][3]);
    float mxv = fmaxf(redbuf[w0][r16][4],redbuf[w1][r16][4]);
    int row = p*NTOK + n0 + tid;
    float vr = sm * (1.0f/1024.0f);
    var_row[row] = vr;
    mxcosA[row] = mxc; mxcovA[row] = mxv;
    // fused row-finish: per-row moments -> racc
    double dv = (double)vr;
    double rc = (double)sc, rv = (double)sv;
    double vals2[6];
    vals2[0] = 1024.0*dv;
    vals2[1] = 1024.0*dv*dv;
    vals2[2] = dv*rc;
    vals2[3] = dv*rv;
    vals2[4] = rc;
    vals2[5] = rv;
    int hh = p >> 2;
    #pragma unroll
    for (int c2 = 0; c2 < 6; ++c2){
      double vv = vals2[c2];
      vv += __shfl_down(vv,16);
      vv += __shfl_down(vv,8);
      vv += __shfl_down(vv,4);
      vv += __shfl_down(vv,2);
      vv += __shfl_down(vv,1);
      if (tid==0) atomicAdd(&racc[hh*6+c2], vv);
    }
  }
  if (tid == 0){
    int h = p >> 2;
    #pragma unroll
    for (int c2=0;c2<3;++c2){
      double t = wredS[0][c2]+wredS[1][c2]+wredS[2][c2]+wredS[3][c2];
      atomicAdd(&gacc[h*3+c2], t);
    }
  }
}

// ------------------------------------- finalize scalars -> d2 coefficients

__global__ void k_final(const double* __restrict__ gacc, const double* __restrict__ racc,
                        const float* __restrict__ wp_out, float* __restrict__ coef){
  if (threadIdx.x != 0) return;
  const double N = 33554432.0;
  double Sc1=0,Sc2=0,Sv1=0,Sv2=0,Sr1=0,Sr2=0;
  for (int h=0;h<8;++h){
    Sc2+=gacc[h*3+0]; Sv2+=gacc[h*3+1];
    Sr1+=racc[h*6+0]; Sr2+=racc[h*6+1];
    Sc1+=racc[h*6+4]; Sv1+=racc[h*6+5];
  }
  double cvar = (Sc2 - Sc1*Sc1/N)/(N-1.0);
  double cn = sqrt(fmax(cvar,0.0)) + 1e-6;
  double cscale = (cn < 1e-4) ? 0.1 : 1.0;
  double vraw = (Sv2 - Sv1*Sv1/N)/(N-1.0);
  double sraw = sqrt(fmax(vraw,0.0));
  double basev = 0.001/1024.0;
  double regv = (sraw < 1e-6) ? basev*10.0 : basev;
  double covn = regv*sraw + 1e-6;
  double vvar = (Sr2 - Sr1*Sr1/N)/(N-1.0);
  double vn = sqrt(fmax(vvar,0.0)) + 1e-6;
  double ah[8], bh[8], chh[8];
  double Sd1=0.0, Sd2=0.0;
  for (int h=0;h<8;++h){
    double a = (double)wp_out[h*3+0]/cn*cscale;
    double b = (double)wp_out[h*3+1]*regv*0.5/covn;
    double c = (double)wp_out[h*3+2]*0.5/vn;
    ah[h]=a; bh[h]=b; chh[h]=c;
    Sd1 += a*racc[h*6+4] + b*racc[h*6+5] + c*racc[h*6+0];
    Sd2 += a*a*gacc[h*3+0] + b*b*gacc[h*3+1] + c*c*racc[h*6+1]
         + 2.0*(a*b*gacc[h*3+2] + a*c*racc[h*6+2] + b*c*racc[h*6+3]);
  }
  double dvar = (Sd2 - Sd1*Sd1/N)/(N-1.0);
  double dstd = sqrt(fmax(dvar,0.0));
  double temp = (dstd < 1e-6) ? 0.1 : 0.3 + dstd;
  double tcl = fmin(fmax(temp,0.1),5.0);
  double it = 1.0/tcl;
  for (int h=0;h<8;++h){
    coef[h*3+0] = (float)(ah[h]*it);
    coef[h*3+1] = (float)(bh[h]*it);
    coef[h*3+2] = (float)(chh[h]*it);
  }
}

// -------------------- pass C (MFMA): K/V direct from L2; P-transpose in
// LDS (double-buffered, stride 72: 16B-aligned rows; the 2-way write
// aliasing it causes is free per bank rules — stride 76 broke b128
// alignment of the P reads and cost ~16 us).

__global__ __launch_bounds__(256) void k_pv(
    const unsigned short* __restrict__ fqh, const unsigned short* __restrict__ fql,
    const unsigned short* __restrict__ fkh, const unsigned short* __restrict__ fkl,
    const unsigned short* __restrict__ fvTh, const unsigned short* __restrict__ fvTl,
    const float* __restrict__ inv_na_q, const float* __restrict__ muqA,
    const float* __restrict__ tqA,
    const float* __restrict__ inv_na_k, const float* __restrict__ skA,
    const float* __restrict__ Sarr, const float* __restrict__ var_row,
    const float* __restrict__ mxcosA, const float* __restrict__ mxcovA,
    const float* __restrict__ coef,
    unsigned short* __restrict__ ohh, unsigned short* __restrict__ ohl){
  __shared__ __align__(16) unsigned short ph[2][32][72];
  __shared__ float denbuf[4][16];
  __shared__ float dnv[32];
  int b = blockIdx.x;
  int p = ((b&7)<<2) | ((b>>3)&3);   // XCD swizzle
  int s = b>>5;
  int n0 = s*32;
  int h = p>>2, qb = p&3;
  int tid = threadIdx.x, w = tid>>6, l = tid&63;
  int lm = l&15, q = l>>4;
  int rt = w&1, cw = w>>1;
  int nw = n0 + rt*16;
  float A = coef[h*3+0], B = coef[h*3+1], C = coef[h*3+2];
  float Sp = Sarr[p];
  const float inv8 = (float)(1.0/(8.0+1e-6));
  float B8 = B*inv8;
  float ia[4], bm[4], o2[4];
  #pragma unroll
  for (int i=0;i<4;++i){
    int rg = p*NTOK + nw + q*4 + i;
    float mq = muqA[rg];
    ia[i] = inv_na_q[rg];
    bm[i] = B8*mq;
    float tq2 = tqA[rg] - mq*Sp;
    float vr = var_row[rg];
    float Mh = A*mxcosA[rg] + B*mxcovA[rg] + C*vr;
    o2[i] = (C*vr - Mh) - B8*tq2;
  }
  const short8* aqh = (const short8*)(fqh + (size_t)(p*NTOK + nw + lm)*DH);
  const short8* aql = (const short8*)(fql + (size_t)(p*NTOK + nw + lm)*DH);
  short8 ah0 = aqh[q], ah1 = aqh[4+q], al0 = aql[q], al1 = aql[4+q];
  const unsigned short* gKh = fkh  + (size_t)p*16*4096;
  const unsigned short* gKl = fkl  + (size_t)p*16*4096;
  const unsigned short* gVh = fvTh + (size_t)p*16*4096;
  const unsigned short* gVl = fvTl + (size_t)p*16*4096;
  const float* cAg = inv_na_k + p*NTOK;
  const float* cSg = skA + p*NTOK;
  f32x4 o0 = {0.f,0.f,0.f,0.f}, o1 = {0.f,0.f,0.f,0.f};
  float den[4] = {0.f,0.f,0.f,0.f};
  int ko0 = ((q  )*64 + (cw*2)*16+lm)*8;
  int ko1 = ((q+4)*64 + (cw*2)*16+lm)*8;
  int vo0 = ((q  )*64 + w*16+lm)*8;
  int vo1 = ((q+4)*64 + w*16+lm)*8;
  int c0 = s & 15;                   // rotation offset

#define PV_KLOAD(K, cc_) do{ \
    const unsigned short* cbh_ = gKh + (size_t)(cc_)*4096; \
    const unsigned short* cbl_ = gKl + (size_t)(cc_)*4096; \
    K[0] = *(const short8*)(cbh_ + ko0); \
    K[1] = *(const short8*)(cbh_ + ko1); \
    K[2] = *(const short8*)(cbl_ + ko0); \
    K[3] = *(const short8*)(cbl_ + ko1); \
    K[4] = *(const short8*)(cbh_ + ko0 + 128); \
    K[5] = *(const short8*)(cbh_ + ko1 + 128); \
    K[6] = *(const short8*)(cbl_ + ko0 + 128); \
    K[7] = *(const short8*)(cbl_ + ko1 + 128); \
  }while(0)

#define PV_QK(K, cc_, phc_) do{ \
    _Pragma("unroll") \
    for (int t2=0; t2<2; ++t2){ \
      int c16 = cw*2 + t2; \
      f32x4 acc = {0.f,0.f,0.f,0.f}; \
      acc = mfma16(ah0,K[t2*4+0],acc); acc = mfma16(ah1,K[t2*4+1],acc); \
      acc = mfma16(al0,K[t2*4+0],acc); acc = mfma16(al1,K[t2*4+1],acc); \
      acc = mfma16(ah0,K[t2*4+2],acc); acc = mfma16(ah1,K[t2*4+3],acc); \
      int colg = (cc_)*64 + c16*16 + lm; \
      float ca = cAg[colg], cs = cSg[colg]; \
      _Pragma("unroll") \
      for (int i=0;i<4;++i){ \
        float dot = acc[i]; \
        float cosv = fminf(fmaxf(dot*ia[i]*ca,-0.99f),0.99f); \
        float arg = fmaf(A, cosv, fmaf(-bm[i], cs, fmaf(B8, dot, o2[i]))); \
        float e = __expf(arg); \
        unsigned short us = f2h(e); \
        phc_[rt*16+q*4+i][c16*16+lm] = us; \
        den[i] += h2f(us); \
      } \
    } \
  }while(0)

#define PV_TAIL(cc_, phc_) do{ \
    const unsigned short* cvh_ = gVh + (size_t)(cc_)*4096; \
    const unsigned short* cvl_ = gVl + (size_t)(cc_)*4096; \
    half8 vh0 = *(const half8*)(cvh_ + vo0); \
    half8 vh1 = *(const half8*)(cvh_ + vo1); \
    half8 vl0 = *(const half8*)(cvl_ + vo0); \
    half8 vl1 = *(const half8*)(cvl_ + vo1); \
    __syncthreads(); \
    half8 pb00 = *(const half8*)&phc_[lm][q*8]; \
    half8 pb01 = *(const half8*)&phc_[lm][32+q*8]; \
    half8 pb10 = *(const half8*)&phc_[16+lm][q*8]; \
    half8 pb11 = *(const half8*)&phc_[16+lm][32+q*8]; \
    o0 = mfma16f(vh0,pb00,o0); o0 = mfma16f(vl0,pb00,o0); \
    o0 = mfma16f(vh1,pb01,o0); o0 = mfma16f(vl1,pb01,o0); \
    o1 = mfma16f(vh0,pb10,o1); o1 = mfma16f(vl0,pb10,o1); \
    o1 = mfma16f(vh1,pb11,o1); o1 = mfma16f(vl1,pb11,o1); \
  }while(0)

  short8 KA[8], KB[8];
  PV_KLOAD(KA, c0);
  for (int t = 0; t < 16; t += 2){
    int ccA = (t + c0) & 15;
    int ccB = (t + 1 + c0) & 15;
    PV_KLOAD(KB, ccB);
    {
      unsigned short (*phc)[72] = ph[0];
      PV_QK(KA, ccA, phc);
      PV_TAIL(ccA, phc);
    }
    if (t < 14){
      int ccA2 = (t + 2 + c0) & 15;
      PV_KLOAD(KA, ccA2);
    }
    {
      unsigned short (*phc)[72] = ph[1];
      PV_QK(KB, ccB, phc);
      PV_TAIL(ccB, phc);
    }
  }
#undef PV_KLOAD
#undef PV_QK
#undef PV_TAIL

  #pragma unroll
  for (int m=1;m<16;m<<=1){
    #pragma unroll
    for (int i=0;i<4;++i) den[i] += __shfl_xor(den[i],m);
  }
  if (lm==0){
    #pragma unroll
    for (int i=0;i<4;++i) denbuf[w][q*4+i] = den[i];
  }
  __syncthreads();
  if (tid < 32){
    int rt2 = tid>>4, r16 = tid&15;
    dnv[tid] = 1.0f/(denbuf[rt2][r16] + denbuf[rt2+2][r16]);
  }
  __syncthreads();
  {
    float inv0 = dnv[lm];
    float inv1 = dnv[16+lm];
    int dcol = h*64 + w*16 + q*4;
    int row0 = qb*NTOK + n0 + lm;
    int row1 = row0 + 16;
    size_t b0i = cidx(row0, dcol);
    size_t b1i = cidx(row1, dcol);
    ushort4 h0,l0,h1,l1;
    { float xx=o0[0]*inv0; unsigned short hh=f2bf(xx); h0.x=hh; l0.x=f2bf(xx-bf2f(hh)); }
    { float xx=o0[1]*inv0; unsigned short hh=f2bf(xx); h0.y=hh; l0.y=f2bf(xx-bf2f(hh)); }
    { float xx=o0[2]*inv0; unsigned short hh=f2bf(xx); h0.z=hh; l0.z=f2bf(xx-bf2f(hh)); }
    { float xx=o0[3]*inv0; unsigned short hh=f2bf(xx); h0.w=hh; l0.w=f2bf(xx-bf2f(hh)); }
    { float xx=o1[0]*inv1; unsigned short hh=f2bf(xx); h1.x=hh; l1.x=f2bf(xx-bf2f(hh)); }
    { float xx=o1[1]*inv1; unsigned short hh=f2bf(xx); h1.y=hh; l1.y=f2bf(xx-bf2f(hh)); }
    { float xx=o1[2]*inv1; unsigned short hh=f2bf(xx); h1.z=hh; l1.z=f2bf(xx-bf2f(hh)); }
    { float xx=o1[3]*inv1; unsigned short hh=f2bf(xx); h1.w=hh; l1.w=f2bf(xx-bf2f(hh)); }
    *(ushort4*)(ohh+b0i)=h0; *(ushort4*)(ohl+b0i)=l0;
    *(ushort4*)(ohh+b1i)=h1; *(ushort4*)(ohl+b1i)=l1;
  }
}

// ----------------- output GEMM (MFMA): A and W staged via global_load_lds.

__global__ __launch_bounds__(256) void k_outmm(
    const unsigned short* __restrict__ ohh, const unsigned short* __restrict__ ohl,
    const unsigned short* __restrict__ Woth, const unsigned short* __restrict__ Wotl,
    const float* __restrict__ bias, float* __restrict__ out){
  __shared__ __align__(16) unsigned short Ah[4096];
  __shared__ __align__(16) unsigned short Al[4096];
  __shared__ __align__(16) unsigned short W0h[4096];
  __shared__ __align__(16) unsigned short W0l[4096];
  __shared__ __align__(16) unsigned short W1h[4096];
  __shared__ __align__(16) unsigned short W1l[4096];
  int mb = blockIdx.x, nb = blockIdx.y;
  int tid = threadIdx.x, w = tid>>6, l = tid&63, lm = l&15, qd = l>>4;
  int rh = w&1, tile = w>>1;
  int cbase = nb*128 + tile*64;
  f32x4 acc[2][4];
  #pragma unroll
  for (int mt=0;mt<2;++mt)
    #pragma unroll
    for (int nt=0;nt<4;++nt) acc[mt][nt] = (f32x4){0.f,0.f,0.f,0.f};
  int r0 = mb & 7;
  for (int t=0; t<8; ++t){
    int kc8 = (t + r0) & 7;
    __syncthreads();
    {
      const unsigned short* aSh = ohh  + ((size_t)(mb*8+kc8))*4096;
      const unsigned short* aSl = ohl  + ((size_t)(mb*8+kc8))*4096;
      const unsigned short* s0h = Woth + ((size_t)((nb*2  )*8+kc8))*4096;
      const unsigned short* s0l = Wotl + ((size_t)((nb*2  )*8+kc8))*4096;
      const unsigned short* s1h = Woth + ((size_t)((nb*2+1)*8+kc8))*4096;
      const unsigned short* s1l = Wotl + ((size_t)((nb*2+1)*8+kc8))*4096;
      if (w==0){
        #pragma unroll
        for (int j=0;j<8;++j) dma16(aSh + j*512 + l*8, &Ah[j*512]);
        #pragma unroll
        for (int j=0;j<4;++j) dma16(s1h + j*512 + l*8, &W1h[j*512]);
      } else if (w==1){
        #pragma unroll
        for (int j=0;j<8;++j) dma16(aSl + j*512 + l*8, &Al[j*512]);
        #pragma unroll
        for (int j=4;j<8;++j) dma16(s1h + j*512 + l*8, &W1h[j*512]);
      } else if (w==2){
        #pragma unroll
        for (int j=0;j<8;++j) dma16(s0h + j*512 + l*8, &W0h[j*512]);
        #pragma unroll
        for (int j=0;j<4;++j) dma16(s1l + j*512 + l*8, &W1l[j*512]);
      } else {
        #pragma unroll
        for (int j=0;j<8;++j) dma16(s0l + j*512 + l*8, &W0l[j*512]);
        #pragma unroll
        for (int j=4;j<8;++j) dma16(s1l + j*512 + l*8, &W1l[j*512]);
      }
    }
    __syncthreads();
    const unsigned short* Wh_ = tile ? W1h : W0h;
    const unsigned short* Wl_ = tile ? W1l : W0l;
    #pragma unroll
    for (int kch=0; kch<2; ++kch){
      short8 a_h[2], a_l[2];
      #pragma unroll
      for (int mt=0;mt<2;++mt){
        int off = ((kch*4+qd)*64 + rh*32 + mt*16 + lm)*8;
        a_h[mt] = *(const short8*)(Ah + off);
        a_l[mt] = *(const short8*)(Al + off);
      }
      #pragma unroll
      for (int nt=0;nt<4;++nt){
        int off = ((kch*4+qd)*64 + nt*16+lm)*8;
        short8 bh = *(const short8*)(Wh_ + off);
        short8 bl = *(const short8*)(Wl_ + off);
        #pragma unroll
        for (int mt=0;mt<2;++mt){
          acc[mt][nt] = mfma16(a_h[mt], bh, acc[mt][nt]);
          acc[mt][nt] = mfma16(a_h[mt], bl, acc[mt][nt]);
          acc[mt][nt] = mfma16(a_l[mt], bh, acc[mt][nt]);
        }
      }
    }
  }
  float bv[4];
  #pragma unroll
  for (int nt=0;nt<4;++nt) bv[nt] = bias[cbase+nt*16+lm];
  #pragma unroll
  for (int mt=0;mt<2;++mt){
    #pragma unroll
    for (int i=0;i<4;++i){
      int row = mb*64 + rh*32 + mt*16 + qd*4 + i;
      #pragma unroll
      for (int nt=0;nt<4;++nt){
        out[(size_t)row*DIMX + cbase + nt*16 + lm] = acc[mt][nt][i] + bv[nt];
      }
    }
  }
}

// ----------------------------------------------------------------- launch

extern "C" void kernel_launch(void* const* d_in, const int* in_sizes, int n_in,
                              void* d_out, int out_size, void* d_ws, size_t ws_size,
                              hipStream_t stream) {
  (void)in_sizes; (void)n_in; (void)out_size;
  const float* q     = (const float*)d_in[0];
  const float* k     = (const float*)d_in[1];
  const float* v     = (const float*)d_in[2];
  const float* ln_g  = (const float*)d_in[3];
  const float* ln_b  = (const float*)d_in[4];
  const float* W_in  = (const float*)d_in[5];
  const float* wp_W1 = (const float*)d_in[6];
  const float* wp_b1 = (const float*)d_in[7];
  const float* wp_lg = (const float*)d_in[8];
  const float* wp_lb = (const float*)d_in[9];
  const float* wp_W2 = (const float*)d_in[10];
  const float* wp_b2 = (const float*)d_in[11];
  const float* wp_W3 = (const float*)d_in[12];
  const float* wp_b3 = (const float*)d_in[13];
  const float* wtemp = (const float*)d_in[14];
  const float* W_out = (const float*)d_in[15];
  const float* b_out = (const float*)d_in[16];
  float* out = (float*)d_out;

  char* wsb = (char*)d_ws;
  double* gacc = (double*)wsb;            // 24 doubles
  double* racc = gacc + 24;               // 48
  double* qgs  = racc + 48;               // 512
  double* nusum= qgs + 512;               // 2048  (doubles end @ 21056 B)
  float* coefG  = (float*)(wsb + 21120);      // 24 floats, inside zeroed zone
  float* fvA = (float*)(wsb + 24576);     // 8 MB; reused as ohh/ohl after k_mid
  unsigned short* ohh = (unsigned short*)fvA;                   // 4 MB
  unsigned short* ohl = ohh + (size_t)NQB*NTOK*NH*DH;           // 4 MB
  float* mu_rstd = fvA + (size_t)NPAIR*NTOK*DH;   // 24576
  float* Sarr = mu_rstd + 24576;          // 64 (padded)
  float* inv_na_q = Sarr + 64;
  float* muqA     = inv_na_q + NROWS;
  float* tqA      = muqA + NROWS;
  float* inv_na_k = tqA + NROWS;
  float* skA      = inv_na_k + NROWS;
  float* var_row  = skA + NROWS;
  float* mxcos    = var_row + NROWS;
  float* mxcov    = mxcos + NROWS;
  float* wp_out   = mxcov + NROWS;        // 32 (padded)
  float* endf     = wp_out + 32;
  size_t off16 = (size_t)((char*)endf - wsb);
  off16 = (off16 + 63) & ~(size_t)63;
  unsigned short* fqh  = (unsigned short*)(wsb + off16);
  unsigned short* fql  = fqh  + (size_t)NPAIR*NTOK*DH;
  unsigned short* fkh  = fql  + (size_t)NPAIR*NTOK*DH;
  unsigned short* fkl  = fkh  + (size_t)NPAIR*NTOK*DH;
  unsigned short* fvTh = fkl  + (size_t)NPAIR*NTOK*DH;
  unsigned short* fvTl = fvTh + (size_t)NPAIR*NTOK*DH;
  unsigned short* Wth  = fvTl + (size_t)NPAIR*NTOK*DH;
  unsigned short* Wtl  = Wth  + (size_t)DIMX*DIMX;
  unsigned short* Woth = Wtl  + (size_t)DIMX*DIMX;
  unsigned short* Wotl = Woth + (size_t)DIMX*DIMX;
  size_t need = (size_t)((char*)(Wotl + (size_t)DIMX*DIMX) - wsb);
  if (ws_size < need) return;  // fail cleanly rather than corrupt

  k_pre<<<3201, 256, 0, stream>>>(q, k, v, mu_rstd, W_in, W_out,
                                  Wth, Wtl, Woth, Wotl, (float*)wsb);
  k_projmm<<<dim3(64,4,3), 256, 0, stream>>>(q, k, v, ln_g, ln_b, Wth, Wtl,
                                             mu_rstd, fqh, fql, fkh, fkl, fvA,
                                             qgs, nusum);
  k_mid<<<8705, 256, 0, stream>>>(fvA, fvTh, fvTl, fqh, fql, fkh, fkl, nusum,
                                  inv_na_q, muqA, tqA, inv_na_k, skA,
                                  qgs, wp_W1, wp_b1, wp_lg, wp_lb,
                                  wp_W2, wp_b2, wp_W3, wp_b3, wtemp,
                                  wp_out, Sarr);
  k_passA<<<1024, 256, 0, stream>>>(fqh, fql, fkh, fkl,
                                    inv_na_q, muqA, tqA, inv_na_k, skA, Sarr,
                                    var_row, mxcos, mxcov, gacc, racc);
  k_final<<<1, 64, 0, stream>>>(gacc, racc, wp_out, coefG);
  k_pv<<<1024, 256, 0, stream>>>(fqh, fql, fkh, fkl, fvTh, fvTl,
                                 inv_na_q, muqA, tqA, inv_na_k, skA, Sarr,
                                 var_row, mxcos, mxcov, coefG,
                                 ohh, ohl);
  k_outmm<<<dim3(64,4), 256, 0, stream>>>(ohh, ohl, Woth, Wotl, b_out, out);
}

// Round 11
// 239.202 us; speedup vs baseline: 1.1012x; 1.0509x over previous
//
#include <hip/hip_runtime.h>
#include <math.h>

#define NH    8
#define NQB   4
#define NPAIR 32
#define NTOK  1024
#define DH    64
#define DIMX  512
#define NROWS (NPAIR*NTOK)

typedef __attribute__((ext_vector_type(8))) short short8;
typedef _Float16 half8 __attribute__((ext_vector_type(8)));
typedef __attribute__((ext_vector_type(4))) float f32x4;

__device__ __forceinline__ unsigned short f2bf(float x){
  unsigned u = __float_as_uint(x);
  u += 0x7fffu + ((u>>16)&1u);
  return (unsigned short)(u>>16);
}
__device__ __forceinline__ float bf2f(unsigned short h){
  return __uint_as_float(((unsigned)h)<<16);
}
__device__ __forceinline__ unsigned short f2h(float x){
  union{ _Float16 f; unsigned short u; } c; c.f = (_Float16)x; return c.u;
}
__device__ __forceinline__ float h2f(unsigned short u){
  union{ _Float16 f; unsigned short u; } c; c.u = u; return (float)c.f;
}
__device__ __forceinline__ f32x4 mfma16(short8 a, short8 b, f32x4 c){
  return __builtin_amdgcn_mfma_f32_16x16x32_bf16(a,b,c,0,0,0);
}
__device__ __forceinline__ f32x4 mfma16f(half8 a, half8 b, f32x4 c){
  return __builtin_amdgcn_mfma_f32_16x16x32_f16(a,b,c,0,0,0);
}
// async global->LDS DMA, 16B per lane; LDS dest = base + lane*16
__device__ __forceinline__ void dma16(const void* g, void* l){
  __builtin_amdgcn_global_load_lds(
      (const __attribute__((address_space(1))) void*)g,
      (__attribute__((address_space(3))) void*)l, 16, 0, 0);
}

// chunk layout for 512-col matrices: [rowgrp64][colgrp64][cq8][row64][8]
__device__ __forceinline__ size_t cidx(int r, int c){
  return ((((size_t)((r>>6)*8 + (c>>6)))*8 + ((c&63)>>3))*64 + (r&63))*8 + (c&7);
}
// K layout: FK[p][kc][dq][k64][8]
__device__ __forceinline__ size_t kidx(int p, int key, int dh){
  return ((((size_t)(p*16 + (key>>6)))*8 + (dh>>3))*64 + (key&63))*8 + (dh&7);
}

// ---------------- fused prelude: LN stats | W split | accumulator zeroing

__global__ __launch_bounds__(256) void k_pre(
    const float* __restrict__ q, const float* __restrict__ k, const float* __restrict__ v,
    float* __restrict__ mu_rstd,
    const float* __restrict__ Wa, const float* __restrict__ Wb,
    unsigned short* __restrict__ Wth, unsigned short* __restrict__ Wtl,
    unsigned short* __restrict__ Woth, unsigned short* __restrict__ Wotl,
    float* __restrict__ zacc){
  __shared__ float tile[64][65];
  int b = blockIdx.x, tid = threadIdx.x;
  if (b < 3072){
    int wid = tid >> 6, lane = tid & 63;
    int tok = b*4 + wid;                   // 0..12287
    const float* src = (tok < 4096) ? q : ((tok < 8192) ? k : v);
    int t = tok & 4095;
    const float4* p4 = (const float4*)(src + (size_t)t*DIMX) + lane*2;
    float4 a = p4[0], bb = p4[1];
    float s  = a.x+a.y+a.z+a.w + bb.x+bb.y+bb.z+bb.w;
    float ss = a.x*a.x+a.y*a.y+a.z*a.z+a.w*a.w
             + bb.x*bb.x+bb.y*bb.y+bb.z*bb.z+bb.w*bb.w;
    #pragma unroll
    for (int off=32; off; off>>=1){ s += __shfl_down(s,off); ss += __shfl_down(ss,off); }
    if (lane==0){
      float mu = s*(1.0f/512.0f);
      float var = ss*(1.0f/512.0f) - mu*mu;
      mu_rstd[tok*2+0] = mu;
      mu_rstd[tok*2+1] = 1.0f/sqrtf(var + 1e-5f);
    }
  } else if (b < 3200){
    int sb = b - 3072;
    int z = sb >> 6, rem = sb & 63, kb = rem & 7, nb = rem >> 3;
    const float* W = z ? Wb : Wa;
    unsigned short* oh_ = z ? Woth : Wth;
    unsigned short* ol_ = z ? Wotl : Wtl;
    #pragma unroll
    for (int it=0; it<4; ++it){
      int idx = tid + 256*it;          // 0..1023
      int kr = idx>>4, c4 = idx&15;
      float4 vv = *(const float4*)(W + (size_t)(kb*64+kr)*DIMX + nb*64 + c4*4);
      tile[c4*4+0][kr]=vv.x; tile[c4*4+1][kr]=vv.y; tile[c4*4+2][kr]=vv.z; tile[c4*4+3][kr]=vv.w;
    }
    __syncthreads();
    #pragma unroll
    for (int it=0; it<4; ++it){
      int idx = tid + 256*it;
      int n = idx>>4, k4 = idx&15;
      size_t base = cidx(nb*64+n, kb*64+k4*4);
      ushort4 hv, lv;
      { float xx=tile[n][k4*4+0]; unsigned short hh=f2bf(xx); hv.x=hh; lv.x=f2bf(xx-bf2f(hh)); }
      { float xx=tile[n][k4*4+1]; unsigned short hh=f2bf(xx); hv.y=hh; lv.y=f2bf(xx-bf2f(hh)); }
      { float xx=tile[n][k4*4+2]; unsigned short hh=f2bf(xx); hv.z=hh; lv.z=f2bf(xx-bf2f(hh)); }
      { float xx=tile[n][k4*4+3]; unsigned short hh=f2bf(xx); hv.w=hh; lv.w=f2bf(xx-bf2f(hh)); }
      *(ushort4*)(oh_+base) = hv;
      *(ushort4*)(ol_+base) = lv;
    }
  } else {
    // zero 24576 B of accumulators (gacc/racc/qgs/nusum/coefG)
    uint4 z4 = {0u,0u,0u,0u};
    uint4* dst = (uint4*)zacc;
    #pragma unroll
    for (int i=0;i<6;++i) dst[tid + 256*i] = z4;
  }
}

// --------------- LN + projection GEMM via split-bf16 MFMA (q, k, v by z)

__global__ __launch_bounds__(256) void k_projmm(
    const float* __restrict__ q, const float* __restrict__ k, const float* __restrict__ v,
    const float* __restrict__ g, const float* __restrict__ bln,
    const unsigned short* __restrict__ Wth, const unsigned short* __restrict__ Wtl,
    const float* __restrict__ mu_rstd,
    unsigned short* __restrict__ fqh, unsigned short* __restrict__ fql,
    unsigned short* __restrict__ fkh, unsigned short* __restrict__ fkl,
    float* __restrict__ fv,
    double* __restrict__ qgs, double* __restrict__ nusum){
  __shared__ __align__(16) unsigned short Ahs[64*72];
  __shared__ __align__(16) unsigned short Als[64*72];
  __shared__ __align__(16) unsigned short WhL[2][4096];
  __shared__ __align__(16) unsigned short WlL[2][4096];
  __shared__ float scrc[4][128];
  int z = blockIdx.z;
  const float* x = (z==0) ? q : ((z==1) ? k : v);
  int mb = blockIdx.x, nb = blockIdx.y;
  int tid = threadIdx.x, w = tid>>6, l = tid&63, lm = l&15, qd = l>>4;
  int rbase = (w&1)*32;
  int tile = w>>1;
  int cbase = nb*128 + tile*64;
  scrc[tid>>7][tid&127] = 0.f;
  scrc[2+(tid>>7)][tid&127] = 0.f;
  f32x4 acc[2][4];
  #pragma unroll
  for (int mt=0;mt<2;++mt)
    #pragma unroll
    for (int nt=0;nt<4;++nt) acc[mt][nt] = (f32x4){0.f,0.f,0.f,0.f};
  int r0 = mb & 7;
  for (int t = 0; t < 8; ++t){
    int kc8 = (t + r0) & 7;
    float4 xv[4]; float mus[4], rss[4]; float4 gv[4], bv[4]; int rr[4], kk4[4];
    #pragma unroll
    for (int it=0; it<4; ++it){
      int idx = tid + 256*it;          // 0..1023
      int r = idx>>4, k4 = idx&15;
      rr[it]=r; kk4[it]=k4;
      int tokg = z*4096 + mb*64 + r;
      mus[it] = mu_rstd[tokg*2+0]; rss[it] = mu_rstd[tokg*2+1];
      xv[it] = *(const float4*)(x + (size_t)(mb*64+r)*DIMX + kc8*64 + k4*4);
      gv[it] = *(const float4*)(g   + kc8*64 + k4*4);
      bv[it] = *(const float4*)(bln + kc8*64 + k4*4);
    }
    __syncthreads();                   // prev chunk consumed
    {  // wave w stages W chunk: tile w>>1, hi/lo w&1
      int st = w>>1, hl = w&1;
      const unsigned short* src = (hl ? Wtl : Wth)
          + ((size_t)((nb*2+st)*8 + kc8))*4096;
      unsigned short* dst = hl ? WlL[st] : WhL[st];
      #pragma unroll
      for (int j=0;j<8;++j) dma16(src + j*512 + l*8, dst + j*512);
    }
    #pragma unroll
    for (int it=0; it<4; ++it){
      float y0 = (xv[it].x-mus[it])*rss[it]*gv[it].x + bv[it].x;
      float y1 = (xv[it].y-mus[it])*rss[it]*gv[it].y + bv[it].y;
      float y2 = (xv[it].z-mus[it])*rss[it]*gv[it].z + bv[it].z;
      float y3 = (xv[it].w-mus[it])*rss[it]*gv[it].w + bv[it].w;
      ushort4 hv, lv;
      { unsigned short hh=f2bf(y0); hv.x=hh; lv.x=f2bf(y0-bf2f(hh)); }
      { unsigned short hh=f2bf(y1); hv.y=hh; lv.y=f2bf(y1-bf2f(hh)); }
      { unsigned short hh=f2bf(y2); hv.z=hh; lv.z=f2bf(y2-bf2f(hh)); }
      { unsigned short hh=f2bf(y3); hv.w=hh; lv.w=f2bf(y3-bf2f(hh)); }
      *(ushort4*)(Ahs + rr[it]*72 + kk4[it]*4) = hv;
      *(ushort4*)(Als + rr[it]*72 + kk4[it]*4) = lv;
    }
    __syncthreads();                   // staging + DMA visible
    #pragma unroll
    for (int kch=0; kch<2; ++kch){
      short8 a_h[2], a_l[2];
      #pragma unroll
      for (int mt=0;mt<2;++mt){
        a_h[mt] = *(const short8*)(Ahs + (rbase+mt*16+lm)*72 + kch*32 + qd*8);
        a_l[mt] = *(const short8*)(Als + (rbase+mt*16+lm)*72 + kch*32 + qd*8);
      }
      #pragma unroll
      for (int nt=0;nt<4;++nt){
        int off = ((kch*4+qd)*64 + nt*16+lm)*8;
        short8 bh = *(const short8*)(WhL[tile] + off);
        short8 bl = *(const short8*)(WlL[tile] + off);
        #pragma unroll
        for (int mt=0;mt<2;++mt){
          acc[mt][nt] = mfma16(a_h[mt], bh, acc[mt][nt]);
          acc[mt][nt] = mfma16(a_h[mt], bl, acc[mt][nt]);
          acc[mt][nt] = mfma16(a_l[mt], bh, acc[mt][nt]);
        }
      }
    }
  }
  int head = cbase >> 6;
  if (z < 2){
    float csum[4] = {0.f,0.f,0.f,0.f};
    #pragma unroll
    for (int mt=0;mt<2;++mt){
      #pragma unroll
      for (int nt=0;nt<4;++nt){
        #pragma unroll
        for (int i=0;i<4;++i){
          float val = acc[mt][nt][i];
          csum[nt] += val;
          int tglob = mb*64 + rbase + mt*16 + qd*4 + i;
          int qb = tglob>>10, n = tglob&1023;
          int p = head*4 + qb;
          int d = nt*16 + lm;
          unsigned short hh = f2bf(val);
          unsigned short ll = f2bf(val - bf2f(hh));
          if (z==0){
            size_t ix = ((size_t)(p*NTOK+n))*DH + d;
            fqh[ix] = hh; fql[ix] = ll;
          } else {
            size_t ix = kidx(p, n, d);
            fkh[ix] = hh; fkl[ix] = ll;
          }
        }
      }
    }
    #pragma unroll
    for (int m=16;m<64;m<<=1){
      #pragma unroll
      for (int nt=0;nt<4;++nt) csum[nt] += __shfl_xor(csum[nt], m);
    }
    if (qd==0){
      #pragma unroll
      for (int nt=0;nt<4;++nt) scrc[w][tile*64 + nt*16 + lm] = csum[nt];
    }
    __syncthreads();
    if (tid < 128){
      float s = scrc[0][tid]+scrc[1][tid]+scrc[2][tid]+scrc[3][tid];
      if (z==0){
        atomicAdd(&qgs[nb*128 + tid], (double)s);
      } else {
        int col = nb*128 + tid;
        int hh2 = col>>6, d = col&63;
        int qb = mb>>4;
        atomicAdd(&nusum[(size_t)(hh2*4+qb)*DH + d], (double)s);
      }
    }
  } else {
    #pragma unroll
    for (int mt=0;mt<2;++mt){
      #pragma unroll
      for (int nt=0;nt<4;++nt){
        #pragma unroll
        for (int i=0;i<4;++i){
          int tglob = mb*64 + rbase + mt*16 + qd*4 + i;
          int qb = tglob>>10, n = tglob&1023;
          int p = head*4 + qb;
          int d = nt*16 + lm;
          fv[((size_t)(p*NTOK+n))*DH + d] = acc[mt][nt][i];
        }
      }
    }
  }
}

// ------- fused mid pass: fv transpose | per-row scalars | weight predictor

__global__ __launch_bounds__(256) void k_mid(
    const float* __restrict__ fv,
    unsigned short* __restrict__ fvTh, unsigned short* __restrict__ fvTl,
    const unsigned short* __restrict__ fqh, const unsigned short* __restrict__ fql,
    const unsigned short* __restrict__ fkh, const unsigned short* __restrict__ fkl,
    const double* __restrict__ nusum,
    float* __restrict__ inv_na_q, float* __restrict__ muqA, float* __restrict__ tqA,
    float* __restrict__ inv_na_k, float* __restrict__ skA,
    const double* __restrict__ qgs,
    const float* __restrict__ W1, const float* __restrict__ b1,
    const float* __restrict__ lgv, const float* __restrict__ lbv,
    const float* __restrict__ W2, const float* __restrict__ b2,
    const float* __restrict__ W3, const float* __restrict__ b3,
    const float* __restrict__ wtemp, float* __restrict__ wp_out,
    float* __restrict__ Sarr){
  __shared__ __align__(16) float msm[64*65];
  int b = blockIdx.x, tid = threadIdx.x;
  if (b < 512){
    float (*tile)[65] = (float(*)[65])msm;
    int mc = b & 15, p = b >> 4;
    #pragma unroll
    for (int it=0; it<4; ++it){
      int idx = tid + 256*it;
      int m = idx>>4, d4 = idx&15;
      float4 vv = *(const float4*)(fv + ((size_t)(p*NTOK + mc*64 + m)*DH + d4*4));
      tile[d4*4+0][m]=vv.x; tile[d4*4+1][m]=vv.y; tile[d4*4+2][m]=vv.z; tile[d4*4+3][m]=vv.w;
    }
    __syncthreads();
    #pragma unroll
    for (int it=0; it<2; ++it){
      int idx = tid + 256*it;       // 0..511
      int d = idx>>3, seg = idx&7;  // keys seg*8..seg*8+8
      size_t base = ((((size_t)(p*16+mc))*8 + seg)*64 + d)*8;
      ushort4 h0,h1v,l0,l1;
      { float xx=tile[d][seg*8+0]; unsigned short hh=f2h(xx); h0.x=hh; l0.x=f2h(xx-h2f(hh)); }
      { float xx=tile[d][seg*8+1]; unsigned short hh=f2h(xx); h0.y=hh; l0.y=f2h(xx-h2f(hh)); }
      { float xx=tile[d][seg*8+2]; unsigned short hh=f2h(xx); h0.z=hh; l0.z=f2h(xx-h2f(hh)); }
      { float xx=tile[d][seg*8+3]; unsigned short hh=f2h(xx); h0.w=hh; l0.w=f2h(xx-h2f(hh)); }
      { float xx=tile[d][seg*8+4]; unsigned short hh=f2h(xx); h1v.x=hh; l1.x=f2h(xx-h2f(hh)); }
      { float xx=tile[d][seg*8+5]; unsigned short hh=f2h(xx); h1v.y=hh; l1.y=f2h(xx-h2f(hh)); }
      { float xx=tile[d][seg*8+6]; unsigned short hh=f2h(xx); h1v.z=hh; l1.z=f2h(xx-h2f(hh)); }
      { float xx=tile[d][seg*8+7]; unsigned short hh=f2h(xx); h1v.w=hh; l1.w=f2h(xx-h2f(hh)); }
      *(ushort4*)(fvTh+base)   = h0;
      *(ushort4*)(fvTh+base+4) = h1v;
      *(ushort4*)(fvTl+base)   = l0;
      *(ushort4*)(fvTl+base+4) = l1;
    }
  } else if (b < 8704){
    int rb = b - 512;
    int wid = tid >> 6, lane = tid & 63;
    int row = rb*4 + wid;            // < 32768
    int p = row >> 10;
    int key = row & 1023;
    size_t ix = (size_t)row*DH + lane;
    float xq = bf2f(fqh[ix]) + bf2f(fql[ix]);
    float nv = (float)(nusum[(size_t)p*DH + lane] * (1.0/1024.0));
    float s = xq, ss = xq*xq, sd = xq*nv;
    #pragma unroll
    for (int off=32; off; off>>=1){
      s += __shfl_down(s,off); ss += __shfl_down(ss,off); sd += __shfl_down(sd,off);
    }
    if (lane==0){
      float nrm = sqrtf(ss);
      inv_na_q[row] = 1.0f/(nrm+1e-8f);
      muqA[row] = s*(1.0f/64.0f);
      tqA[row] = sd;
    }
    size_t ixk = kidx(p, key, lane);
    float xk = bf2f(fkh[ixk]) + bf2f(fkl[ixk]);
    float s2 = xk, ss2 = xk*xk;
    #pragma unroll
    for (int off=32; off; off>>=1){
      s2 += __shfl_down(s2,off); ss2 += __shfl_down(ss2,off);
    }
    if (lane==0){
      float nrm = sqrtf(ss2);
      inv_na_k[row] = 1.0f/(nrm+1e-8f);
      skA[row] = s2;
    }
  } else {
    // weight predictor + Sarr (single block)
    float* feats = msm;           // 8*128
    float* h1    = msm + 1024;    // 8*64
    float* h2s   = msm + 1536;    // 8*32
    float* lgt   = msm + 1792;    // 8*3 (stride 3)
    float* mv    = msm + 1832;    // 8*2
    for (int idx = tid; idx < 1024; idx += 256){
      int h = idx >> 7, i = idx & 127;
      double vv;
      if (i < 64){
        vv = qgs[h*64+i];
      } else {
        int d = i - 64;
        vv = nusum[(size_t)(h*4+0)*DH+d] + nusum[(size_t)(h*4+1)*DH+d]
           + nusum[(size_t)(h*4+2)*DH+d] + nusum[(size_t)(h*4+3)*DH+d];
      }
      feats[h*128+i] = (float)(vv * (1.0/4096.0));
    }
    if (tid < 32){
      double s = 0.0;
      for (int d = 0; d < 64; ++d) s += nusum[(size_t)tid*DH + d];
      Sarr[tid] = (float)(s * (1.0/1024.0));
    }
    __syncthreads();
    for (int idx = tid; idx < 512; idx += 256){
      int h = idx >> 6, j = idx & 63;
      float s = b1[j];
      for (int i = 0; i < 128; ++i) s += feats[h*128+i]*W1[i*64+j];
      h1[h*64+j] = s;
    }
    __syncthreads();
    if (tid < 8){
      float s=0.f, ss=0.f;
      for (int j=0;j<64;++j){ float vv=h1[tid*64+j]; s+=vv; ss+=vv*vv; }
      float mu = s*(1.0f/64.0f);
      float var = ss*(1.0f/64.0f)-mu*mu;
      mv[tid*2+0]=mu; mv[tid*2+1]=1.0f/sqrtf(var+1e-5f);
    }
    __syncthreads();
    for (int idx = tid; idx < 512; idx += 256){
      int h = idx>>6, j = idx&63;
      float vv = (h1[h*64+j]-mv[h*2+0])*mv[h*2+1]*lgv[j] + lbv[j];
      h1[h*64+j] = fmaxf(vv, 0.f);
    }
    __syncthreads();
    {
      int h = tid >> 5, j = tid & 31;
      float s = b2[j];
      for (int i=0;i<64;++i) s += h1[h*64+i]*W2[i*32+j];
      h2s[h*32+j] = fmaxf(s, 0.f);
    }
    __syncthreads();
    if (tid < 24){
      int h = tid/3, j = tid - h*3;
      float s = b3[j];
      for (int i=0;i<32;++i) s += h2s[h*32+i]*W3[i*3+j];
      lgt[h*3+j] = s;
    }
    __syncthreads();
    if (tid < 8){
      int h = tid;
      float z0=lgt[h*3+0], z1=lgt[h*3+1], z2=lgt[h*3+2];
      float m = fmaxf(z0,fmaxf(z1,z2));
      float e0=expf(z0-m), e1=expf(z1-m), e2=expf(z2-m);
      float inv = 1.0f/(e0+e1+e2);
      float l0=e0*inv, l1=e1*inv, l2=e2*inv;
      float wt = fminf(fmaxf(wtemp[0], 0.1f), 20.0f);
      float y0=l0/wt, y1=l1/wt, y2=l2/wt;
      float m2 = fmaxf(y0,fmaxf(y1,y2));
      float f0=expf(y0-m2), f1=expf(y1-m2), f2=expf(y2-m2);
      float inv2 = 1.0f/(f0+f1+f2);
      float w0=f0*inv2, w1=f1*inv2, w2=f2*inv2;
      w0 = fminf(fmaxf(w0,0.05f),0.8f);
      w1 = fminf(fmaxf(w1,0.05f),0.8f);
      w2 = fminf(fmaxf(w2,0.05f),0.8f);
      float isum = 1.0f/(w0+w1+w2);
      wp_out[h*3+0]=w0*isum; wp_out[h*3+1]=w1*isum; wp_out[h*3+2]=w2*isum;
    }
  }
}

// ------------- pass A (MFMA): KA/KB register prefetch; float-only epilogue
// (rowfin un-fused — its fp64 state cost ~16 VGPR and ~25% occupancy).

__global__ __launch_bounds__(256) void k_passA(
    const unsigned short* __restrict__ fqh, const unsigned short* __restrict__ fql,
    const unsigned short* __restrict__ fkh, const unsigned short* __restrict__ fkl,
    const float* __restrict__ inv_na_q, const float* __restrict__ muqA,
    const float* __restrict__ tqA,
    const float* __restrict__ inv_na_k, const float* __restrict__ skA,
    const float* __restrict__ Sarr,
    float* __restrict__ rs_cos, float* __restrict__ rs_cov, float* __restrict__ rs_marg,
    float* __restrict__ mxcosA, float* __restrict__ mxcovA,
    double* __restrict__ gacc){
  __shared__ float redbuf[4][16][5];
  __shared__ double wredS[4][3];
  int b = blockIdx.x;
  int p = ((b&7)<<2) | ((b>>3)&3);   // XCD swizzle
  int s = b>>5;                      // 0..31
  int n0 = s*32;
  int tid = threadIdx.x, w = tid>>6, l = tid&63;
  int lm = l&15, q = l>>4;
  int rt = w&1, cw = w>>1;
  int nw = n0 + rt*16;
  float Sp = Sarr[p];
  const float inv8 = (float)(1.0/(8.0+1e-6));
  float ia[4], m8[4], t8[4];
  #pragma unroll
  for (int i=0;i<4;++i){
    int rg = p*NTOK + nw + q*4 + i;
    float mq = muqA[rg];
    ia[i] = inv_na_q[rg];
    m8[i] = mq*inv8;
    t8[i] = (tqA[rg] - mq*Sp)*inv8;
  }
  const short8* aqh = (const short8*)(fqh + (size_t)(p*NTOK + nw + lm)*DH);
  const short8* aql = (const short8*)(fql + (size_t)(p*NTOK + nw + lm)*DH);
  short8 ah0 = aqh[q], ah1 = aqh[4+q], al0 = aql[q], al1 = aql[4+q];
  const unsigned short* gKh = fkh + (size_t)p*16*4096;
  const unsigned short* gKl = fkl + (size_t)p*16*4096;
  const float* cAg = inv_na_k + p*NTOK;
  const float* cSg = skA + p*NTOK;
  float sc2=0.f, sv2=0.f, scv=0.f;
  float pc[4]={0,0,0,0}, pv_[4]={0,0,0,0}, pm[4]={0,0,0,0};
  float xc[4], xv[4];
  #pragma unroll
  for (int i=0;i<4;++i){ xc[i]=-1e30f; xv[i]=-1e30f; }
  int ko0 = ((q  )*64 + (cw*2)*16+lm)*8;
  int ko1 = ((q+4)*64 + (cw*2)*16+lm)*8;
  int c0 = s & 15;                   // rotation offset

#define PA_LOAD(K, cc_) do{ \
    const unsigned short* cbh_ = gKh + (size_t)(cc_)*4096; \
    const unsigned short* cbl_ = gKl + (size_t)(cc_)*4096; \
    K[0] = *(const short8*)(cbh_ + ko0); \
    K[1] = *(const short8*)(cbh_ + ko1); \
    K[2] = *(const short8*)(cbl_ + ko0); \
    K[3] = *(const short8*)(cbl_ + ko1); \
    K[4] = *(const short8*)(cbh_ + ko0 + 128); \
    K[5] = *(const short8*)(cbh_ + ko1 + 128); \
    K[6] = *(const short8*)(cbl_ + ko0 + 128); \
    K[7] = *(const short8*)(cbl_ + ko1 + 128); \
  }while(0)

#define PA_COMP(K, cc_) do{ \
    _Pragma("unroll") \
    for (int t2=0; t2<2; ++t2){ \
      int c16 = cw*2 + t2; \
      f32x4 acc = {0.f,0.f,0.f,0.f}; \
      acc = mfma16(ah0,K[t2*4+0],acc); acc = mfma16(ah1,K[t2*4+1],acc); \
      acc = mfma16(al0,K[t2*4+0],acc); acc = mfma16(al1,K[t2*4+1],acc); \
      acc = mfma16(ah0,K[t2*4+2],acc); acc = mfma16(ah1,K[t2*4+3],acc); \
      int colg = (cc_)*64 + c16*16 + lm; \
      float ca = cAg[colg], cs = cSg[colg]; \
      _Pragma("unroll") \
      for (int i=0;i<4;++i){ \
        float dot = acc[i]; \
        float cosv = fminf(fmaxf(dot*ia[i]*ca,-0.99f),0.99f); \
        float cov  = fmaf(-m8[i], cs, fmaf(dot, inv8, -t8[i])); \
        float marg = fmaxf(0.01f - cosv, 0.f); \
        sc2 = fmaf(cosv,cosv,sc2); sv2 = fmaf(cov,cov,sv2); scv = fmaf(cosv,cov,scv); \
        pc[i]+=cosv; pv_[i]+=cov; pm[i]+=marg; \
        xc[i]=fmaxf(xc[i],cosv); \
        xv[i]=fmaxf(xv[i],cov); \
      } \
    } \
  }while(0)

  short8 KA[8], KB[8];
  PA_LOAD(KA, c0);
  for (int t = 0; t < 16; t += 2){
    int ccA = (t + c0) & 15;
    int ccB = (t + 1 + c0) & 15;
    PA_LOAD(KB, ccB);
    PA_COMP(KA, ccA);
    if (t < 14){
      int ccA2 = (t + 2 + c0) & 15;
      PA_LOAD(KA, ccA2);
    }
    PA_COMP(KB, ccB);
  }
#undef PA_LOAD
#undef PA_COMP

  #pragma unroll
  for (int m=1;m<16;m<<=1){
    #pragma unroll
    for (int i=0;i<4;++i){
      pc[i]+=__shfl_xor(pc[i],m); pv_[i]+=__shfl_xor(pv_[i],m); pm[i]+=__shfl_xor(pm[i],m);
      xc[i]=fmaxf(xc[i],__shfl_xor(xc[i],m));
      xv[i]=fmaxf(xv[i],__shfl_xor(xv[i],m));
    }
  }
  if (lm==0){
    #pragma unroll
    for (int i=0;i<4;++i){
      int r16 = q*4+i;
      redbuf[w][r16][0]=pc[i]; redbuf[w][r16][1]=pv_[i]; redbuf[w][r16][2]=pm[i];
      redbuf[w][r16][3]=xc[i]; redbuf[w][r16][4]=xv[i];
    }
  }
  double vals[3] = {(double)sc2,(double)sv2,(double)scv};
  #pragma unroll
  for (int c2=0;c2<3;++c2){
    double vv = vals[c2];
    #pragma unroll
    for (int off=32; off; off>>=1) vv += __shfl_down(vv, off);
    if (l==0) wredS[w][c2] = vv;
  }
  __syncthreads();
  if (tid < 32){
    int rt2 = tid>>4, r16 = tid&15;
    int w0 = rt2, w1 = rt2+2;
    float sc = redbuf[w0][r16][0]+redbuf[w1][r16][0];
    float sv = redbuf[w0][r16][1]+redbuf[w1][r16][1];
    float sm = redbuf[w0][r16][2]+redbuf[w1][r16][2];
    float mxc = fmaxf(redbuf[w0][r16][3],redbuf[w1][r16][3]);
    float mxv = fmaxf(redbuf[w0][r16][4],redbuf[w1][r16][4]);
    int row = p*NTOK + n0 + tid;
    rs_cos[row]=sc; rs_cov[row]=sv; rs_marg[row]=sm;
    mxcosA[row]=mxc; mxcovA[row]=mxv;
  }
  if (tid == 0){
    int h = p >> 2;
    #pragma unroll
    for (int c2=0;c2<3;++c2){
      double t = wredS[0][c2]+wredS[1][c2]+wredS[2][c2]+wredS[3][c2];
      atomicAdd(&gacc[h*3+c2], t);
    }
  }
}

// ---------------------- row finish: var_row + row-sum-derived moments

__global__ __launch_bounds__(256) void k_rowfin(const float* __restrict__ rs_cos,
    const float* __restrict__ rs_cov, const float* __restrict__ rs_marg,
    float* __restrict__ var_row, double* __restrict__ racc){
  __shared__ double wredS[4][6];
  int row = blockIdx.x*256 + threadIdx.x;
  int p = row >> 10; int h = p >> 2;
  float vr = rs_marg[row] * (1.0f/1024.0f);
  var_row[row] = vr;
  double dv = (double)vr;
  double rc = (double)rs_cos[row], rv = (double)rs_cov[row];
  double vals[6];
  vals[0] = 1024.0*dv;
  vals[1] = 1024.0*dv*dv;
  vals[2] = dv*rc;
  vals[3] = dv*rv;
  vals[4] = rc;
  vals[5] = rv;
  int lane = threadIdx.x & 63, wid = threadIdx.x >> 6;
  #pragma unroll
  for (int c2 = 0; c2 < 6; ++c2){
    double vv = vals[c2];
    #pragma unroll
    for (int off=32; off; off>>=1) vv += __shfl_down(vv, off);
    if (lane==0) wredS[wid][c2] = vv;
  }
  __syncthreads();
  if (threadIdx.x == 0){
    #pragma unroll
    for (int c2 = 0; c2 < 6; ++c2){
      double t = wredS[0][c2]+wredS[1][c2]+wredS[2][c2]+wredS[3][c2];
      atomicAdd(&racc[h*6+c2], t);
    }
  }
}

// ------------------------------------- finalize scalars -> d2 coefficients

__global__ void k_final(const double* __restrict__ gacc, const double* __restrict__ racc,
                        const float* __restrict__ wp_out, float* __restrict__ coef){
  if (threadIdx.x != 0) return;
  const double N = 33554432.0;
  double Sc1=0,Sc2=0,Sv1=0,Sv2=0,Sr1=0,Sr2=0;
  for (int h=0;h<8;++h){
    Sc2+=gacc[h*3+0]; Sv2+=gacc[h*3+1];
    Sr1+=racc[h*6+0]; Sr2+=racc[h*6+1];
    Sc1+=racc[h*6+4]; Sv1+=racc[h*6+5];
  }
  double cvar = (Sc2 - Sc1*Sc1/N)/(N-1.0);
  double cn = sqrt(fmax(cvar,0.0)) + 1e-6;
  double cscale = (cn < 1e-4) ? 0.1 : 1.0;
  double vraw = (Sv2 - Sv1*Sv1/N)/(N-1.0);
  double sraw = sqrt(fmax(vraw,0.0));
  double basev = 0.001/1024.0;
  double regv = (sraw < 1e-6) ? basev*10.0 : basev;
  double covn = regv*sraw + 1e-6;
  double vvar = (Sr2 - Sr1*Sr1/N)/(N-1.0);
  double vn = sqrt(fmax(vvar,0.0)) + 1e-6;
  double ah[8], bh[8], chh[8];
  double Sd1=0.0, Sd2=0.0;
  for (int h=0;h<8;++h){
    double a = (double)wp_out[h*3+0]/cn*cscale;
    double b = (double)wp_out[h*3+1]*regv*0.5/covn;
    double c = (double)wp_out[h*3+2]*0.5/vn;
    ah[h]=a; bh[h]=b; chh[h]=c;
    Sd1 += a*racc[h*6+4] + b*racc[h*6+5] + c*racc[h*6+0];
    Sd2 += a*a*gacc[h*3+0] + b*b*gacc[h*3+1] + c*c*racc[h*6+1]
         + 2.0*(a*b*gacc[h*3+2] + a*c*racc[h*6+2] + b*c*racc[h*6+3]);
  }
  double dvar = (Sd2 - Sd1*Sd1/N)/(N-1.0);
  double dstd = sqrt(fmax(dvar,0.0));
  double temp = (dstd < 1e-6) ? 0.1 : 0.3 + dstd;
  double tcl = fmin(fmax(temp,0.1),5.0);
  double it = 1.0/tcl;
  for (int h=0;h<8;++h){
    coef[h*3+0] = (float)(ah[h]*it);
    coef[h*3+1] = (float)(bh[h]*it);
    coef[h*3+2] = (float)(chh[h]*it);
  }
}

// -------------------- pass C (MFMA): K/V direct from L2; P-transpose in
// LDS (double-buffered, stride 72: 16B-aligned rows; 2-way aliasing free).

__global__ __launch_bounds__(256) void k_pv(
    const unsigned short* __restrict__ fqh, const unsigned short* __restrict__ fql,
    const unsigned short* __restrict__ fkh, const unsigned short* __restrict__ fkl,
    const unsigned short* __restrict__ fvTh, const unsigned short* __restrict__ fvTl,
    const float* __restrict__ inv_na_q, const float* __restrict__ muqA,
    const float* __restrict__ tqA,
    const float* __restrict__ inv_na_k, const float* __restrict__ skA,
    const float* __restrict__ Sarr, const float* __restrict__ var_row,
    const float* __restrict__ mxcosA, const float* __restrict__ mxcovA,
    const float* __restrict__ coef,
    unsigned short* __restrict__ ohh, unsigned short* __restrict__ ohl){
  __shared__ __align__(16) unsigned short ph[2][32][72];
  __shared__ float denbuf[4][16];
  __shared__ float dnv[32];
  int b = blockIdx.x;
  int p = ((b&7)<<2) | ((b>>3)&3);   // XCD swizzle
  int s = b>>5;
  int n0 = s*32;
  int h = p>>2, qb = p&3;
  int tid = threadIdx.x, w = tid>>6, l = tid&63;
  int lm = l&15, q = l>>4;
  int rt = w&1, cw = w>>1;
  int nw = n0 + rt*16;
  float A = coef[h*3+0], B = coef[h*3+1], C = coef[h*3+2];
  float Sp = Sarr[p];
  const float inv8 = (float)(1.0/(8.0+1e-6));
  float B8 = B*inv8;
  float ia[4], bm[4], o2[4];
  #pragma unroll
  for (int i=0;i<4;++i){
    int rg = p*NTOK + nw + q*4 + i;
    float mq = muqA[rg];
    ia[i] = inv_na_q[rg];
    bm[i] = B8*mq;
    float tq2 = tqA[rg] - mq*Sp;
    float vr = var_row[rg];
    float Mh = A*mxcosA[rg] + B*mxcovA[rg] + C*vr;
    o2[i] = (C*vr - Mh) - B8*tq2;
  }
  const short8* aqh = (const short8*)(fqh + (size_t)(p*NTOK + nw + lm)*DH);
  const short8* aql = (const short8*)(fql + (size_t)(p*NTOK + nw + lm)*DH);
  short8 ah0 = aqh[q], ah1 = aqh[4+q], al0 = aql[q], al1 = aql[4+q];
  const unsigned short* gKh = fkh  + (size_t)p*16*4096;
  const unsigned short* gKl = fkl  + (size_t)p*16*4096;
  const unsigned short* gVh = fvTh + (size_t)p*16*4096;
  const unsigned short* gVl = fvTl + (size_t)p*16*4096;
  const float* cAg = inv_na_k + p*NTOK;
  const float* cSg = skA + p*NTOK;
  f32x4 o0 = {0.f,0.f,0.f,0.f}, o1 = {0.f,0.f,0.f,0.f};
  float den[4] = {0.f,0.f,0.f,0.f};
  int ko0 = ((q  )*64 + (cw*2)*16+lm)*8;
  int ko1 = ((q+4)*64 + (cw*2)*16+lm)*8;
  int vo0 = ((q  )*64 + w*16+lm)*8;
  int vo1 = ((q+4)*64 + w*16+lm)*8;
  int c0 = s & 15;                   // rotation offset

#define PV_KLOAD(K, cc_) do{ \
    const unsigned short* cbh_ = gKh + (size_t)(cc_)*4096; \
    const unsigned short* cbl_ = gKl + (size_t)(cc_)*4096; \
    K[0] = *(const short8*)(cbh_ + ko0); \
    K[1] = *(const short8*)(cbh_ + ko1); \
    K[2] = *(const short8*)(cbl_ + ko0); \
    K[3] = *(const short8*)(cbl_ + ko1); \
    K[4] = *(const short8*)(cbh_ + ko0 + 128); \
    K[5] = *(const short8*)(cbh_ + ko1 + 128); \
    K[6] = *(const short8*)(cbl_ + ko0 + 128); \
    K[7] = *(const short8*)(cbl_ + ko1 + 128); \
  }while(0)

#define PV_QK(K, cc_, phc_) do{ \
    _Pragma("unroll") \
    for (int t2=0; t2<2; ++t2){ \
      int c16 = cw*2 + t2; \
      f32x4 acc = {0.f,0.f,0.f,0.f}; \
      acc = mfma16(ah0,K[t2*4+0],acc); acc = mfma16(ah1,K[t2*4+1],acc); \
      acc = mfma16(al0,K[t2*4+0],acc); acc = mfma16(al1,K[t2*4+1],acc); \
      acc = mfma16(ah0,K[t2*4+2],acc); acc = mfma16(ah1,K[t2*4+3],acc); \
      int colg = (cc_)*64 + c16*16 + lm; \
      float ca = cAg[colg], cs = cSg[colg]; \
      _Pragma("unroll") \
      for (int i=0;i<4;++i){ \
        float dot = acc[i]; \
        float cosv = fminf(fmaxf(dot*ia[i]*ca,-0.99f),0.99f); \
        float arg = fmaf(A, cosv, fmaf(-bm[i], cs, fmaf(B8, dot, o2[i]))); \
        float e = __expf(arg); \
        unsigned short us = f2h(e); \
        phc_[rt*16+q*4+i][c16*16+lm] = us; \
        den[i] += h2f(us); \
      } \
    } \
  }while(0)

#define PV_TAIL(cc_, phc_) do{ \
    const unsigned short* cvh_ = gVh + (size_t)(cc_)*4096; \
    const unsigned short* cvl_ = gVl + (size_t)(cc_)*4096; \
    half8 vh0 = *(const half8*)(cvh_ + vo0); \
    half8 vh1 = *(const half8*)(cvh_ + vo1); \
    half8 vl0 = *(const half8*)(cvl_ + vo0); \
    half8 vl1 = *(const half8*)(cvl_ + vo1); \
    __syncthreads(); \
    half8 pb00 = *(const half8*)&phc_[lm][q*8]; \
    half8 pb01 = *(const half8*)&phc_[lm][32+q*8]; \
    half8 pb10 = *(const half8*)&phc_[16+lm][q*8]; \
    half8 pb11 = *(const half8*)&phc_[16+lm][32+q*8]; \
    o0 = mfma16f(vh0,pb00,o0); o0 = mfma16f(vl0,pb00,o0); \
    o0 = mfma16f(vh1,pb01,o0); o0 = mfma16f(vl1,pb01,o0); \
    o1 = mfma16f(vh0,pb10,o1); o1 = mfma16f(vl0,pb10,o1); \
    o1 = mfma16f(vh1,pb11,o1); o1 = mfma16f(vl1,pb11,o1); \
  }while(0)

  short8 KA[8], KB[8];
  PV_KLOAD(KA, c0);
  for (int t = 0; t < 16; t += 2){
    int ccA = (t + c0) & 15;
    int ccB = (t + 1 + c0) & 15;
    PV_KLOAD(KB, ccB);
    {
      unsigned short (*phc)[72] = ph[0];
      PV_QK(KA, ccA, phc);
      PV_TAIL(ccA, phc);
    }
    if (t < 14){
      int ccA2 = (t + 2 + c0) & 15;
      PV_KLOAD(KA, ccA2);
    }
    {
      unsigned short (*phc)[72] = ph[1];
      PV_QK(KB, ccB, phc);
      PV_TAIL(ccB, phc);
    }
  }
#undef PV_KLOAD
#undef PV_QK
#undef PV_TAIL

  #pragma unroll
  for (int m=1;m<16;m<<=1){
    #pragma unroll
    for (int i=0;i<4;++i) den[i] += __shfl_xor(den[i],m);
  }
  if (lm==0){
    #pragma unroll
    for (int i=0;i<4;++i) denbuf[w][q*4+i] = den[i];
  }
  __syncthreads();
  if (tid < 32){
    int rt2 = tid>>4, r16 = tid&15;
    dnv[tid] = 1.0f/(denbuf[rt2][r16] + denbuf[rt2+2][r16]);
  }
  __syncthreads();
  {
    float inv0 = dnv[lm];
    float inv1 = dnv[16+lm];
    int dcol = h*64 + w*16 + q*4;
    int row0 = qb*NTOK + n0 + lm;
    int row1 = row0 + 16;
    size_t b0i = cidx(row0, dcol);
    size_t b1i = cidx(row1, dcol);
    ushort4 h0,l0,h1,l1;
    { float xx=o0[0]*inv0; unsigned short hh=f2bf(xx); h0.x=hh; l0.x=f2bf(xx-bf2f(hh)); }
    { float xx=o0[1]*inv0; unsigned short hh=f2bf(xx); h0.y=hh; l0.y=f2bf(xx-bf2f(hh)); }
    { float xx=o0[2]*inv0; unsigned short hh=f2bf(xx); h0.z=hh; l0.z=f2bf(xx-bf2f(hh)); }
    { float xx=o0[3]*inv0; unsigned short hh=f2bf(xx); h0.w=hh; l0.w=f2bf(xx-bf2f(hh)); }
    { float xx=o1[0]*inv1; unsigned short hh=f2bf(xx); h1.x=hh; l1.x=f2bf(xx-bf2f(hh)); }
    { float xx=o1[1]*inv1; unsigned short hh=f2bf(xx); h1.y=hh; l1.y=f2bf(xx-bf2f(hh)); }
    { float xx=o1[2]*inv1; unsigned short hh=f2bf(xx); h1.z=hh; l1.z=f2bf(xx-bf2f(hh)); }
    { float xx=o1[3]*inv1; unsigned short hh=f2bf(xx); h1.w=hh; l1.w=f2bf(xx-bf2f(hh)); }
    *(ushort4*)(ohh+b0i)=h0; *(ushort4*)(ohl+b0i)=l0;
    *(ushort4*)(ohh+b1i)=h1; *(ushort4*)(ohl+b1i)=l1;
  }
}

// ----------------- output GEMM (MFMA): A and W staged via global_load_lds.

__global__ __launch_bounds__(256) void k_outmm(
    const unsigned short* __restrict__ ohh, const unsigned short* __restrict__ ohl,
    const unsigned short* __restrict__ Woth, const unsigned short* __restrict__ Wotl,
    const float* __restrict__ bias, float* __restrict__ out){
  __shared__ __align__(16) unsigned short Ah[4096];
  __shared__ __align__(16) unsigned short Al[4096];
  __shared__ __align__(16) unsigned short W0h[4096];
  __shared__ __align__(16) unsigned short W0l[4096];
  __shared__ __align__(16) unsigned short W1h[4096];
  __shared__ __align__(16) unsigned short W1l[4096];
  int mb = blockIdx.x, nb = blockIdx.y;
  int tid = threadIdx.x, w = tid>>6, l = tid&63, lm = l&15, qd = l>>4;
  int rh = w&1, tile = w>>1;
  int cbase = nb*128 + tile*64;
  f32x4 acc[2][4];
  #pragma unroll
  for (int mt=0;mt<2;++mt)
    #pragma unroll
    for (int nt=0;nt<4;++nt) acc[mt][nt] = (f32x4){0.f,0.f,0.f,0.f};
  int r0 = mb & 7;
  for (int t=0; t<8; ++t){
    int kc8 = (t + r0) & 7;
    __syncthreads();
    {
      const unsigned short* aSh = ohh  + ((size_t)(mb*8+kc8))*4096;
      const unsigned short* aSl = ohl  + ((size_t)(mb*8+kc8))*4096;
      const unsigned short* s0h = Woth + ((size_t)((nb*2  )*8+kc8))*4096;
      const unsigned short* s0l = Wotl + ((size_t)((nb*2  )*8+kc8))*4096;
      const unsigned short* s1h = Woth + ((size_t)((nb*2+1)*8+kc8))*4096;
      const unsigned short* s1l = Wotl + ((size_t)((nb*2+1)*8+kc8))*4096;
      if (w==0){
        #pragma unroll
        for (int j=0;j<8;++j) dma16(aSh + j*512 + l*8, &Ah[j*512]);
        #pragma unroll
        for (int j=0;j<4;++j) dma16(s1h + j*512 + l*8, &W1h[j*512]);
      } else if (w==1){
        #pragma unroll
        for (int j=0;j<8;++j) dma16(aSl + j*512 + l*8, &Al[j*512]);
        #pragma unroll
        for (int j=4;j<8;++j) dma16(s1h + j*512 + l*8, &W1h[j*512]);
      } else if (w==2){
        #pragma unroll
        for (int j=0;j<8;++j) dma16(s0h + j*512 + l*8, &W0h[j*512]);
        #pragma unroll
        for (int j=0;j<4;++j) dma16(s1l + j*512 + l*8, &W1l[j*512]);
      } else {
        #pragma unroll
        for (int j=0;j<8;++j) dma16(s0l + j*512 + l*8, &W0l[j*512]);
        #pragma unroll
        for (int j=4;j<8;++j) dma16(s1l + j*512 + l*8, &W1l[j*512]);
      }
    }
    __syncthreads();
    const unsigned short* Wh_ = tile ? W1h : W0h;
    const unsigned short* Wl_ = tile ? W1l : W0l;
    #pragma unroll
    for (int kch=0; kch<2; ++kch){
      short8 a_h[2], a_l[2];
      #pragma unroll
      for (int mt=0;mt<2;++mt){
        int off = ((kch*4+qd)*64 + rh*32 + mt*16 + lm)*8;
        a_h[mt] = *(const short8*)(Ah + off);
        a_l[mt] = *(const short8*)(Al + off);
      }
      #pragma unroll
      for (int nt=0;nt<4;++nt){
        int off = ((kch*4+qd)*64 + nt*16+lm)*8;
        short8 bh = *(const short8*)(Wh_ + off);
        short8 bl = *(const short8*)(Wl_ + off);
        #pragma unroll
        for (int mt=0;mt<2;++mt){
          acc[mt][nt] = mfma16(a_h[mt], bh, acc[mt][nt]);
          acc[mt][nt] = mfma16(a_h[mt], bl, acc[mt][nt]);
          acc[mt][nt] = mfma16(a_l[mt], bh, acc[mt][nt]);
        }
      }
    }
  }
  float bv[4];
  #pragma unroll
  for (int nt=0;nt<4;++nt) bv[nt] = bias[cbase+nt*16+lm];
  #pragma unroll
  for (int mt=0;mt<2;++mt){
    #pragma unroll
    for (int i=0;i<4;++i){
      int row = mb*64 + rh*32 + mt*16 + qd*4 + i;
      #pragma unroll
      for (int nt=0;nt<4;++nt){
        out[(size_t)row*DIMX + cbase + nt*16 + lm] = acc[mt][nt][i] + bv[nt];
      }
    }
  }
}

// ----------------------------------------------------------------- launch

extern "C" void kernel_launch(void* const* d_in, const int* in_sizes, int n_in,
                              void* d_out, int out_size, void* d_ws, size_t ws_size,
                              hipStream_t stream) {
  (void)in_sizes; (void)n_in; (void)out_size;
  const float* q     = (const float*)d_in[0];
  const float* k     = (const float*)d_in[1];
  const float* v     = (const float*)d_in[2];
  const float* ln_g  = (const float*)d_in[3];
  const float* ln_b  = (const float*)d_in[4];
  const float* W_in  = (const float*)d_in[5];
  const float* wp_W1 = (const float*)d_in[6];
  const float* wp_b1 = (const float*)d_in[7];
  const float* wp_lg = (const float*)d_in[8];
  const float* wp_lb = (const float*)d_in[9];
  const float* wp_W2 = (const float*)d_in[10];
  const float* wp_b2 = (const float*)d_in[11];
  const float* wp_W3 = (const float*)d_in[12];
  const float* wp_b3 = (const float*)d_in[13];
  const float* wtemp = (const float*)d_in[14];
  const float* W_out = (const float*)d_in[15];
  const float* b_out = (const float*)d_in[16];
  float* out = (float*)d_out;

  char* wsb = (char*)d_ws;
  double* gacc = (double*)wsb;            // 24 doubles
  double* racc = gacc + 24;               // 48
  double* qgs  = racc + 48;               // 512
  double* nusum= qgs + 512;               // 2048  (doubles end @ 21056 B)
  float* coefG  = (float*)(wsb + 21120);      // 24 floats, inside zeroed zone
  float* fvA = (float*)(wsb + 24576);     // 8 MB; reused as ohh/ohl after k_mid
  unsigned short* ohh = (unsigned short*)fvA;                   // 4 MB
  unsigned short* ohl = ohh + (size_t)NQB*NTOK*NH*DH;           // 4 MB
  float* mu_rstd = fvA + (size_t)NPAIR*NTOK*DH;   // 24576
  float* Sarr = mu_rstd + 24576;          // 64 (padded)
  float* inv_na_q = Sarr + 64;
  float* muqA     = inv_na_q + NROWS;
  float* tqA      = muqA + NROWS;
  float* inv_na_k = tqA + NROWS;
  float* skA      = inv_na_k + NROWS;
  float* rs_cos   = skA + NROWS;
  float* rs_cov   = rs_cos + NROWS;
  float* rs_marg  = rs_cov + NROWS;
  float* var_row  = rs_marg + NROWS;
  float* mxcos    = var_row + NROWS;
  float* mxcov    = mxcos + NROWS;
  float* wp_out   = mxcov + NROWS;        // 32 (padded)
  float* endf     = wp_out + 32;
  size_t off16 = (size_t)((char*)endf - wsb);
  off16 = (off16 + 63) & ~(size_t)63;
  unsigned short* fqh  = (unsigned short*)(wsb + off16);
  unsigned short* fql  = fqh  + (size_t)NPAIR*NTOK*DH;
  unsigned short* fkh  = fql  + (size_t)NPAIR*NTOK*DH;
  unsigned short* fkl  = fkh  + (size_t)NPAIR*NTOK*DH;
  unsigned short* fvTh = fkl  + (size_t)NPAIR*NTOK*DH;
  unsigned short* fvTl = fvTh + (size_t)NPAIR*NTOK*DH;
  unsigned short* Wth  = fvTl + (size_t)NPAIR*NTOK*DH;
  unsigned short* Wtl  = Wth  + (size_t)DIMX*DIMX;
  unsigned short* Woth = Wtl  + (size_t)DIMX*DIMX;
  unsigned short* Wotl = Woth + (size_t)DIMX*DIMX;
  size_t need = (size_t)((char*)(Wotl + (size_t)DIMX*DIMX) - wsb);
  if (ws_size < need) return;  // fail cleanly rather than corrupt

  k_pre<<<3201, 256, 0, stream>>>(q, k, v, mu_rstd, W_in, W_out,
                                  Wth, Wtl, Woth, Wotl, (float*)wsb);
  k_projmm<<<dim3(64,4,3), 256, 0, stream>>>(q, k, v, ln_g, ln_b, Wth, Wtl,
                                             mu_rstd, fqh, fql, fkh, fkl, fvA,
                                             qgs, nusum);
  k_mid<<<8705, 256, 0, stream>>>(fvA, fvTh, fvTl, fqh, fql, fkh, fkl, nusum,
                                  inv_na_q, muqA, tqA, inv_na_k, skA,
                                  qgs, wp_W1, wp_b1, wp_lg, wp_lb,
                                  wp_W2, wp_b2, wp_W3, wp_b3, wtemp,
                                  wp_out, Sarr);
  k_passA<<<1024, 256, 0, stream>>>(fqh, fql, fkh, fkl,
                                    inv_na_q, muqA, tqA, inv_na_k, skA, Sarr,
                                    rs_cos, rs_cov, rs_marg,
                                    mxcos, mxcov, gacc);
  k_rowfin<<<128, 256, 0, stream>>>(rs_cos, rs_cov, rs_marg, var_row, racc);
  k_final<<<1, 64, 0, stream>>>(gacc, racc, wp_out, coefG);
  k_pv<<<1024, 256, 0, stream>>>(fqh, fql, fkh, fkl, fvTh, fvTl,
                                 inv_na_q, muqA, tqA, inv_na_k, skA, Sarr,
                                 var_row, mxcos, mxcov, coefG,
                                 ohh, ohl);
  k_outmm<<<dim3(64,4), 256, 0, stream>>>(ohh, ohl, Woth, Wotl, b_out, out);
}